// Round 1
// baseline (10459.945 us; speedup 1.0000x reference)
//
#include <hip/hip_runtime.h>
#include <math.h>

#define B_ 2
#define T_ 4096
#define D_ 2048
#define H_ 16
#define DK 128
#define DV 128
#define CH 64
#define M_ (B_ * T_)  // 8192

// ---------------------------------------------------------------------------
// GEMM: C[M,N] = A[M,K] @ W[K,N], f32 row-major. 128x128 tile, 256 thr, 8x8 reg.
// ---------------------------------------------------------------------------
__global__ __launch_bounds__(256) void gemm_f32(const float* __restrict__ A,
                                                const float* __restrict__ W,
                                                float* __restrict__ C,
                                                int M, int N, int K) {
  __shared__ float As[16][132];
  __shared__ float Bs[16][132];
  const int t = threadIdx.x;
  const int m0 = blockIdx.y * 128;
  const int n0 = blockIdx.x * 128;
  const int tm = (t >> 4) * 8;
  const int tn = (t & 15) * 8;
  const int a_k = t & 15;
  const int a_r = t >> 4;
  const int b_n = (t & 31) * 4;
  const int b_k = t >> 5;
  float acc[8][8];
#pragma unroll
  for (int i = 0; i < 8; ++i)
#pragma unroll
    for (int j = 0; j < 8; ++j) acc[i][j] = 0.f;

  for (int k0 = 0; k0 < K; k0 += 16) {
#pragma unroll
    for (int p = 0; p < 8; ++p) {
      const int r = a_r + p * 16;
      As[a_k][r] = A[(size_t)(m0 + r) * K + (k0 + a_k)];
    }
#pragma unroll
    for (int p = 0; p < 2; ++p) {
      const int kk = b_k + p * 8;
      *reinterpret_cast<float4*>(&Bs[kk][b_n]) =
          *reinterpret_cast<const float4*>(&W[(size_t)(k0 + kk) * N + (n0 + b_n)]);
    }
    __syncthreads();
#pragma unroll
    for (int kk = 0; kk < 16; ++kk) {
      float a[8], b[8];
      *reinterpret_cast<float4*>(&a[0]) = *reinterpret_cast<float4*>(&As[kk][tm]);
      *reinterpret_cast<float4*>(&a[4]) = *reinterpret_cast<float4*>(&As[kk][tm + 4]);
      *reinterpret_cast<float4*>(&b[0]) = *reinterpret_cast<float4*>(&Bs[kk][tn]);
      *reinterpret_cast<float4*>(&b[4]) = *reinterpret_cast<float4*>(&Bs[kk][tn + 4]);
#pragma unroll
      for (int i = 0; i < 8; ++i)
#pragma unroll
        for (int j = 0; j < 8; ++j) acc[i][j] = fmaf(a[i], b[j], acc[i][j]);
    }
    __syncthreads();
  }
#pragma unroll
  for (int i = 0; i < 8; ++i) {
#pragma unroll
    for (int j = 0; j < 8; j += 4) {
      float4 o4 = make_float4(acc[i][j], acc[i][j + 1], acc[i][j + 2], acc[i][j + 3]);
      *reinterpret_cast<float4*>(&C[(size_t)(m0 + tm + i) * N + (n0 + tn + j)]) = o4;
    }
  }
}

// ---------------------------------------------------------------------------
// Causal shared-kernel conv (K=4) + silu (+ optional per-head l2norm over 128)
// grid = B*T rows, 256 threads, 8 elems/thread.
// out[t] = w3*x[t] + w2*x[t-1] + w1*x[t-2] + w0*x[t-3]  (zero pad, per batch)
// ---------------------------------------------------------------------------
__global__ __launch_bounds__(256) void conv_silu(const float* __restrict__ in,
                                                 const float* __restrict__ cw,
                                                 float* __restrict__ out,
                                                 int do_norm) {
  const int bt = blockIdx.x;
  const int tb = bt & (T_ - 1);
  const int d0 = threadIdx.x * 8;
  const float* row = in + (size_t)bt * D_ + d0;
  float v[8];
#pragma unroll
  for (int j = 0; j < 8; ++j) v[j] = 0.f;
#pragma unroll
  for (int j = 0; j < 4; ++j) {
    if (tb >= j) {
      const float* rp = row - (size_t)j * D_;
      const float4 a = *reinterpret_cast<const float4*>(rp);
      const float4 b = *reinterpret_cast<const float4*>(rp + 4);
      const float wj = cw[3 - j];
      v[0] = fmaf(wj, a.x, v[0]); v[1] = fmaf(wj, a.y, v[1]);
      v[2] = fmaf(wj, a.z, v[2]); v[3] = fmaf(wj, a.w, v[3]);
      v[4] = fmaf(wj, b.x, v[4]); v[5] = fmaf(wj, b.y, v[5]);
      v[6] = fmaf(wj, b.z, v[6]); v[7] = fmaf(wj, b.w, v[7]);
    }
  }
#pragma unroll
  for (int j = 0; j < 8; ++j) v[j] = v[j] / (1.f + expf(-v[j]));
  if (do_norm) {
    float ss = 0.f;
#pragma unroll
    for (int j = 0; j < 8; ++j) ss = fmaf(v[j], v[j], ss);
    ss += __shfl_xor(ss, 1);
    ss += __shfl_xor(ss, 2);
    ss += __shfl_xor(ss, 4);
    ss += __shfl_xor(ss, 8);
    const float sc = rsqrtf(ss + 1e-6f);
#pragma unroll
    for (int j = 0; j < 8; ++j) v[j] *= sc;
  }
  float* op = out + (size_t)bt * D_ + d0;
  *reinterpret_cast<float4*>(op) = make_float4(v[0], v[1], v[2], v[3]);
  *reinterpret_cast<float4*>(op + 4) = make_float4(v[4], v[5], v[6], v[7]);
}

// ---------------------------------------------------------------------------
// beta = sigmoid(x @ Wb), Wb [D,16]. 4 rows/block (wave per row).
// ---------------------------------------------------------------------------
__global__ __launch_bounds__(256) void beta_sigmoid(const float* __restrict__ x,
                                                    const float* __restrict__ Wb,
                                                    float* __restrict__ beta) {
  const int t = threadIdx.x;
  const int m = blockIdx.x * 4 + (t >> 6);
  const int l = t & 63;
  const int c = l & 15;
  const int s = l >> 4;
  const float* xr = x + (size_t)m * D_;
  const int kb = s * (D_ / 4);
  float acc = 0.f;
  for (int k = 0; k < D_ / 4; ++k)
    acc = fmaf(xr[kb + k], Wb[(size_t)(kb + k) * H_ + c], acc);
  acc += __shfl_xor(acc, 16);
  acc += __shfl_xor(acc, 32);
  if (l < 16) beta[(size_t)m * H_ + c] = 1.f / (1.f + expf(-acc));
}

// ---------------------------------------------------------------------------
// Delta rule, one block per (b,h). 256 threads. All f32, all tiles in LDS.
// Uses u = M^-1 (v*beta - k_beta @ S)  (eliminates the separate w solve).
// ---------------------------------------------------------------------------
__global__ __launch_bounds__(256) void delta_rule(const float* __restrict__ q,
                                                  const float* __restrict__ k,
                                                  const float* __restrict__ v,
                                                  const float* __restrict__ beta,
                                                  float* __restrict__ o) {
  __shared__ float S[DK][DV];         // 64 KB, persistent state
  __shared__ float kc[CH][DK];        // 32 KB
  __shared__ float uT[DV][CH + 1];    // 33.3 KB (u transposed: uT[e][r])
  __shared__ float Am[CH][CH + 4];    // 17.4 KB (A, then attn)
  __shared__ float betac[CH];

  const int bh = blockIdx.x;
  const int b = bh >> 4;
  const int h = bh & 15;
  const int t = threadIdx.x;
  const float qscale = 0.08838834764831845f;  // 128^-0.5

  for (int i = t; i < DK * DV; i += 256) (&S[0][0])[i] = 0.f;

  const size_t rowbase = ((size_t)b * T_) * D_ + (size_t)h * DK;
  const int i0 = (t >> 4) * 4;   // A/attn row tile
  const int j0 = (t & 15) * 4;   // A/attn col tile
  const int r0 = (t >> 4) * 4;   // u/o row tile
  const int e0 = (t & 15) * 8;   // u/o col tile
  const int sd0 = (t >> 4) * 8;  // S-update d tile
  const int se0 = (t & 15) * 8;  // S-update e tile

  for (int c0 = 0; c0 < T_; c0 += CH) {
    __syncthreads();  // protects kc/betac reload + S init/update visibility
    {  // load k chunk + beta
      const int cc = (t & 31) * 4;
      const int rr = t >> 5;
#pragma unroll
      for (int p = 0; p < 8; ++p) {
        const int r = rr + p * 8;
        *reinterpret_cast<float4*>(&kc[r][cc]) =
            *reinterpret_cast<const float4*>(&k[rowbase + (size_t)(c0 + r) * D_ + cc]);
      }
      if (t < CH) betac[t] = beta[((size_t)b * T_ + c0 + t) * H_ + h];
    }
    __syncthreads();

    {  // A[i][j] = (j<i) ? beta[i]*dot(k[i],k[j]) : 0
      float acc[4][4];
#pragma unroll
      for (int xx = 0; xx < 4; ++xx)
#pragma unroll
        for (int yy = 0; yy < 4; ++yy) acc[xx][yy] = 0.f;
      for (int d = 0; d < DK; d += 4) {
        float4 ai[4], kj[4];
#pragma unroll
        for (int xx = 0; xx < 4; ++xx) ai[xx] = *reinterpret_cast<float4*>(&kc[i0 + xx][d]);
#pragma unroll
        for (int xx = 0; xx < 4; ++xx) kj[xx] = *reinterpret_cast<float4*>(&kc[j0 + xx][d]);
#pragma unroll
        for (int xx = 0; xx < 4; ++xx)
#pragma unroll
          for (int yy = 0; yy < 4; ++yy)
            acc[xx][yy] += ai[xx].x * kj[yy].x + ai[xx].y * kj[yy].y +
                           ai[xx].z * kj[yy].z + ai[xx].w * kj[yy].w;
      }
#pragma unroll
      for (int xx = 0; xx < 4; ++xx)
#pragma unroll
        for (int yy = 0; yy < 4; ++yy) {
          const int ii = i0 + xx, jj = j0 + yy;
          Am[ii][jj] = (jj < ii) ? betac[ii] * acc[xx][yy] : 0.f;
        }
    }

    {  // u_r[r][e] = beta[r]*(v[r][e] - sum_d k[r][d]*S[d][e])  -> uT[e][r]
      float acc[4][8];
#pragma unroll
      for (int xx = 0; xx < 4; ++xx) {
        const float* vp = &v[rowbase + (size_t)(c0 + r0 + xx) * D_ + e0];
        const float4 v0 = *reinterpret_cast<const float4*>(vp);
        const float4 v1 = *reinterpret_cast<const float4*>(vp + 4);
        acc[xx][0] = v0.x; acc[xx][1] = v0.y; acc[xx][2] = v0.z; acc[xx][3] = v0.w;
        acc[xx][4] = v1.x; acc[xx][5] = v1.y; acc[xx][6] = v1.z; acc[xx][7] = v1.w;
      }
      for (int d = 0; d < DK; d += 4) {
        float ka[4][4];
#pragma unroll
        for (int xx = 0; xx < 4; ++xx) {
          const float4 k4 = *reinterpret_cast<float4*>(&kc[r0 + xx][d]);
          ka[xx][0] = k4.x; ka[xx][1] = k4.y; ka[xx][2] = k4.z; ka[xx][3] = k4.w;
        }
#pragma unroll
        for (int dd = 0; dd < 4; ++dd) {
          const float4 s0 = *reinterpret_cast<float4*>(&S[d + dd][e0]);
          const float4 s1 = *reinterpret_cast<float4*>(&S[d + dd][e0 + 4]);
          float sv[8] = {s0.x, s0.y, s0.z, s0.w, s1.x, s1.y, s1.z, s1.w};
#pragma unroll
          for (int xx = 0; xx < 4; ++xx)
#pragma unroll
            for (int yy = 0; yy < 8; ++yy)
              acc[xx][yy] = fmaf(-ka[xx][dd], sv[yy], acc[xx][yy]);
        }
      }
#pragma unroll
      for (int xx = 0; xx < 4; ++xx) {
        const float bb = betac[r0 + xx];
#pragma unroll
        for (int yy = 0; yy < 8; ++yy) uT[e0 + yy][r0 + xx] = bb * acc[xx][yy];
      }
    }
    __syncthreads();

    // forward substitution: u[i] -= sum_{j<i} A[i][j]*u[j]; lane owns column e=t
    if (t < DV) {
      for (int i = 1; i < CH; ++i) {
        float s0 = 0.f, s1 = 0.f, s2 = 0.f, s3 = 0.f;
        const int i4 = i & ~3;
        for (int j = 0; j < i4; j += 4) {
          s0 = fmaf(Am[i][j + 0], uT[t][j + 0], s0);
          s1 = fmaf(Am[i][j + 1], uT[t][j + 1], s1);
          s2 = fmaf(Am[i][j + 2], uT[t][j + 2], s2);
          s3 = fmaf(Am[i][j + 3], uT[t][j + 3], s3);
        }
        for (int j = i4; j < i; ++j) s0 = fmaf(Am[i][j], uT[t][j], s0);
        uT[t][i] -= (s0 + s1) + (s2 + s3);
      }
    }
    __syncthreads();

    {  // attn[i][j] = (j<=i) ? qscale*dot(q[i],k[j]) : 0   (overwrites Am)
      float acc[4][4];
#pragma unroll
      for (int xx = 0; xx < 4; ++xx)
#pragma unroll
        for (int yy = 0; yy < 4; ++yy) acc[xx][yy] = 0.f;
      for (int d = 0; d < DK; d += 4) {
        float4 qi[4], kj[4];
#pragma unroll
        for (int xx = 0; xx < 4; ++xx)
          qi[xx] = *reinterpret_cast<const float4*>(&q[rowbase + (size_t)(c0 + i0 + xx) * D_ + d]);
#pragma unroll
        for (int xx = 0; xx < 4; ++xx) kj[xx] = *reinterpret_cast<float4*>(&kc[j0 + xx][d]);
#pragma unroll
        for (int xx = 0; xx < 4; ++xx)
#pragma unroll
          for (int yy = 0; yy < 4; ++yy)
            acc[xx][yy] += qi[xx].x * kj[yy].x + qi[xx].y * kj[yy].y +
                           qi[xx].z * kj[yy].z + qi[xx].w * kj[yy].w;
      }
#pragma unroll
      for (int xx = 0; xx < 4; ++xx)
#pragma unroll
        for (int yy = 0; yy < 4; ++yy) {
          const int ii = i0 + xx, jj = j0 + yy;
          Am[ii][jj] = (jj <= ii) ? qscale * acc[xx][yy] : 0.f;
        }
    }
    __syncthreads();

    {  // o = qscale*(q @ S) + attn @ u ; write to global
      float acc[4][8];
#pragma unroll
      for (int xx = 0; xx < 4; ++xx)
#pragma unroll
        for (int yy = 0; yy < 8; ++yy) acc[xx][yy] = 0.f;
      for (int d = 0; d < DK; d += 4) {
        float qa[4][4];
#pragma unroll
        for (int xx = 0; xx < 4; ++xx) {
          const float4 q4 = *reinterpret_cast<const float4*>(
              &q[rowbase + (size_t)(c0 + r0 + xx) * D_ + d]);
          qa[xx][0] = q4.x; qa[xx][1] = q4.y; qa[xx][2] = q4.z; qa[xx][3] = q4.w;
        }
#pragma unroll
        for (int dd = 0; dd < 4; ++dd) {
          const float4 s0 = *reinterpret_cast<float4*>(&S[d + dd][e0]);
          const float4 s1 = *reinterpret_cast<float4*>(&S[d + dd][e0 + 4]);
          float sv[8] = {s0.x, s0.y, s0.z, s0.w, s1.x, s1.y, s1.z, s1.w};
#pragma unroll
          for (int xx = 0; xx < 4; ++xx)
#pragma unroll
            for (int yy = 0; yy < 8; ++yy)
              acc[xx][yy] = fmaf(qa[xx][dd], sv[yy], acc[xx][yy]);
        }
      }
#pragma unroll
      for (int xx = 0; xx < 4; ++xx)
#pragma unroll
        for (int yy = 0; yy < 8; ++yy) acc[xx][yy] *= qscale;
      for (int m = 0; m < CH; ++m) {
        float ar[4];
#pragma unroll
        for (int xx = 0; xx < 4; ++xx) ar[xx] = Am[r0 + xx][m];
        float ue[8];
#pragma unroll
        for (int yy = 0; yy < 8; ++yy) ue[yy] = uT[e0 + yy][m];
#pragma unroll
        for (int xx = 0; xx < 4; ++xx)
#pragma unroll
          for (int yy = 0; yy < 8; ++yy) acc[xx][yy] = fmaf(ar[xx], ue[yy], acc[xx][yy]);
      }
#pragma unroll
      for (int xx = 0; xx < 4; ++xx) {
        float* op = &o[rowbase + (size_t)(c0 + r0 + xx) * D_ + e0];
        *reinterpret_cast<float4*>(op) =
            make_float4(acc[xx][0], acc[xx][1], acc[xx][2], acc[xx][3]);
        *reinterpret_cast<float4*>(op + 4) =
            make_float4(acc[xx][4], acc[xx][5], acc[xx][6], acc[xx][7]);
      }
    }
    __syncthreads();

    {  // S[d][e] += sum_m k[m][d] * u[m][e]
      float acc[8][8];
#pragma unroll
      for (int xx = 0; xx < 8; ++xx)
#pragma unroll
        for (int yy = 0; yy < 8; ++yy) acc[xx][yy] = 0.f;
      for (int m = 0; m < CH; ++m) {
        float kd[8];
        const float4 k0_ = *reinterpret_cast<float4*>(&kc[m][sd0]);
        const float4 k1_ = *reinterpret_cast<float4*>(&kc[m][sd0 + 4]);
        kd[0] = k0_.x; kd[1] = k0_.y; kd[2] = k0_.z; kd[3] = k0_.w;
        kd[4] = k1_.x; kd[5] = k1_.y; kd[6] = k1_.z; kd[7] = k1_.w;
        float ue[8];
#pragma unroll
        for (int yy = 0; yy < 8; ++yy) ue[yy] = uT[se0 + yy][m];
#pragma unroll
        for (int xx = 0; xx < 8; ++xx)
#pragma unroll
          for (int yy = 0; yy < 8; ++yy) acc[xx][yy] = fmaf(kd[xx], ue[yy], acc[xx][yy]);
      }
#pragma unroll
      for (int xx = 0; xx < 8; ++xx)
#pragma unroll
        for (int yy = 0; yy < 8; ++yy) S[sd0 + xx][se0 + yy] += acc[xx][yy];
    }
  }
}

// ---------------------------------------------------------------------------
// per-head RMSNorm (over 128) * onorm_w, in-place.
// ---------------------------------------------------------------------------
__global__ __launch_bounds__(256) void rms_onorm(float* __restrict__ io,
                                                 const float* __restrict__ w) {
  const int bt = blockIdx.x;
  const int d0 = threadIdx.x * 8;
  float* p = io + (size_t)bt * D_ + d0;
  const float4 a = *reinterpret_cast<float4*>(p);
  const float4 b = *reinterpret_cast<float4*>(p + 4);
  float v[8] = {a.x, a.y, a.z, a.w, b.x, b.y, b.z, b.w};
  float ss = 0.f;
#pragma unroll
  for (int j = 0; j < 8; ++j) ss = fmaf(v[j], v[j], ss);
  ss += __shfl_xor(ss, 1);
  ss += __shfl_xor(ss, 2);
  ss += __shfl_xor(ss, 4);
  ss += __shfl_xor(ss, 8);
  const float sc = rsqrtf(ss * (1.0f / 128.0f) + 1e-5f);
  const int hd = d0 & 127;
#pragma unroll
  for (int j = 0; j < 8; ++j) v[j] *= sc * w[hd + j];
  *reinterpret_cast<float4*>(p) = make_float4(v[0], v[1], v[2], v[3]);
  *reinterpret_cast<float4*>(p + 4) = make_float4(v[4], v[5], v[6], v[7]);
}

// ---------------------------------------------------------------------------
extern "C" void kernel_launch(void* const* d_in, const int* in_sizes, int n_in,
                              void* d_out, int out_size, void* d_ws, size_t ws_size,
                              hipStream_t stream) {
  const float* x  = (const float*)d_in[0];
  const float* Wq = (const float*)d_in[1];
  const float* Wk = (const float*)d_in[2];
  const float* Wv = (const float*)d_in[3];
  const float* Wb = (const float*)d_in[4];
  const float* Wo = (const float*)d_in[5];
  const float* cq = (const float*)d_in[6];
  const float* ck = (const float*)d_in[7];
  const float* cv = (const float*)d_in[8];
  const float* ow = (const float*)d_in[9];
  float* out = (float*)d_out;

  const size_t NE = (size_t)M_ * D_;
  float* raw   = (float*)d_ws;      // [M,D] scratch (gemm out, later o)
  float* qb    = raw + NE;          // [M,D]
  float* kb    = qb + NE;           // [M,D]
  float* betab = kb + NE;           // [M,H]
  float* vb    = out;               // v lives in d_out until final GEMM

  dim3 gg(D_ / 128, M_ / 128);
  gemm_f32<<<gg, 256, 0, stream>>>(x, Wq, raw, M_, D_, D_);
  conv_silu<<<M_, 256, 0, stream>>>(raw, cq, qb, 1);
  gemm_f32<<<gg, 256, 0, stream>>>(x, Wk, raw, M_, D_, D_);
  conv_silu<<<M_, 256, 0, stream>>>(raw, ck, kb, 1);
  gemm_f32<<<gg, 256, 0, stream>>>(x, Wv, raw, M_, D_, D_);
  conv_silu<<<M_, 256, 0, stream>>>(raw, cv, vb, 0);
  beta_sigmoid<<<M_ / 4, 256, 0, stream>>>(x, Wb, betab);
  delta_rule<<<B_ * H_, 256, 0, stream>>>(qb, kb, vb, betab, raw);
  rms_onorm<<<M_, 256, 0, stream>>>(raw, ow);
  gemm_f32<<<gg, 256, 0, stream>>>(raw, Wo, out, M_, D_, D_);
}

// Round 2
// 4998.195 us; speedup vs baseline: 2.0927x; 2.0927x over previous
//
#include <hip/hip_runtime.h>
#include <math.h>

#define B_ 2
#define T_ 4096
#define D_ 2048
#define H_ 16
#define DK 128
#define DV 128
#define CH 64
#define DVS 16  // dv columns per block (8-way split)
#define M_ (B_ * T_)  // 8192

// ---------------------------------------------------------------------------
// GEMM: C[M,N] = A[M,K] @ W[K,N], f32 row-major. 128x128 tile, 256 thr, 8x8 reg.
// ---------------------------------------------------------------------------
__global__ __launch_bounds__(256) void gemm_f32(const float* __restrict__ A,
                                                const float* __restrict__ W,
                                                float* __restrict__ C,
                                                int M, int N, int K) {
  __shared__ float As[16][132];
  __shared__ float Bs[16][132];
  const int t = threadIdx.x;
  const int m0 = blockIdx.y * 128;
  const int n0 = blockIdx.x * 128;
  const int tm = (t >> 4) * 8;
  const int tn = (t & 15) * 8;
  const int a_k = t & 15;
  const int a_r = t >> 4;
  const int b_n = (t & 31) * 4;
  const int b_k = t >> 5;
  float acc[8][8];
#pragma unroll
  for (int i = 0; i < 8; ++i)
#pragma unroll
    for (int j = 0; j < 8; ++j) acc[i][j] = 0.f;

  for (int k0 = 0; k0 < K; k0 += 16) {
#pragma unroll
    for (int p = 0; p < 8; ++p) {
      const int r = a_r + p * 16;
      As[a_k][r] = A[(size_t)(m0 + r) * K + (k0 + a_k)];
    }
#pragma unroll
    for (int p = 0; p < 2; ++p) {
      const int kk = b_k + p * 8;
      *reinterpret_cast<float4*>(&Bs[kk][b_n]) =
          *reinterpret_cast<const float4*>(&W[(size_t)(k0 + kk) * N + (n0 + b_n)]);
    }
    __syncthreads();
#pragma unroll
    for (int kk = 0; kk < 16; ++kk) {
      float a[8], b[8];
      *reinterpret_cast<float4*>(&a[0]) = *reinterpret_cast<float4*>(&As[kk][tm]);
      *reinterpret_cast<float4*>(&a[4]) = *reinterpret_cast<float4*>(&As[kk][tm + 4]);
      *reinterpret_cast<float4*>(&b[0]) = *reinterpret_cast<float4*>(&Bs[kk][tn]);
      *reinterpret_cast<float4*>(&b[4]) = *reinterpret_cast<float4*>(&Bs[kk][tn + 4]);
#pragma unroll
      for (int i = 0; i < 8; ++i)
#pragma unroll
        for (int j = 0; j < 8; ++j) acc[i][j] = fmaf(a[i], b[j], acc[i][j]);
    }
    __syncthreads();
  }
#pragma unroll
  for (int i = 0; i < 8; ++i) {
#pragma unroll
    for (int j = 0; j < 8; j += 4) {
      float4 o4 = make_float4(acc[i][j], acc[i][j + 1], acc[i][j + 2], acc[i][j + 3]);
      *reinterpret_cast<float4*>(&C[(size_t)(m0 + tm + i) * N + (n0 + tn + j)]) = o4;
    }
  }
}

// ---------------------------------------------------------------------------
// Causal shared-kernel conv (K=4) + silu (+ optional per-head l2norm over 128)
// ---------------------------------------------------------------------------
__global__ __launch_bounds__(256) void conv_silu(const float* __restrict__ in,
                                                 const float* __restrict__ cw,
                                                 float* __restrict__ out,
                                                 int do_norm) {
  const int bt = blockIdx.x;
  const int tb = bt & (T_ - 1);
  const int d0 = threadIdx.x * 8;
  const float* row = in + (size_t)bt * D_ + d0;
  float v[8];
#pragma unroll
  for (int j = 0; j < 8; ++j) v[j] = 0.f;
#pragma unroll
  for (int j = 0; j < 4; ++j) {
    if (tb >= j) {
      const float* rp = row - (size_t)j * D_;
      const float4 a = *reinterpret_cast<const float4*>(rp);
      const float4 b = *reinterpret_cast<const float4*>(rp + 4);
      const float wj = cw[3 - j];
      v[0] = fmaf(wj, a.x, v[0]); v[1] = fmaf(wj, a.y, v[1]);
      v[2] = fmaf(wj, a.z, v[2]); v[3] = fmaf(wj, a.w, v[3]);
      v[4] = fmaf(wj, b.x, v[4]); v[5] = fmaf(wj, b.y, v[5]);
      v[6] = fmaf(wj, b.z, v[6]); v[7] = fmaf(wj, b.w, v[7]);
    }
  }
#pragma unroll
  for (int j = 0; j < 8; ++j) v[j] = v[j] / (1.f + expf(-v[j]));
  if (do_norm) {
    float ss = 0.f;
#pragma unroll
    for (int j = 0; j < 8; ++j) ss = fmaf(v[j], v[j], ss);
    ss += __shfl_xor(ss, 1);
    ss += __shfl_xor(ss, 2);
    ss += __shfl_xor(ss, 4);
    ss += __shfl_xor(ss, 8);
    const float sc = rsqrtf(ss + 1e-6f);
#pragma unroll
    for (int j = 0; j < 8; ++j) v[j] *= sc;
  }
  float* op = out + (size_t)bt * D_ + d0;
  *reinterpret_cast<float4*>(op) = make_float4(v[0], v[1], v[2], v[3]);
  *reinterpret_cast<float4*>(op + 4) = make_float4(v[4], v[5], v[6], v[7]);
}

// ---------------------------------------------------------------------------
// beta = sigmoid(x @ Wb), Wb [D,16].
// ---------------------------------------------------------------------------
__global__ __launch_bounds__(256) void beta_sigmoid(const float* __restrict__ x,
                                                    const float* __restrict__ Wb,
                                                    float* __restrict__ beta) {
  const int t = threadIdx.x;
  const int m = blockIdx.x * 4 + (t >> 6);
  const int l = t & 63;
  const int c = l & 15;
  const int s = l >> 4;
  const float* xr = x + (size_t)m * D_;
  const int kb = s * (D_ / 4);
  float acc = 0.f;
  for (int k = 0; k < D_ / 4; ++k)
    acc = fmaf(xr[kb + k], Wb[(size_t)(kb + k) * H_ + c], acc);
  acc += __shfl_xor(acc, 16);
  acc += __shfl_xor(acc, 32);
  if (l < 16) beta[(size_t)m * H_ + c] = 1.f / (1.f + expf(-acc));
}

// ---------------------------------------------------------------------------
// Delta rule, dv-split: one block per (b,h,vslice) = 32*8 = 256 blocks.
// Each block owns DVS=16 v-columns; S[128][16] lives in LDS.
// All LDS layouts padded/mapped for <=2-way bank conflicts.
// ---------------------------------------------------------------------------
__global__ __launch_bounds__(256) void delta_rule(const float* __restrict__ q,
                                                  const float* __restrict__ k,
                                                  const float* __restrict__ v,
                                                  const float* __restrict__ beta,
                                                  float* __restrict__ o) {
  __shared__ float kc[CH][132];   // 33.8 KB  k chunk (raw)
  __shared__ float qc[CH][132];   // 33.8 KB  q chunk
  __shared__ float S[DK][20];     // 10 KB    state slice
  __shared__ float Am[CH][68];    // 17.4 KB  A = strict-tril(beta_i * k_i.k_j)
  __shared__ float At[CH][68];    // 17.4 KB  attn = tril(qscale * q_i.k_j)
  __shared__ float uu[CH][20];    // 5 KB     u (rows x 16 cols)
  __shared__ float betac[CH];

  const int bh = blockIdx.x >> 3;
  const int vs = blockIdx.x & 7;
  const int b = bh >> 4;
  const int h = bh & 15;
  const int t = threadIdx.x;
  const float qscale = 0.08838834764831845f;  // 128^-0.5

  {
    float* Sf = &S[0][0];
    for (int i = t; i < DK * 20; i += 256) Sf[i] = 0.f;
  }

  const size_t rowbase = ((size_t)b * T_) * D_ + (size_t)h * DK;
  const size_t vcol = rowbase + (size_t)vs * DVS;

  // load mapping
  const int lr = t >> 5;           // 0..7 (+p*8)
  const int lc = (t & 31) * 4;     // 0..124
  // A/attn mapping (strided rows: i = ti+16a, j = tj+16b -> 2-way banks)
  const int ti = t >> 4;           // 0..15
  const int tj = t & 15;           // 0..15
  // u0 / o mapping
  const int ur = t >> 2;           // 0..63
  const int ue0 = (t & 3) * 4;     // 0,4,8,12
  // S-update mapping
  const int sd0 = (t >> 3) * 4;    // 0..124
  const int se0 = (t & 7) * 2;     // 0..14

  for (int c0 = 0; c0 < T_; c0 += CH) {
    __syncthreads();  // prev S-update / o-phase done before kc/qc overwrite
#pragma unroll
    for (int p = 0; p < 8; ++p) {
      const int r = lr + p * 8;
      const size_t g = rowbase + (size_t)(c0 + r) * D_ + lc;
      *reinterpret_cast<float4*>(&kc[r][lc]) = *reinterpret_cast<const float4*>(&k[g]);
      *reinterpret_cast<float4*>(&qc[r][lc]) = *reinterpret_cast<const float4*>(&q[g]);
    }
    if (t < CH) betac[t] = beta[((size_t)b * T_ + c0 + t) * H_ + h];
    __syncthreads();

    {  // fused A + attn (full 64x64, mask on write)
      float accA[4][4], accQ[4][4];
#pragma unroll
      for (int a = 0; a < 4; ++a)
#pragma unroll
        for (int c = 0; c < 4; ++c) { accA[a][c] = 0.f; accQ[a][c] = 0.f; }
      for (int d = 0; d < DK; d += 4) {
        float4 kj[4], ai[4], qi[4];
#pragma unroll
        for (int c = 0; c < 4; ++c) {
          kj[c] = *reinterpret_cast<float4*>(&kc[tj + 16 * c][d]);
          ai[c] = *reinterpret_cast<float4*>(&kc[ti + 16 * c][d]);
          qi[c] = *reinterpret_cast<float4*>(&qc[ti + 16 * c][d]);
        }
#pragma unroll
        for (int a = 0; a < 4; ++a)
#pragma unroll
          for (int c = 0; c < 4; ++c) {
            accA[a][c] += ai[a].x * kj[c].x + ai[a].y * kj[c].y +
                          ai[a].z * kj[c].z + ai[a].w * kj[c].w;
            accQ[a][c] += qi[a].x * kj[c].x + qi[a].y * kj[c].y +
                          qi[a].z * kj[c].z + qi[a].w * kj[c].w;
          }
      }
#pragma unroll
      for (int a = 0; a < 4; ++a)
#pragma unroll
        for (int c = 0; c < 4; ++c) {
          const int i = ti + 16 * a, j = tj + 16 * c;
          Am[i][j] = (j < i) ? betac[i] * accA[a][c] : 0.f;
          At[i][j] = (j <= i) ? qscale * accQ[a][c] : 0.f;
        }
    }

    {  // u0[r][e] = beta[r]*(v[r][e] - sum_d k[r][d]*S[d][e])
      const float4 vv = *reinterpret_cast<const float4*>(&v[vcol + (size_t)(c0 + ur) * D_ + ue0]);
      float a0 = vv.x, a1 = vv.y, a2 = vv.z, a3 = vv.w;
      for (int d = 0; d < DK; d += 4) {
        const float4 kr = *reinterpret_cast<float4*>(&kc[ur][d]);
        const float4 s0 = *reinterpret_cast<float4*>(&S[d][ue0]);
        const float4 s1 = *reinterpret_cast<float4*>(&S[d + 1][ue0]);
        const float4 s2 = *reinterpret_cast<float4*>(&S[d + 2][ue0]);
        const float4 s3 = *reinterpret_cast<float4*>(&S[d + 3][ue0]);
        a0 -= kr.x * s0.x + kr.y * s1.x + kr.z * s2.x + kr.w * s3.x;
        a1 -= kr.x * s0.y + kr.y * s1.y + kr.z * s2.y + kr.w * s3.y;
        a2 -= kr.x * s0.z + kr.y * s1.z + kr.z * s2.z + kr.w * s3.z;
        a3 -= kr.x * s0.w + kr.y * s1.w + kr.z * s2.w + kr.w * s3.w;
      }
      const float bb = betac[ur];
      *reinterpret_cast<float4*>(&uu[ur][ue0]) =
          make_float4(bb * a0, bb * a1, bb * a2, bb * a3);
    }
    __syncthreads();  // Am, uu ready

    // blocked forward substitution: 4 blocks of 16 rows
#pragma unroll 1
    for (int blk = 0; blk < 4; ++blk) {
      const int R0 = blk << 4;
      if (blk > 0) {  // u[R0+ri] -= A[R0+ri][0:R0] @ u[0:R0]
        const int ri = t >> 4, e = t & 15;
        float s = 0.f;
        for (int j = 0; j < R0; ++j) s = fmaf(Am[R0 + ri][j], uu[j][e], s);
        uu[R0 + ri][e] -= s;
      }
      __syncthreads();
      if (t < 16) {  // 16x16 unit-lower triangle solve, column t in registers
        float ue[16];
#pragma unroll
        for (int i = 0; i < 16; ++i) ue[i] = uu[R0 + i][t];
#pragma unroll
        for (int i = 1; i < 16; ++i) {
          float s = 0.f;
#pragma unroll
          for (int j = 0; j < i; ++j) s = fmaf(Am[R0 + i][R0 + j], ue[j], s);
          ue[i] -= s;
        }
#pragma unroll
        for (int i = 1; i < 16; ++i) uu[R0 + i][t] = ue[i];
      }
      __syncthreads();
    }

    {  // o = qscale*(q @ S) + attn @ u
      float a0 = 0.f, a1 = 0.f, a2 = 0.f, a3 = 0.f;
      for (int d = 0; d < DK; d += 4) {
        const float4 qr = *reinterpret_cast<float4*>(&qc[ur][d]);
        const float4 s0 = *reinterpret_cast<float4*>(&S[d][ue0]);
        const float4 s1 = *reinterpret_cast<float4*>(&S[d + 1][ue0]);
        const float4 s2 = *reinterpret_cast<float4*>(&S[d + 2][ue0]);
        const float4 s3 = *reinterpret_cast<float4*>(&S[d + 3][ue0]);
        a0 += qr.x * s0.x + qr.y * s1.x + qr.z * s2.x + qr.w * s3.x;
        a1 += qr.x * s0.y + qr.y * s1.y + qr.z * s2.y + qr.w * s3.y;
        a2 += qr.x * s0.z + qr.y * s1.z + qr.z * s2.z + qr.w * s3.z;
        a3 += qr.x * s0.w + qr.y * s1.w + qr.z * s2.w + qr.w * s3.w;
      }
      a0 *= qscale; a1 *= qscale; a2 *= qscale; a3 *= qscale;
      const int mhi = ((t >> 6) + 1) * 16;  // wave-uniform causal bound (> ur)
      for (int m = 0; m < mhi; ++m) {
        const float am = At[ur][m];
        const float4 um = *reinterpret_cast<float4*>(&uu[m][ue0]);
        a0 = fmaf(am, um.x, a0);
        a1 = fmaf(am, um.y, a1);
        a2 = fmaf(am, um.z, a2);
        a3 = fmaf(am, um.w, a3);
      }
      *reinterpret_cast<float4*>(&o[vcol + (size_t)(c0 + ur) * D_ + ue0]) =
          make_float4(a0, a1, a2, a3);
    }
    __syncthreads();  // all S reads done before update

    {  // S[d][e] += sum_m k[m][d] * u[m][e]
      float acc[4][2];
#pragma unroll
      for (int dd = 0; dd < 4; ++dd) { acc[dd][0] = 0.f; acc[dd][1] = 0.f; }
      for (int m = 0; m < CH; ++m) {
        const float4 km = *reinterpret_cast<float4*>(&kc[m][sd0]);
        const float u0_ = uu[m][se0];
        const float u1_ = uu[m][se0 + 1];
        acc[0][0] = fmaf(km.x, u0_, acc[0][0]); acc[0][1] = fmaf(km.x, u1_, acc[0][1]);
        acc[1][0] = fmaf(km.y, u0_, acc[1][0]); acc[1][1] = fmaf(km.y, u1_, acc[1][1]);
        acc[2][0] = fmaf(km.z, u0_, acc[2][0]); acc[2][1] = fmaf(km.z, u1_, acc[2][1]);
        acc[3][0] = fmaf(km.w, u0_, acc[3][0]); acc[3][1] = fmaf(km.w, u1_, acc[3][1]);
      }
#pragma unroll
      for (int dd = 0; dd < 4; ++dd) {
        S[sd0 + dd][se0] += acc[dd][0];
        S[sd0 + dd][se0 + 1] += acc[dd][1];
      }
    }
  }
}

// ---------------------------------------------------------------------------
// per-head RMSNorm (over 128) * onorm_w, in-place.
// ---------------------------------------------------------------------------
__global__ __launch_bounds__(256) void rms_onorm(float* __restrict__ io,
                                                 const float* __restrict__ w) {
  const int bt = blockIdx.x;
  const int d0 = threadIdx.x * 8;
  float* p = io + (size_t)bt * D_ + d0;
  const float4 a = *reinterpret_cast<float4*>(p);
  const float4 b = *reinterpret_cast<float4*>(p + 4);
  float v[8] = {a.x, a.y, a.z, a.w, b.x, b.y, b.z, b.w};
  float ss = 0.f;
#pragma unroll
  for (int j = 0; j < 8; ++j) ss = fmaf(v[j], v[j], ss);
  ss += __shfl_xor(ss, 1);
  ss += __shfl_xor(ss, 2);
  ss += __shfl_xor(ss, 4);
  ss += __shfl_xor(ss, 8);
  const float sc = rsqrtf(ss * (1.0f / 128.0f) + 1e-5f);
  const int hd = d0 & 127;
#pragma unroll
  for (int j = 0; j < 8; ++j) v[j] *= sc * w[hd + j];
  *reinterpret_cast<float4*>(p) = make_float4(v[0], v[1], v[2], v[3]);
  *reinterpret_cast<float4*>(p + 4) = make_float4(v[4], v[5], v[6], v[7]);
}

// ---------------------------------------------------------------------------
extern "C" void kernel_launch(void* const* d_in, const int* in_sizes, int n_in,
                              void* d_out, int out_size, void* d_ws, size_t ws_size,
                              hipStream_t stream) {
  const float* x  = (const float*)d_in[0];
  const float* Wq = (const float*)d_in[1];
  const float* Wk = (const float*)d_in[2];
  const float* Wv = (const float*)d_in[3];
  const float* Wb = (const float*)d_in[4];
  const float* Wo = (const float*)d_in[5];
  const float* cq = (const float*)d_in[6];
  const float* ck = (const float*)d_in[7];
  const float* cv = (const float*)d_in[8];
  const float* ow = (const float*)d_in[9];
  float* out = (float*)d_out;

  const size_t NE = (size_t)M_ * D_;
  float* raw   = (float*)d_ws;      // [M,D] scratch (gemm out, later o)
  float* qb    = raw + NE;          // [M,D]
  float* kb    = qb + NE;           // [M,D]
  float* betab = kb + NE;           // [M,H]
  float* vb    = out;               // v lives in d_out until final GEMM

  dim3 gg(D_ / 128, M_ / 128);
  gemm_f32<<<gg, 256, 0, stream>>>(x, Wq, raw, M_, D_, D_);
  conv_silu<<<M_, 256, 0, stream>>>(raw, cq, qb, 1);
  gemm_f32<<<gg, 256, 0, stream>>>(x, Wk, raw, M_, D_, D_);
  conv_silu<<<M_, 256, 0, stream>>>(raw, ck, kb, 1);
  gemm_f32<<<gg, 256, 0, stream>>>(x, Wv, raw, M_, D_, D_);
  conv_silu<<<M_, 256, 0, stream>>>(raw, cv, vb, 0);
  beta_sigmoid<<<M_ / 4, 256, 0, stream>>>(x, Wb, betab);
  delta_rule<<<B_ * H_ * 8, 256, 0, stream>>>(qb, kb, vb, betab, raw);
  rms_onorm<<<M_, 256, 0, stream>>>(raw, ow);
  gemm_f32<<<gg, 256, 0, stream>>>(raw, Wo, out, M_, D_, D_);
}

// Round 4
// 1457.810 us; speedup vs baseline: 7.1751x; 3.4286x over previous
//
#include <hip/hip_runtime.h>
#include <math.h>

#define B_ 2
#define T_ 4096
#define D_ 2048
#define H_ 16
#define DK 128
#define DV 128
#define CH 64
#define M_ (B_ * T_)  // 8192
#define NCH (T_ / CH) // 64 chunks

typedef __attribute__((ext_vector_type(8))) short bfrag;   // 8 bf16
typedef __attribute__((ext_vector_type(4))) float ffrag;   // 4 f32 acc

__device__ inline unsigned short f2bf(float f) {
  union { float f; unsigned u; } v; v.f = f;
  unsigned r = v.u + 0x7fffu + ((v.u >> 16) & 1u);
  return (unsigned short)(r >> 16);
}
__device__ inline float bf2f(unsigned short u) {
  union { unsigned u; float f; } v; v.u = ((unsigned)u) << 16;
  return v.f;
}

// ---------------------------------------------------------------------------
// transpose + convert: Wt[n][k] = bf16(W[k][n]), 64x64 tiles
// ---------------------------------------------------------------------------
__global__ __launch_bounds__(256) void wtrans(const float* __restrict__ W,
                                              unsigned short* __restrict__ Wt) {
  __shared__ float tile[64][68];
  const int k0 = blockIdx.y * 64, n0 = blockIdx.x * 64;
  const int lr = threadIdx.x >> 4, lc = (threadIdx.x & 15) * 4;
#pragma unroll
  for (int p = 0; p < 4; ++p) {
    const int r = lr + p * 16;
    *reinterpret_cast<float4*>(&tile[r][lc]) =
        *reinterpret_cast<const float4*>(&W[(size_t)(k0 + r) * D_ + n0 + lc]);
  }
  __syncthreads();
#pragma unroll
  for (int p = 0; p < 4; ++p) {
    const int r = lr + p * 16;
    ushort4 o;
    o.x = f2bf(tile[lc + 0][r]); o.y = f2bf(tile[lc + 1][r]);
    o.z = f2bf(tile[lc + 2][r]); o.w = f2bf(tile[lc + 3][r]);
    *reinterpret_cast<ushort4*>(&Wt[(size_t)(n0 + r) * D_ + k0 + lc]) = o;
  }
}

// ---------------------------------------------------------------------------
// bf16 MFMA GEMM: C[M,N] = A[M,K] @ Bt[N,K]^T (bf16). A may be f32 (converted
// during staging). 128x128 tile, BK=32, 4 waves, 4x4 16x16x32 frags/wave.
// LDS row stride 40 shorts -> <=2-way banks on b128 frag reads.
// ---------------------------------------------------------------------------
template <bool AF32, bool OUTF32>
__global__ __launch_bounds__(256) void gemm_bf16(const void* __restrict__ Ap,
                                                 const unsigned short* __restrict__ Bt,
                                                 void* __restrict__ Cp,
                                                 int M, int N, int K) {
  __shared__ __align__(16) unsigned short As[128 * 40];
  __shared__ __align__(16) unsigned short Bs[128 * 40];
  const int t = threadIdx.x, l = t & 63, w = t >> 6;
  const int m0 = blockIdx.y * 128, n0 = blockIdx.x * 128;
  const int wr = w >> 1, wc = w & 1;
  const int sr = t >> 2;            // staging row 0..63 (+64 second pass)
  const int sp = (t & 3) * 8;       // staging k-part (8 bf16)
  const int fr = l & 15, fs = (l >> 4) * 8;

  ffrag acc[4][4];
#pragma unroll
  for (int mi = 0; mi < 4; ++mi)
#pragma unroll
    for (int ni = 0; ni < 4; ++ni)
#pragma unroll
      for (int e = 0; e < 4; ++e) acc[mi][ni][e] = 0.f;

  for (int k0 = 0; k0 < K; k0 += 32) {
    bfrag a0, a1;
    if constexpr (AF32) {
      const float* Af = (const float*)Ap;
      const float* p0 = Af + (size_t)(m0 + sr) * K + k0 + sp;
      const float* p1 = Af + (size_t)(m0 + sr + 64) * K + k0 + sp;
      const float4 x0 = *reinterpret_cast<const float4*>(p0);
      const float4 x1 = *reinterpret_cast<const float4*>(p0 + 4);
      const float4 y0 = *reinterpret_cast<const float4*>(p1);
      const float4 y1 = *reinterpret_cast<const float4*>(p1 + 4);
      a0[0] = (short)f2bf(x0.x); a0[1] = (short)f2bf(x0.y);
      a0[2] = (short)f2bf(x0.z); a0[3] = (short)f2bf(x0.w);
      a0[4] = (short)f2bf(x1.x); a0[5] = (short)f2bf(x1.y);
      a0[6] = (short)f2bf(x1.z); a0[7] = (short)f2bf(x1.w);
      a1[0] = (short)f2bf(y0.x); a1[1] = (short)f2bf(y0.y);
      a1[2] = (short)f2bf(y0.z); a1[3] = (short)f2bf(y0.w);
      a1[4] = (short)f2bf(y1.x); a1[5] = (short)f2bf(y1.y);
      a1[6] = (short)f2bf(y1.z); a1[7] = (short)f2bf(y1.w);
    } else {
      const unsigned short* Ab = (const unsigned short*)Ap;
      a0 = *reinterpret_cast<const bfrag*>(Ab + (size_t)(m0 + sr) * K + k0 + sp);
      a1 = *reinterpret_cast<const bfrag*>(Ab + (size_t)(m0 + sr + 64) * K + k0 + sp);
    }
    const bfrag b0 = *reinterpret_cast<const bfrag*>(Bt + (size_t)(n0 + sr) * K + k0 + sp);
    const bfrag b1 = *reinterpret_cast<const bfrag*>(Bt + (size_t)(n0 + sr + 64) * K + k0 + sp);
    __syncthreads();  // previous iter's frag reads done
    *reinterpret_cast<bfrag*>(As + sr * 40 + sp) = a0;
    *reinterpret_cast<bfrag*>(As + (sr + 64) * 40 + sp) = a1;
    *reinterpret_cast<bfrag*>(Bs + sr * 40 + sp) = b0;
    *reinterpret_cast<bfrag*>(Bs + (sr + 64) * 40 + sp) = b1;
    __syncthreads();
    bfrag af[4], bfr[4];
#pragma unroll
    for (int mi = 0; mi < 4; ++mi)
      af[mi] = *reinterpret_cast<const bfrag*>(As + (wr * 64 + mi * 16 + fr) * 40 + fs);
#pragma unroll
    for (int ni = 0; ni < 4; ++ni)
      bfr[ni] = *reinterpret_cast<const bfrag*>(Bs + (wc * 64 + ni * 16 + fr) * 40 + fs);
#pragma unroll
    for (int mi = 0; mi < 4; ++mi)
#pragma unroll
      for (int ni = 0; ni < 4; ++ni)
        acc[mi][ni] = __builtin_amdgcn_mfma_f32_16x16x32_bf16(af[mi], bfr[ni], acc[mi][ni], 0, 0, 0);
  }
  const int cr = (l >> 4) * 4, cc = l & 15;
#pragma unroll
  for (int mi = 0; mi < 4; ++mi)
#pragma unroll
    for (int ni = 0; ni < 4; ++ni)
#pragma unroll
      for (int j = 0; j < 4; ++j) {
        const size_t idx = (size_t)(m0 + wr * 64 + mi * 16 + cr + j) * N +
                           n0 + wc * 64 + ni * 16 + cc;
        if constexpr (OUTF32) ((float*)Cp)[idx] = acc[mi][ni][j];
        else ((unsigned short*)Cp)[idx] = f2bf(acc[mi][ni][j]);
      }
}

// ---------------------------------------------------------------------------
// Causal shared-kernel conv (K=4) + silu; bf16 in/out.
// mode: 0=none, 1=l2norm, 2=l2norm*qscale
// ---------------------------------------------------------------------------
__global__ __launch_bounds__(256) void conv_silu_bf16(const unsigned short* __restrict__ in,
                                                      const float* __restrict__ cw,
                                                      unsigned short* __restrict__ out,
                                                      int mode) {
  const int bt = blockIdx.x;
  const int tb = bt & (T_ - 1);
  const int d0 = threadIdx.x * 8;
  const unsigned short* row = in + (size_t)bt * D_ + d0;
  float v[8];
#pragma unroll
  for (int j = 0; j < 8; ++j) v[j] = 0.f;
#pragma unroll
  for (int j = 0; j < 4; ++j) {
    if (tb >= j) {
      const unsigned short* rp = row - (size_t)(j * D_);
      const ushort4 a = *reinterpret_cast<const ushort4*>(rp);
      const ushort4 b = *reinterpret_cast<const ushort4*>(rp + 4);
      const float wj = cw[3 - j];
      v[0] = fmaf(wj, bf2f(a.x), v[0]); v[1] = fmaf(wj, bf2f(a.y), v[1]);
      v[2] = fmaf(wj, bf2f(a.z), v[2]); v[3] = fmaf(wj, bf2f(a.w), v[3]);
      v[4] = fmaf(wj, bf2f(b.x), v[4]); v[5] = fmaf(wj, bf2f(b.y), v[5]);
      v[6] = fmaf(wj, bf2f(b.z), v[6]); v[7] = fmaf(wj, bf2f(b.w), v[7]);
    }
  }
#pragma unroll
  for (int j = 0; j < 8; ++j) v[j] = v[j] / (1.f + expf(-v[j]));
  if (mode) {
    float ss = 0.f;
#pragma unroll
    for (int j = 0; j < 8; ++j) ss = fmaf(v[j], v[j], ss);
    ss += __shfl_xor(ss, 1);
    ss += __shfl_xor(ss, 2);
    ss += __shfl_xor(ss, 4);
    ss += __shfl_xor(ss, 8);
    float sc = rsqrtf(ss + 1e-6f);
    if (mode == 2) sc *= 0.08838834764831845f;  // 128^-0.5
#pragma unroll
    for (int j = 0; j < 8; ++j) v[j] *= sc;
  }
  ushort4 o0, o1;
  o0.x = f2bf(v[0]); o0.y = f2bf(v[1]); o0.z = f2bf(v[2]); o0.w = f2bf(v[3]);
  o1.x = f2bf(v[4]); o1.y = f2bf(v[5]); o1.z = f2bf(v[6]); o1.w = f2bf(v[7]);
  unsigned short* op = out + (size_t)bt * D_ + d0;
  *reinterpret_cast<ushort4*>(op) = o0;
  *reinterpret_cast<ushort4*>(op + 4) = o1;
}

// ---------------------------------------------------------------------------
// beta = sigmoid(x @ Wb), Wb [D,16].
// ---------------------------------------------------------------------------
__global__ __launch_bounds__(256) void beta_sigmoid(const float* __restrict__ x,
                                                    const float* __restrict__ Wb,
                                                    float* __restrict__ beta) {
  const int t = threadIdx.x;
  const int m = blockIdx.x * 4 + (t >> 6);
  const int l = t & 63;
  const int c = l & 15;
  const int s = l >> 4;
  const float* xr = x + (size_t)m * D_;
  const int kb = s * (D_ / 4);
  float acc = 0.f;
  for (int k = 0; k < D_ / 4; ++k)
    acc = fmaf(xr[kb + k], Wb[(size_t)(kb + k) * H_ + c], acc);
  acc += __shfl_xor(acc, 16);
  acc += __shfl_xor(acc, 32);
  if (l < 16) beta[(size_t)m * H_ + c] = 1.f / (1.f + expf(-acc));
}

// ---------------------------------------------------------------------------
// delta_prep: one block per (b,h,chunk) = 2048 blocks, 256 threads.
// In: q,k,v bf16. Out: attn bf16 (chunk layout), W = M^-1(beta*k) bf16 (chunk
// layout), u_v = M^-1(beta*v) bf16 (o-layout [M,D]).
// fwd-sub column-private: thread t owns column t of [W | u_v].
// ---------------------------------------------------------------------------
__global__ __launch_bounds__(256) void delta_prep(const unsigned short* __restrict__ q,
                                                  const unsigned short* __restrict__ k,
                                                  const unsigned short* __restrict__ v,
                                                  const float* __restrict__ beta,
                                                  unsigned short* __restrict__ Wout,
                                                  unsigned short* __restrict__ UVout,
                                                  unsigned short* __restrict__ Aout) {
  __shared__ float kc[CH][132];     // 33.8 KB
  __shared__ float qc[CH][132];     // 33.8 KB
  __shared__ float Am[CH][68];      // 17.4 KB
  __shared__ float uvw[CH][264];    // 67.6 KB : cols 0..127 = W, 128..255 = u_v
  __shared__ float betac[CH];

  const int bx = blockIdx.x;
  const int bh = bx >> 6, cid = bx & 63;
  const int b = bh >> 4, h = bh & 15;
  const int t = threadIdx.x;
  const size_t rowbase = ((size_t)b * T_ + (size_t)cid * CH) * D_ + (size_t)h * DK;

  {  // load k,q chunk (bf16 -> f32 LDS) + beta
    const int lr = t >> 5, lc = (t & 31) * 4;
#pragma unroll
    for (int p = 0; p < 8; ++p) {
      const int r = lr + p * 8;
      const size_t g = rowbase + (size_t)r * D_ + lc;
      const ushort4 kv = *reinterpret_cast<const ushort4*>(&k[g]);
      const ushort4 qv = *reinterpret_cast<const ushort4*>(&q[g]);
      *reinterpret_cast<float4*>(&kc[r][lc]) =
          make_float4(bf2f(kv.x), bf2f(kv.y), bf2f(kv.z), bf2f(kv.w));
      *reinterpret_cast<float4*>(&qc[r][lc]) =
          make_float4(bf2f(qv.x), bf2f(qv.y), bf2f(qv.z), bf2f(qv.w));
    }
    if (t < CH) betac[t] = beta[((size_t)b * T_ + (size_t)cid * CH + t) * H_ + h];
  }
  __syncthreads();

  {  // A (-> Am LDS) + attn (-> global bf16), fused
    const int ti = t >> 4, tj = t & 15;
    float accA[4][4], accQ[4][4];
#pragma unroll
    for (int a = 0; a < 4; ++a)
#pragma unroll
      for (int c = 0; c < 4; ++c) { accA[a][c] = 0.f; accQ[a][c] = 0.f; }
    for (int d = 0; d < DK; d += 4) {
      float4 kj[4], ai[4], qi[4];
#pragma unroll
      for (int c = 0; c < 4; ++c) {
        kj[c] = *reinterpret_cast<float4*>(&kc[tj + 16 * c][d]);
        ai[c] = *reinterpret_cast<float4*>(&kc[ti + 16 * c][d]);
        qi[c] = *reinterpret_cast<float4*>(&qc[ti + 16 * c][d]);
      }
#pragma unroll
      for (int a = 0; a < 4; ++a)
#pragma unroll
        for (int c = 0; c < 4; ++c) {
          accA[a][c] += ai[a].x * kj[c].x + ai[a].y * kj[c].y +
                        ai[a].z * kj[c].z + ai[a].w * kj[c].w;
          accQ[a][c] += qi[a].x * kj[c].x + qi[a].y * kj[c].y +
                        qi[a].z * kj[c].z + qi[a].w * kj[c].w;
        }
    }
    const size_t abase = (size_t)bx * (CH * CH);
#pragma unroll
    for (int a = 0; a < 4; ++a)
#pragma unroll
      for (int c = 0; c < 4; ++c) {
        const int i = ti + 16 * a, j = tj + 16 * c;
        Am[i][j] = (j < i) ? betac[i] * accA[a][c] : 0.f;
        Aout[abase + i * CH + j] = f2bf((j <= i) ? accQ[a][c] : 0.f);
      }
  }

  {  // uvw init: W-half = beta*k (LDS), uv-half = beta*v (global bf16)
    for (int idx = t; idx < CH * 32; idx += 256) {
      const int r = idx >> 5, c4 = (idx & 31) * 4;
      const float bb = betac[r];
      const float4 kv = *reinterpret_cast<float4*>(&kc[r][c4]);
      *reinterpret_cast<float4*>(&uvw[r][c4]) =
          make_float4(bb * kv.x, bb * kv.y, bb * kv.z, bb * kv.w);
      const ushort4 vv = *reinterpret_cast<const ushort4*>(&v[rowbase + (size_t)r * D_ + c4]);
      *reinterpret_cast<float4*>(&uvw[r][128 + c4]) =
          make_float4(bb * bf2f(vv.x), bb * bf2f(vv.y), bb * bf2f(vv.z), bb * bf2f(vv.w));
    }
  }
  __syncthreads();  // Am + uvw ready

  {  // column-private blocked forward substitution (unit lower M = I + Am)
    float ue[16];
#pragma unroll 1
    for (int blk = 0; blk < 4; ++blk) {
      const int R0 = blk << 4;
#pragma unroll
      for (int i = 0; i < 16; ++i) ue[i] = uvw[R0 + i][t];
#pragma unroll
      for (int i = 1; i < 16; ++i) {
        float s = 0.f;
#pragma unroll
        for (int j = 0; j < i; ++j) s = fmaf(Am[R0 + i][R0 + j], ue[j], s);
        ue[i] -= s;
      }
#pragma unroll
      for (int i = 1; i < 16; ++i) uvw[R0 + i][t] = ue[i];
      for (int i = R0 + 16; i < CH; ++i) {  // right-looking update
        const float4 a0 = *reinterpret_cast<float4*>(&Am[i][R0]);
        const float4 a1 = *reinterpret_cast<float4*>(&Am[i][R0 + 4]);
        const float4 a2 = *reinterpret_cast<float4*>(&Am[i][R0 + 8]);
        const float4 a3 = *reinterpret_cast<float4*>(&Am[i][R0 + 12]);
        float s = a0.x * ue[0] + a0.y * ue[1] + a0.z * ue[2] + a0.w * ue[3];
        s += a1.x * ue[4] + a1.y * ue[5] + a1.z * ue[6] + a1.w * ue[7];
        s += a2.x * ue[8] + a2.y * ue[9] + a2.z * ue[10] + a2.w * ue[11];
        s += a3.x * ue[12] + a3.y * ue[13] + a3.z * ue[14] + a3.w * ue[15];
        uvw[i][t] -= s;
      }
    }
  }
  __syncthreads();

  {  // write W (chunk layout) and u_v (o-layout), both bf16
    const size_t obase = (size_t)bx * (CH * DK);
    for (int idx = t; idx < CH * 32; idx += 256) {
      const int r = idx >> 5, c4 = (idx & 31) * 4;
      const float4 wv = *reinterpret_cast<float4*>(&uvw[r][c4]);
      ushort4 wo;
      wo.x = f2bf(wv.x); wo.y = f2bf(wv.y); wo.z = f2bf(wv.z); wo.w = f2bf(wv.w);
      *reinterpret_cast<ushort4*>(&Wout[obase + r * DK + c4]) = wo;
      const float4 uv = *reinterpret_cast<float4*>(&uvw[r][128 + c4]);
      ushort4 uo;
      uo.x = f2bf(uv.x); uo.y = f2bf(uv.y); uo.z = f2bf(uv.z); uo.w = f2bf(uv.w);
      *reinterpret_cast<ushort4*>(&UVout[rowbase + (size_t)r * D_ + c4]) = uo;
    }
  }
}

// ---------------------------------------------------------------------------
// delta_seq: sequential S-recurrence. 256 blocks; vs = bid>>5, bh = bid&31
// (8 siblings sharing (b,h) are 32 apart -> same XCD under round-robin).
// Per chunk: u = u_v - W.S ; o = q.S + attn.u (in place over u_v); S += k^T.u
// ---------------------------------------------------------------------------
__global__ __launch_bounds__(256) void delta_seq(const unsigned short* __restrict__ q,
                                                 const unsigned short* __restrict__ k,
                                                 const unsigned short* __restrict__ Wbuf,
                                                 const unsigned short* __restrict__ Abuf,
                                                 unsigned short* __restrict__ uv_o) {
  __shared__ float Wc[CH][132];    // 33.8 KB
  __shared__ float qcs[CH][132];   // 33.8 KB
  __shared__ float kcs[CH][132];   // 33.8 KB
  __shared__ float attc[CH][68];   // 17.4 KB
  __shared__ float S[DK][20];      // 10 KB
  __shared__ float uu[CH][20];     // 5 KB

  const int bx = blockIdx.x;
  const int vs = bx >> 5, bh = bx & 31;
  const int b = bh >> 4, h = bh & 15;
  const int t = threadIdx.x;

  {
    float* Sf = &S[0][0];
    for (int i = t; i < DK * 20; i += 256) Sf[i] = 0.f;
  }

  const size_t rowbase0 = ((size_t)b * T_) * D_ + (size_t)h * DK;
  const int lr = t >> 5, lc = (t & 31) * 4;
  const int ur = t >> 2, ue0 = (t & 3) * 4;
  const int sd0 = (t >> 3) * 4, se0 = (t & 7) * 2;

  for (int cid = 0; cid < NCH; ++cid) {
    const size_t rowbase = rowbase0 + (size_t)cid * CH * D_;
    const size_t pbase = (size_t)(bh * NCH + cid) * (CH * DK);
    const size_t abase = (size_t)(bh * NCH + cid) * (CH * CH);
    __syncthreads();  // prior chunk's reads complete before restage
    {  // stage q, k (bf16 -> f32)
#pragma unroll
      for (int p = 0; p < 8; ++p) {
        const int r = lr + p * 8;
        const size_t g = rowbase + (size_t)r * D_ + lc;
        const ushort4 qv = *reinterpret_cast<const ushort4*>(&q[g]);
        const ushort4 kv = *reinterpret_cast<const ushort4*>(&k[g]);
        *reinterpret_cast<float4*>(&qcs[r][lc]) =
            make_float4(bf2f(qv.x), bf2f(qv.y), bf2f(qv.z), bf2f(qv.w));
        *reinterpret_cast<float4*>(&kcs[r][lc]) =
            make_float4(bf2f(kv.x), bf2f(kv.y), bf2f(kv.z), bf2f(kv.w));
      }
      // stage W (bf16 chunk layout -> f32)
#pragma unroll
      for (int p = 0; p < 8; ++p) {
        const int off = (t + p * 256) * 4;
        const ushort4 wv = *reinterpret_cast<const ushort4*>(&Wbuf[pbase + off]);
        *reinterpret_cast<float4*>(&Wc[off >> 7][off & 127]) =
            make_float4(bf2f(wv.x), bf2f(wv.y), bf2f(wv.z), bf2f(wv.w));
      }
      // stage attn (bf16 -> f32)
#pragma unroll
      for (int p = 0; p < 4; ++p) {
        const int off = (t + p * 256) * 4;
        const ushort4 u4 = *reinterpret_cast<const ushort4*>(&Abuf[abase + off]);
        *reinterpret_cast<float4*>(&attc[off >> 6][off & 63]) =
            make_float4(bf2f(u4.x), bf2f(u4.y), bf2f(u4.z), bf2f(u4.w));
      }
      // stage u_v slice (bf16 o-layout -> f32)
      const ushort4 uvv = *reinterpret_cast<const ushort4*>(
          &uv_o[rowbase + (size_t)ur * D_ + vs * 16 + ue0]);
      *reinterpret_cast<float4*>(&uu[ur][ue0]) =
          make_float4(bf2f(uvv.x), bf2f(uvv.y), bf2f(uvv.z), bf2f(uvv.w));
    }
    __syncthreads();

    {  // u -= W.S
      float4 a = *reinterpret_cast<float4*>(&uu[ur][ue0]);
      for (int d = 0; d < DK; d += 4) {
        const float4 wr4 = *reinterpret_cast<float4*>(&Wc[ur][d]);
        const float4 s0 = *reinterpret_cast<float4*>(&S[d][ue0]);
        const float4 s1 = *reinterpret_cast<float4*>(&S[d + 1][ue0]);
        const float4 s2 = *reinterpret_cast<float4*>(&S[d + 2][ue0]);
        const float4 s3 = *reinterpret_cast<float4*>(&S[d + 3][ue0]);
        a.x -= wr4.x * s0.x + wr4.y * s1.x + wr4.z * s2.x + wr4.w * s3.x;
        a.y -= wr4.x * s0.y + wr4.y * s1.y + wr4.z * s2.y + wr4.w * s3.y;
        a.z -= wr4.x * s0.z + wr4.y * s1.z + wr4.z * s2.z + wr4.w * s3.z;
        a.w -= wr4.x * s0.w + wr4.y * s1.w + wr4.z * s2.w + wr4.w * s3.w;
      }
      *reinterpret_cast<float4*>(&uu[ur][ue0]) = a;
    }
    __syncthreads();  // u ready

    {  // o = q.S + attn.u -> write bf16 in place over u_v
      float a0 = 0.f, a1 = 0.f, a2 = 0.f, a3 = 0.f;
      for (int d = 0; d < DK; d += 4) {
        const float4 qr = *reinterpret_cast<float4*>(&qcs[ur][d]);
        const float4 s0 = *reinterpret_cast<float4*>(&S[d][ue0]);
        const float4 s1 = *reinterpret_cast<float4*>(&S[d + 1][ue0]);
        const float4 s2 = *reinterpret_cast<float4*>(&S[d + 2][ue0]);
        const float4 s3 = *reinterpret_cast<float4*>(&S[d + 3][ue0]);
        a0 += qr.x * s0.x + qr.y * s1.x + qr.z * s2.x + qr.w * s3.x;
        a1 += qr.x * s0.y + qr.y * s1.y + qr.z * s2.y + qr.w * s3.y;
        a2 += qr.x * s0.z + qr.y * s1.z + qr.z * s2.z + qr.w * s3.z;
        a3 += qr.x * s0.w + qr.y * s1.w + qr.z * s2.w + qr.w * s3.w;
      }
      const int mhi = ((t >> 6) + 1) * 16;  // wave-uniform causal bound (> ur)
      for (int m = 0; m < mhi; ++m) {
        const float am = attc[ur][m];
        const float4 um = *reinterpret_cast<float4*>(&uu[m][ue0]);
        a0 = fmaf(am, um.x, a0);
        a1 = fmaf(am, um.y, a1);
        a2 = fmaf(am, um.z, a2);
        a3 = fmaf(am, um.w, a3);
      }
      ushort4 ov;
      ov.x = f2bf(a0); ov.y = f2bf(a1); ov.z = f2bf(a2); ov.w = f2bf(a3);
      *reinterpret_cast<ushort4*>(&uv_o[rowbase + (size_t)ur * D_ + vs * 16 + ue0]) = ov;
    }
    __syncthreads();  // all S reads done before update

    {  // S += k^T u
      float acc[4][2];
#pragma unroll
      for (int dd = 0; dd < 4; ++dd) { acc[dd][0] = 0.f; acc[dd][1] = 0.f; }
      for (int m = 0; m < CH; ++m) {
        const float4 km = *reinterpret_cast<float4*>(&kcs[m][sd0]);
        const float u0_ = uu[m][se0];
        const float u1_ = uu[m][se0 + 1];
        acc[0][0] = fmaf(km.x, u0_, acc[0][0]); acc[0][1] = fmaf(km.x, u1_, acc[0][1]);
        acc[1][0] = fmaf(km.y, u0_, acc[1][0]); acc[1][1] = fmaf(km.y, u1_, acc[1][1]);
        acc[2][0] = fmaf(km.z, u0_, acc[2][0]); acc[2][1] = fmaf(km.z, u1_, acc[2][1]);
        acc[3][0] = fmaf(km.w, u0_, acc[3][0]); acc[3][1] = fmaf(km.w, u1_, acc[3][1]);
      }
#pragma unroll
      for (int dd = 0; dd < 4; ++dd) {
        S[sd0 + dd][se0] += acc[dd][0];
        S[sd0 + dd][se0 + 1] += acc[dd][1];
      }
    }
  }
}

// ---------------------------------------------------------------------------
// per-head RMSNorm (over 128) * onorm_w, bf16 in-place.
// ---------------------------------------------------------------------------
__global__ __launch_bounds__(256) void rms_onorm_bf16(unsigned short* __restrict__ io,
                                                      const float* __restrict__ w) {
  const int bt = blockIdx.x;
  const int d0 = threadIdx.x * 8;
  unsigned short* p = io + (size_t)bt * D_ + d0;
  const ushort4 a = *reinterpret_cast<ushort4*>(p);
  const ushort4 b = *reinterpret_cast<ushort4*>(p + 4);
  float v[8] = {bf2f(a.x), bf2f(a.y), bf2f(a.z), bf2f(a.w),
                bf2f(b.x), bf2f(b.y), bf2f(b.z), bf2f(b.w)};
  float ss = 0.f;
#pragma unroll
  for (int j = 0; j < 8; ++j) ss = fmaf(v[j], v[j], ss);
  ss += __shfl_xor(ss, 1);
  ss += __shfl_xor(ss, 2);
  ss += __shfl_xor(ss, 4);
  ss += __shfl_xor(ss, 8);
  const float sc = rsqrtf(ss * (1.0f / 128.0f) + 1e-5f);
  const int hd = d0 & 127;
  ushort4 o0, o1;
  o0.x = f2bf(v[0] * sc * w[hd + 0]); o0.y = f2bf(v[1] * sc * w[hd + 1]);
  o0.z = f2bf(v[2] * sc * w[hd + 2]); o0.w = f2bf(v[3] * sc * w[hd + 3]);
  o1.x = f2bf(v[4] * sc * w[hd + 4]); o1.y = f2bf(v[5] * sc * w[hd + 5]);
  o1.z = f2bf(v[6] * sc * w[hd + 6]); o1.w = f2bf(v[7] * sc * w[hd + 7]);
  *reinterpret_cast<ushort4*>(p) = o0;
  *reinterpret_cast<ushort4*>(p + 4) = o1;
}

// ---------------------------------------------------------------------------
extern "C" void kernel_launch(void* const* d_in, const int* in_sizes, int n_in,
                              void* d_out, int out_size, void* d_ws, size_t ws_size,
                              hipStream_t stream) {
  const float* x  = (const float*)d_in[0];
  const float* Wq = (const float*)d_in[1];
  const float* Wk = (const float*)d_in[2];
  const float* Wv = (const float*)d_in[3];
  const float* Wb = (const float*)d_in[4];
  const float* Wo = (const float*)d_in[5];
  const float* cq = (const float*)d_in[6];
  const float* ck = (const float*)d_in[7];
  const float* cv = (const float*)d_in[8];
  const float* ow = (const float*)d_in[9];
  float* out = (float*)d_out;

  // workspace layout (bf16-resident; 193.5 MB total < 201.8 MB proven floor)
  const size_t NE = (size_t)M_ * D_;  // 16.78M elems
  unsigned short* gout = (unsigned short*)d_ws;        // [M,D]   GEMM out scratch
  unsigned short* qb   = gout + NE;                    // [M,D]   q (post conv/norm/qscale)
  unsigned short* kb2  = qb + NE;                      // [M,D]   k
  unsigned short* Wbuf = kb2 + NE;                     // [2048][64][128] W
  unsigned short* uvb  = Wbuf + NE;                    // [M,D]   u_v -> o (in place)
  unsigned short* attb = uvb + NE;                     // [2048][64][64]
  unsigned short* wt   = attb + (size_t)2048 * CH * CH;// [D,D]   W^T (reused 4x)
  float* betab = (float*)(wt + (size_t)D_ * D_);       // [M,H]
  unsigned short* vb = (unsigned short*)d_out;         // v bf16, dead before final GEMM

  dim3 gg(D_ / 128, M_ / 128);
  dim3 wg(D_ / 64, D_ / 64);

  wtrans<<<wg, 256, 0, stream>>>(Wq, wt);
  gemm_bf16<true, false><<<gg, 256, 0, stream>>>(x, wt, gout, M_, D_, D_);
  conv_silu_bf16<<<M_, 256, 0, stream>>>(gout, cq, qb, 2);

  wtrans<<<wg, 256, 0, stream>>>(Wk, wt);
  gemm_bf16<true, false><<<gg, 256, 0, stream>>>(x, wt, gout, M_, D_, D_);
  conv_silu_bf16<<<M_, 256, 0, stream>>>(gout, ck, kb2, 1);

  wtrans<<<wg, 256, 0, stream>>>(Wv, wt);
  gemm_bf16<true, false><<<gg, 256, 0, stream>>>(x, wt, gout, M_, D_, D_);
  conv_silu_bf16<<<M_, 256, 0, stream>>>(gout, cv, vb, 0);

  beta_sigmoid<<<M_ / 4, 256, 0, stream>>>(x, Wb, betab);

  delta_prep<<<32 * NCH, 256, 0, stream>>>(qb, kb2, vb, betab, Wbuf, uvb, attb);
  delta_seq<<<256, 256, 0, stream>>>(qb, kb2, Wbuf, attb, uvb);

  rms_onorm_bf16<<<M_, 256, 0, stream>>>(uvb, ow);

  wtrans<<<wg, 256, 0, stream>>>(Wo, wt);
  gemm_bf16<false, true><<<gg, 256, 0, stream>>>(uvb, wt, out, M_, D_, D_);
}

// Round 5
// 1385.411 us; speedup vs baseline: 7.5501x; 1.0523x over previous
//
#include <hip/hip_runtime.h>
#include <math.h>

#define B_ 2
#define T_ 4096
#define D_ 2048
#define H_ 16
#define DK 128
#define DV 128
#define CH 64
#define M_ (B_ * T_)  // 8192
#define NCH (T_ / CH) // 64 chunks

typedef __attribute__((ext_vector_type(8))) short bfrag;   // 8 bf16
typedef __attribute__((ext_vector_type(4))) float ffrag;   // 4 f32 acc
typedef __attribute__((ext_vector_type(8))) unsigned short u16x8;

__device__ inline unsigned short f2bf(float f) {
  union { float f; unsigned u; } v; v.f = f;
  unsigned r = v.u + 0x7fffu + ((v.u >> 16) & 1u);
  return (unsigned short)(r >> 16);
}
__device__ inline float bf2f(unsigned short u) {
  union { unsigned u; float f; } v; v.u = ((unsigned)u) << 16;
  return v.f;
}

// async global->LDS, 16B per lane (dest = wave-uniform base + lane*16)
__device__ inline void gl_lds16(const unsigned short* g, unsigned short* l) {
  __builtin_amdgcn_global_load_lds(
      (const __attribute__((address_space(1))) void*)g,
      (__attribute__((address_space(3))) void*)l, 16, 0, 0);
}

// ---------------------------------------------------------------------------
// flat f32 -> bf16 (8 elems/thread)
// ---------------------------------------------------------------------------
__global__ __launch_bounds__(256) void to_bf16(const float* __restrict__ in,
                                               unsigned short* __restrict__ out) {
  const size_t i = ((size_t)blockIdx.x * 256 + threadIdx.x) * 8;
  const float4 a = *reinterpret_cast<const float4*>(in + i);
  const float4 b = *reinterpret_cast<const float4*>(in + i + 4);
  ushort4 o0, o1;
  o0.x = f2bf(a.x); o0.y = f2bf(a.y); o0.z = f2bf(a.z); o0.w = f2bf(a.w);
  o1.x = f2bf(b.x); o1.y = f2bf(b.y); o1.z = f2bf(b.z); o1.w = f2bf(b.w);
  *reinterpret_cast<ushort4*>(out + i) = o0;
  *reinterpret_cast<ushort4*>(out + i + 4) = o1;
}

// ---------------------------------------------------------------------------
// transpose + convert: Wt[n][k] = bf16(W[k][n]), 64x64 tiles
// ---------------------------------------------------------------------------
__global__ __launch_bounds__(256) void wtrans(const float* __restrict__ W,
                                              unsigned short* __restrict__ Wt) {
  __shared__ float tile[64][68];
  const int k0 = blockIdx.y * 64, n0 = blockIdx.x * 64;
  const int lr = threadIdx.x >> 4, lc = (threadIdx.x & 15) * 4;
#pragma unroll
  for (int p = 0; p < 4; ++p) {
    const int r = lr + p * 16;
    *reinterpret_cast<float4*>(&tile[r][lc]) =
        *reinterpret_cast<const float4*>(&W[(size_t)(k0 + r) * D_ + n0 + lc]);
  }
  __syncthreads();
#pragma unroll
  for (int p = 0; p < 4; ++p) {
    const int r = lr + p * 16;
    ushort4 o;
    o.x = f2bf(tile[lc + 0][r]); o.y = f2bf(tile[lc + 1][r]);
    o.z = f2bf(tile[lc + 2][r]); o.w = f2bf(tile[lc + 3][r]);
    *reinterpret_cast<ushort4*>(&Wt[(size_t)(n0 + r) * D_ + k0 + lc]) = o;
  }
}

// ---------------------------------------------------------------------------
// bf16 MFMA GEMM (m97 structure): C[M,N] = A[M,K] @ Bt[N,K]^T, both bf16.
// 128x128 tile, BK=32, 4 waves, 4x4 16x16x32 frags. global_load_lds width=16,
// linear LDS [128][32].
// ---------------------------------------------------------------------------
template <bool OUTF32>
__global__ __launch_bounds__(256) void gemm_bf16(const unsigned short* __restrict__ A,
                                                 const unsigned short* __restrict__ Bt,
                                                 void* __restrict__ Cp,
                                                 int M, int N, int K) {
  __shared__ __align__(16) unsigned short As[128 * 32];
  __shared__ __align__(16) unsigned short Bs[128 * 32];
  const int t = threadIdx.x, l = t & 63, w = t >> 6;
  const int m0 = blockIdx.y * 128, n0 = blockIdx.x * 128;
  const int wr = w >> 1, wc = w & 1;
  const int sr = t >> 2, sp = (t & 3) * 8;  // staging: row, k-offset (8 bf16)
  const int fr = l & 15, fs = (l >> 4) * 8;

  ffrag acc[4][4];
#pragma unroll
  for (int mi = 0; mi < 4; ++mi)
#pragma unroll
    for (int ni = 0; ni < 4; ++ni)
#pragma unroll
      for (int e = 0; e < 4; ++e) acc[mi][ni][e] = 0.f;

  const unsigned short* Ag0 = A + (size_t)(m0 + sr) * K + sp;
  const unsigned short* Ag1 = A + (size_t)(m0 + sr + 64) * K + sp;
  const unsigned short* Bg0 = Bt + (size_t)(n0 + sr) * K + sp;
  const unsigned short* Bg1 = Bt + (size_t)(n0 + sr + 64) * K + sp;
  unsigned short* Al0 = As + sr * 32 + sp;
  unsigned short* Al1 = As + (sr + 64) * 32 + sp;
  unsigned short* Bl0 = Bs + sr * 32 + sp;
  unsigned short* Bl1 = Bs + (sr + 64) * 32 + sp;

  for (int k0 = 0; k0 < K; k0 += 32) {
    __syncthreads();  // prior iter's frag reads retired before LDS overwrite
    gl_lds16(Ag0 + k0, Al0);
    gl_lds16(Ag1 + k0, Al1);
    gl_lds16(Bg0 + k0, Bl0);
    gl_lds16(Bg1 + k0, Bl1);
    __syncthreads();  // compiler drains vmcnt before barrier -> LDS ready
    bfrag af[4], bfr[4];
#pragma unroll
    for (int mi = 0; mi < 4; ++mi)
      af[mi] = *reinterpret_cast<const bfrag*>(As + (wr * 64 + mi * 16 + fr) * 32 + fs);
#pragma unroll
    for (int ni = 0; ni < 4; ++ni)
      bfr[ni] = *reinterpret_cast<const bfrag*>(Bs + (wc * 64 + ni * 16 + fr) * 32 + fs);
#pragma unroll
    for (int mi = 0; mi < 4; ++mi)
#pragma unroll
      for (int ni = 0; ni < 4; ++ni)
        acc[mi][ni] = __builtin_amdgcn_mfma_f32_16x16x32_bf16(af[mi], bfr[ni], acc[mi][ni], 0, 0, 0);
  }
  const int cr = (l >> 4) * 4, cc = l & 15;
#pragma unroll
  for (int mi = 0; mi < 4; ++mi)
#pragma unroll
    for (int ni = 0; ni < 4; ++ni)
#pragma unroll
      for (int j = 0; j < 4; ++j) {
        const size_t idx = (size_t)(m0 + wr * 64 + mi * 16 + cr + j) * N +
                           n0 + wc * 64 + ni * 16 + cc;
        if constexpr (OUTF32) ((float*)Cp)[idx] = acc[mi][ni][j];
        else ((unsigned short*)Cp)[idx] = f2bf(acc[mi][ni][j]);
      }
}

// ---------------------------------------------------------------------------
// Causal shared-kernel conv (K=4) + silu; bf16 in/out.
// mode: 0=none, 1=l2norm, 2=l2norm*qscale
// ---------------------------------------------------------------------------
__global__ __launch_bounds__(256) void conv_silu_bf16(const unsigned short* __restrict__ in,
                                                      const float* __restrict__ cw,
                                                      unsigned short* __restrict__ out,
                                                      int mode) {
  const int bt = blockIdx.x;
  const int tb = bt & (T_ - 1);
  const int d0 = threadIdx.x * 8;
  const unsigned short* row = in + (size_t)bt * D_ + d0;
  float v[8];
#pragma unroll
  for (int j = 0; j < 8; ++j) v[j] = 0.f;
#pragma unroll
  for (int j = 0; j < 4; ++j) {
    if (tb >= j) {
      const unsigned short* rp = row - (size_t)(j * D_);
      const ushort4 a = *reinterpret_cast<const ushort4*>(rp);
      const ushort4 b = *reinterpret_cast<const ushort4*>(rp + 4);
      const float wj = cw[3 - j];
      v[0] = fmaf(wj, bf2f(a.x), v[0]); v[1] = fmaf(wj, bf2f(a.y), v[1]);
      v[2] = fmaf(wj, bf2f(a.z), v[2]); v[3] = fmaf(wj, bf2f(a.w), v[3]);
      v[4] = fmaf(wj, bf2f(b.x), v[4]); v[5] = fmaf(wj, bf2f(b.y), v[5]);
      v[6] = fmaf(wj, bf2f(b.z), v[6]); v[7] = fmaf(wj, bf2f(b.w), v[7]);
    }
  }
#pragma unroll
  for (int j = 0; j < 8; ++j) v[j] = v[j] / (1.f + expf(-v[j]));
  if (mode) {
    float ss = 0.f;
#pragma unroll
    for (int j = 0; j < 8; ++j) ss = fmaf(v[j], v[j], ss);
    ss += __shfl_xor(ss, 1);
    ss += __shfl_xor(ss, 2);
    ss += __shfl_xor(ss, 4);
    ss += __shfl_xor(ss, 8);
    float sc = rsqrtf(ss + 1e-6f);
    if (mode == 2) sc *= 0.08838834764831845f;  // 128^-0.5
#pragma unroll
    for (int j = 0; j < 8; ++j) v[j] *= sc;
  }
  ushort4 o0, o1;
  o0.x = f2bf(v[0]); o0.y = f2bf(v[1]); o0.z = f2bf(v[2]); o0.w = f2bf(v[3]);
  o1.x = f2bf(v[4]); o1.y = f2bf(v[5]); o1.z = f2bf(v[6]); o1.w = f2bf(v[7]);
  unsigned short* op = out + (size_t)bt * D_ + d0;
  *reinterpret_cast<ushort4*>(op) = o0;
  *reinterpret_cast<ushort4*>(op + 4) = o1;
}

// ---------------------------------------------------------------------------
// beta = sigmoid(x @ Wb), Wb [D,16].
// ---------------------------------------------------------------------------
__global__ __launch_bounds__(256) void beta_sigmoid(const float* __restrict__ x,
                                                    const float* __restrict__ Wb,
                                                    float* __restrict__ beta) {
  const int t = threadIdx.x;
  const int m = blockIdx.x * 4 + (t >> 6);
  const int l = t & 63;
  const int c = l & 15;
  const int s = l >> 4;
  const float* xr = x + (size_t)m * D_;
  const int kb = s * (D_ / 4);
  float acc = 0.f;
  for (int k = 0; k < D_ / 4; ++k)
    acc = fmaf(xr[kb + k], Wb[(size_t)(kb + k) * H_ + c], acc);
  acc += __shfl_xor(acc, 16);
  acc += __shfl_xor(acc, 32);
  if (l < 16) beta[(size_t)m * H_ + c] = 1.f / (1.f + expf(-acc));
}

// ---------------------------------------------------------------------------
// delta_prep: one block per (b,h,chunk) = 2048 blocks, 256 threads.
// Outputs: attn bf16 (chunk layout), W = M^-1(beta*k) bf16 (chunk layout),
// u_v = M^-1(beta*v) bf16 (o-layout [M,D]).
// ---------------------------------------------------------------------------
__global__ __launch_bounds__(256) void delta_prep(const unsigned short* __restrict__ q,
                                                  const unsigned short* __restrict__ k,
                                                  const unsigned short* __restrict__ v,
                                                  const float* __restrict__ beta,
                                                  unsigned short* __restrict__ Wout,
                                                  unsigned short* __restrict__ UVout,
                                                  unsigned short* __restrict__ Aout) {
  __shared__ float kc[CH][132];     // 33.8 KB
  __shared__ float qc[CH][132];     // 33.8 KB
  __shared__ float Am[CH][68];      // 17.4 KB
  __shared__ float uvw[CH][264];    // 67.6 KB : cols 0..127 = W, 128..255 = u_v
  __shared__ float betac[CH];

  const int bx = blockIdx.x;
  const int bh = bx >> 6, cid = bx & 63;
  const int b = bh >> 4, h = bh & 15;
  const int t = threadIdx.x;
  const size_t rowbase = ((size_t)b * T_ + (size_t)cid * CH) * D_ + (size_t)h * DK;

  {  // load k,q chunk (bf16 -> f32 LDS) + beta
    const int lr = t >> 5, lc = (t & 31) * 4;
#pragma unroll
    for (int p = 0; p < 8; ++p) {
      const int r = lr + p * 8;
      const size_t g = rowbase + (size_t)r * D_ + lc;
      const ushort4 kv = *reinterpret_cast<const ushort4*>(&k[g]);
      const ushort4 qv = *reinterpret_cast<const ushort4*>(&q[g]);
      *reinterpret_cast<float4*>(&kc[r][lc]) =
          make_float4(bf2f(kv.x), bf2f(kv.y), bf2f(kv.z), bf2f(kv.w));
      *reinterpret_cast<float4*>(&qc[r][lc]) =
          make_float4(bf2f(qv.x), bf2f(qv.y), bf2f(qv.z), bf2f(qv.w));
    }
    if (t < CH) betac[t] = beta[((size_t)b * T_ + (size_t)cid * CH + t) * H_ + h];
  }
  __syncthreads();

  {  // A (-> Am LDS) + attn (-> global bf16), fused
    const int ti = t >> 4, tj = t & 15;
    float accA[4][4], accQ[4][4];
#pragma unroll
    for (int a = 0; a < 4; ++a)
#pragma unroll
      for (int c = 0; c < 4; ++c) { accA[a][c] = 0.f; accQ[a][c] = 0.f; }
    for (int d = 0; d < DK; d += 4) {
      float4 kj[4], ai[4], qi[4];
#pragma unroll
      for (int c = 0; c < 4; ++c) {
        kj[c] = *reinterpret_cast<float4*>(&kc[tj + 16 * c][d]);
        ai[c] = *reinterpret_cast<float4*>(&kc[ti + 16 * c][d]);
        qi[c] = *reinterpret_cast<float4*>(&qc[ti + 16 * c][d]);
      }
#pragma unroll
      for (int a = 0; a < 4; ++a)
#pragma unroll
        for (int c = 0; c < 4; ++c) {
          accA[a][c] += ai[a].x * kj[c].x + ai[a].y * kj[c].y +
                        ai[a].z * kj[c].z + ai[a].w * kj[c].w;
          accQ[a][c] += qi[a].x * kj[c].x + qi[a].y * kj[c].y +
                        qi[a].z * kj[c].z + qi[a].w * kj[c].w;
        }
    }
    const size_t abase = (size_t)bx * (CH * CH);
#pragma unroll
    for (int a = 0; a < 4; ++a)
#pragma unroll
      for (int c = 0; c < 4; ++c) {
        const int i = ti + 16 * a, j = tj + 16 * c;
        Am[i][j] = (j < i) ? betac[i] * accA[a][c] : 0.f;
        Aout[abase + i * CH + j] = f2bf((j <= i) ? accQ[a][c] : 0.f);
      }
  }

  {  // uvw init: W-half = beta*k (LDS), uv-half = beta*v (global bf16)
    for (int idx = t; idx < CH * 32; idx += 256) {
      const int r = idx >> 5, c4 = (idx & 31) * 4;
      const float bb = betac[r];
      const float4 kv = *reinterpret_cast<float4*>(&kc[r][c4]);
      *reinterpret_cast<float4*>(&uvw[r][c4]) =
          make_float4(bb * kv.x, bb * kv.y, bb * kv.z, bb * kv.w);
      const ushort4 vv = *reinterpret_cast<const ushort4*>(&v[rowbase + (size_t)r * D_ + c4]);
      *reinterpret_cast<float4*>(&uvw[r][128 + c4]) =
          make_float4(bb * bf2f(vv.x), bb * bf2f(vv.y), bb * bf2f(vv.z), bb * bf2f(vv.w));
    }
  }
  __syncthreads();  // Am + uvw ready

  {  // column-private blocked forward substitution (unit lower M = I + Am)
    float ue[16];
#pragma unroll 1
    for (int blk = 0; blk < 4; ++blk) {
      const int R0 = blk << 4;
#pragma unroll
      for (int i = 0; i < 16; ++i) ue[i] = uvw[R0 + i][t];
#pragma unroll
      for (int i = 1; i < 16; ++i) {
        float s = 0.f;
#pragma unroll
        for (int j = 0; j < i; ++j) s = fmaf(Am[R0 + i][R0 + j], ue[j], s);
        ue[i] -= s;
      }
#pragma unroll
      for (int i = 1; i < 16; ++i) uvw[R0 + i][t] = ue[i];
      for (int i = R0 + 16; i < CH; ++i) {  // right-looking update
        const float4 a0 = *reinterpret_cast<float4*>(&Am[i][R0]);
        const float4 a1 = *reinterpret_cast<float4*>(&Am[i][R0 + 4]);
        const float4 a2 = *reinterpret_cast<float4*>(&Am[i][R0 + 8]);
        const float4 a3 = *reinterpret_cast<float4*>(&Am[i][R0 + 12]);
        float s = a0.x * ue[0] + a0.y * ue[1] + a0.z * ue[2] + a0.w * ue[3];
        s += a1.x * ue[4] + a1.y * ue[5] + a1.z * ue[6] + a1.w * ue[7];
        s += a2.x * ue[8] + a2.y * ue[9] + a2.z * ue[10] + a2.w * ue[11];
        s += a3.x * ue[12] + a3.y * ue[13] + a3.z * ue[14] + a3.w * ue[15];
        uvw[i][t] -= s;
      }
    }
  }
  __syncthreads();

  {  // write W (chunk layout) and u_v (o-layout), both bf16
    const size_t obase = (size_t)bx * (CH * DK);
    for (int idx = t; idx < CH * 32; idx += 256) {
      const int r = idx >> 5, c4 = (idx & 31) * 4;
      const float4 wv = *reinterpret_cast<float4*>(&uvw[r][c4]);
      ushort4 wo;
      wo.x = f2bf(wv.x); wo.y = f2bf(wv.y); wo.z = f2bf(wv.z); wo.w = f2bf(wv.w);
      *reinterpret_cast<ushort4*>(&Wout[obase + r * DK + c4]) = wo;
      const float4 uv = *reinterpret_cast<float4*>(&uvw[r][128 + c4]);
      ushort4 uo;
      uo.x = f2bf(uv.x); uo.y = f2bf(uv.y); uo.z = f2bf(uv.z); uo.w = f2bf(uv.w);
      *reinterpret_cast<ushort4*>(&UVout[rowbase + (size_t)r * D_ + c4]) = uo;
    }
  }
}

// ---------------------------------------------------------------------------
// delta_seq: sequential S-recurrence. 256 blocks x 512 threads (8 waves).
// T14 async-STAGE: next chunk's q/k/W/attn/uv loaded to regs during compute,
// written to LDS at loop top. uv stays register-resident per thread.
// ---------------------------------------------------------------------------
__global__ __launch_bounds__(512) void delta_seq(const unsigned short* __restrict__ q,
                                                 const unsigned short* __restrict__ k,
                                                 const unsigned short* __restrict__ Wbuf,
                                                 const unsigned short* __restrict__ Abuf,
                                                 unsigned short* __restrict__ uv_o) {
  __shared__ float Wc[CH][132];    // 33.8 KB
  __shared__ float qcs[CH][132];   // 33.8 KB
  __shared__ float kcs[CH][132];   // 33.8 KB
  __shared__ float attc[CH][68];   // 17.4 KB
  __shared__ float S[DK][20];      // 10 KB
  __shared__ float uu[CH][20];     // 5 KB

  const int bx = blockIdx.x;
  const int vs = bx >> 5, bh = bx & 31;
  const int b = bh >> 4, h = bh & 15;
  const int t = threadIdx.x;

  {
    float* Sf = &S[0][0];
    for (int i = t; i < DK * 20; i += 512) Sf[i] = 0.f;
  }

  const size_t rowbase0 = ((size_t)b * T_) * D_ + (size_t)h * DK;
  const int sr = t >> 3;          // staging/compute row 0..63
  const int sc = (t & 7) * 16;    // q/k/W col (16 bf16)
  const int ac = (t & 7) * 8;     // attn col (8 bf16)
  const int ue0 = (t & 7) * 2;    // u col pair (within 16-slice)
  const int sd0 = (t >> 4) * 4;   // S-update d rows (0..124)
  const int se = t & 15;          // S-update e col

  u16x8 qv0, qv1, kv0, kv1, wv0, wv1, av;
  ushort2 uvv_cur, uvv_nxt;

  {  // prologue: load chunk 0 into regs
    const size_t g = rowbase0 + (size_t)sr * D_ + sc;
    qv0 = *reinterpret_cast<const u16x8*>(q + g);
    qv1 = *reinterpret_cast<const u16x8*>(q + g + 8);
    kv0 = *reinterpret_cast<const u16x8*>(k + g);
    kv1 = *reinterpret_cast<const u16x8*>(k + g + 8);
    const size_t pb = (size_t)(bh * NCH) * (CH * DK) + (size_t)sr * DK + sc;
    wv0 = *reinterpret_cast<const u16x8*>(Wbuf + pb);
    wv1 = *reinterpret_cast<const u16x8*>(Wbuf + pb + 8);
    av = *reinterpret_cast<const u16x8*>(Abuf + (size_t)(bh * NCH) * (CH * CH) +
                                         (size_t)sr * CH + ac);
    uvv_cur = *reinterpret_cast<const ushort2*>(uv_o + rowbase0 + (size_t)sr * D_ +
                                                vs * 16 + ue0);
  }
  uvv_nxt = uvv_cur;

  for (int cid = 0; cid < NCH; ++cid) {
    {  // write staged regs -> LDS (f32)
#pragma unroll
      for (int g4 = 0; g4 < 2; ++g4) {
        const u16x8 qv = g4 ? qv1 : qv0;
        const u16x8 kv = g4 ? kv1 : kv0;
        const u16x8 wv = g4 ? wv1 : wv0;
        const int c = sc + g4 * 8;
        *reinterpret_cast<float4*>(&qcs[sr][c]) =
            make_float4(bf2f(qv[0]), bf2f(qv[1]), bf2f(qv[2]), bf2f(qv[3]));
        *reinterpret_cast<float4*>(&qcs[sr][c + 4]) =
            make_float4(bf2f(qv[4]), bf2f(qv[5]), bf2f(qv[6]), bf2f(qv[7]));
        *reinterpret_cast<float4*>(&kcs[sr][c]) =
            make_float4(bf2f(kv[0]), bf2f(kv[1]), bf2f(kv[2]), bf2f(kv[3]));
        *reinterpret_cast<float4*>(&kcs[sr][c + 4]) =
            make_float4(bf2f(kv[4]), bf2f(kv[5]), bf2f(kv[6]), bf2f(kv[7]));
        *reinterpret_cast<float4*>(&Wc[sr][c]) =
            make_float4(bf2f(wv[0]), bf2f(wv[1]), bf2f(wv[2]), bf2f(wv[3]));
        *reinterpret_cast<float4*>(&Wc[sr][c + 4]) =
            make_float4(bf2f(wv[4]), bf2f(wv[5]), bf2f(wv[6]), bf2f(wv[7]));
      }
      *reinterpret_cast<float4*>(&attc[sr][ac]) =
          make_float4(bf2f(av[0]), bf2f(av[1]), bf2f(av[2]), bf2f(av[3]));
      *reinterpret_cast<float4*>(&attc[sr][ac + 4]) =
          make_float4(bf2f(av[4]), bf2f(av[5]), bf2f(av[6]), bf2f(av[7]));
    }
    __syncthreads();

    if (cid + 1 < NCH) {  // prefetch next chunk (loads in flight over compute)
      const size_t rowb = rowbase0 + (size_t)(cid + 1) * CH * D_;
      const size_t g = rowb + (size_t)sr * D_ + sc;
      qv0 = *reinterpret_cast<const u16x8*>(q + g);
      qv1 = *reinterpret_cast<const u16x8*>(q + g + 8);
      kv0 = *reinterpret_cast<const u16x8*>(k + g);
      kv1 = *reinterpret_cast<const u16x8*>(k + g + 8);
      const size_t pb = (size_t)(bh * NCH + cid + 1) * (CH * DK) + (size_t)sr * DK + sc;
      wv0 = *reinterpret_cast<const u16x8*>(Wbuf + pb);
      wv1 = *reinterpret_cast<const u16x8*>(Wbuf + pb + 8);
      av = *reinterpret_cast<const u16x8*>(Abuf + (size_t)(bh * NCH + cid + 1) * (CH * CH) +
                                           (size_t)sr * CH + ac);
      uvv_nxt = *reinterpret_cast<const ushort2*>(uv_o + rowb + (size_t)sr * D_ +
                                                  vs * 16 + ue0);
    }

    {  // u[sr][ue0..+1] = uv - W[sr,:].S[:,ue0..+1]
      float a0 = bf2f(uvv_cur.x), a1 = bf2f(uvv_cur.y);
      for (int d = 0; d < DK; d += 4) {
        const float4 wr4 = *reinterpret_cast<float4*>(&Wc[sr][d]);
        const float2 s0 = *reinterpret_cast<float2*>(&S[d][ue0]);
        const float2 s1 = *reinterpret_cast<float2*>(&S[d + 1][ue0]);
        const float2 s2 = *reinterpret_cast<float2*>(&S[d + 2][ue0]);
        const float2 s3 = *reinterpret_cast<float2*>(&S[d + 3][ue0]);
        a0 -= wr4.x * s0.x + wr4.y * s1.x + wr4.z * s2.x + wr4.w * s3.x;
        a1 -= wr4.x * s0.y + wr4.y * s1.y + wr4.z * s2.y + wr4.w * s3.y;
      }
      *reinterpret_cast<float2*>(&uu[sr][ue0]) = make_float2(a0, a1);
    }
    __syncthreads();  // u ready

    {  // o = q.S + attn.u -> global bf16 (in place over u_v slice)
      float a0 = 0.f, a1 = 0.f;
      for (int d = 0; d < DK; d += 4) {
        const float4 qr = *reinterpret_cast<float4*>(&qcs[sr][d]);
        const float2 s0 = *reinterpret_cast<float2*>(&S[d][ue0]);
        const float2 s1 = *reinterpret_cast<float2*>(&S[d + 1][ue0]);
        const float2 s2 = *reinterpret_cast<float2*>(&S[d + 2][ue0]);
        const float2 s3 = *reinterpret_cast<float2*>(&S[d + 3][ue0]);
        a0 += qr.x * s0.x + qr.y * s1.x + qr.z * s2.x + qr.w * s3.x;
        a1 += qr.x * s0.y + qr.y * s1.y + qr.z * s2.y + qr.w * s3.y;
      }
      const int mhi = ((t >> 6) + 1) * 8;  // wave-uniform causal bound (> sr)
      for (int m = 0; m < mhi; ++m) {
        const float am = attc[sr][m];
        const float2 um = *reinterpret_cast<float2*>(&uu[m][ue0]);
        a0 = fmaf(am, um.x, a0);
        a1 = fmaf(am, um.y, a1);
      }
      ushort2 ov;
      ov.x = f2bf(a0); ov.y = f2bf(a1);
      *reinterpret_cast<ushort2*>(&uv_o[rowbase0 + (size_t)cid * CH * D_ +
                                        (size_t)sr * D_ + vs * 16 + ue0]) = ov;
    }
    __syncthreads();  // all S/uu reads done before S update

    {  // S[sd0..+3][se] += sum_m k[m][sd0..+3] * u[m][se]
      float c0 = 0.f, c1 = 0.f, c2 = 0.f, c3 = 0.f;
      for (int m = 0; m < CH; ++m) {
        const float4 km = *reinterpret_cast<float4*>(&kcs[m][sd0]);
        const float um = uu[m][se];
        c0 = fmaf(km.x, um, c0);
        c1 = fmaf(km.y, um, c1);
        c2 = fmaf(km.z, um, c2);
        c3 = fmaf(km.w, um, c3);
      }
      S[sd0 + 0][se] += c0;
      S[sd0 + 1][se] += c1;
      S[sd0 + 2][se] += c2;
      S[sd0 + 3][se] += c3;
    }
    __syncthreads();  // kcs/uu reads done before next restage
    uvv_cur = uvv_nxt;
  }
}

// ---------------------------------------------------------------------------
// per-head RMSNorm (over 128) * onorm_w, bf16 in-place.
// ---------------------------------------------------------------------------
__global__ __launch_bounds__(256) void rms_onorm_bf16(unsigned short* __restrict__ io,
                                                      const float* __restrict__ w) {
  const int bt = blockIdx.x;
  const int d0 = threadIdx.x * 8;
  unsigned short* p = io + (size_t)bt * D_ + d0;
  const ushort4 a = *reinterpret_cast<ushort4*>(p);
  const ushort4 b = *reinterpret_cast<ushort4*>(p + 4);
  float v[8] = {bf2f(a.x), bf2f(a.y), bf2f(a.z), bf2f(a.w),
                bf2f(b.x), bf2f(b.y), bf2f(b.z), bf2f(b.w)};
  float ss = 0.f;
#pragma unroll
  for (int j = 0; j < 8; ++j) ss = fmaf(v[j], v[j], ss);
  ss += __shfl_xor(ss, 1);
  ss += __shfl_xor(ss, 2);
  ss += __shfl_xor(ss, 4);
  ss += __shfl_xor(ss, 8);
  const float sc = rsqrtf(ss * (1.0f / 128.0f) + 1e-5f);
  const int hd = d0 & 127;
  ushort4 o0, o1;
  o0.x = f2bf(v[0] * sc * w[hd + 0]); o0.y = f2bf(v[1] * sc * w[hd + 1]);
  o0.z = f2bf(v[2] * sc * w[hd + 2]); o0.w = f2bf(v[3] * sc * w[hd + 3]);
  o1.x = f2bf(v[4] * sc * w[hd + 4]); o1.y = f2bf(v[5] * sc * w[hd + 5]);
  o1.z = f2bf(v[6] * sc * w[hd + 6]); o1.w = f2bf(v[7] * sc * w[hd + 7]);
  *reinterpret_cast<ushort4*>(p) = o0;
  *reinterpret_cast<ushort4*>(p + 4) = o1;
}

// ---------------------------------------------------------------------------
extern "C" void kernel_launch(void* const* d_in, const int* in_sizes, int n_in,
                              void* d_out, int out_size, void* d_ws, size_t ws_size,
                              hipStream_t stream) {
  const float* x  = (const float*)d_in[0];
  const float* Wq = (const float*)d_in[1];
  const float* Wk = (const float*)d_in[2];
  const float* Wv = (const float*)d_in[3];
  const float* Wb = (const float*)d_in[4];
  const float* Wo = (const float*)d_in[5];
  const float* cq = (const float*)d_in[6];
  const float* ck = (const float*)d_in[7];
  const float* cv = (const float*)d_in[8];
  const float* ow = (const float*)d_in[9];
  float* out = (float*)d_out;

  // workspace (193.5 MB, same proven-safe footprint as R3)
  const size_t NE = (size_t)M_ * D_;  // 16.78M elems
  unsigned short* gout = (unsigned short*)d_ws;        // [M,D]   GEMM out scratch
  unsigned short* qb   = gout + NE;                    // [M,D]   q (conv/norm/qscale)
  unsigned short* kb2  = qb + NE;                      // [M,D]   k
  unsigned short* Wbuf = kb2 + NE;                     // [2048][64][128] W
  unsigned short* uvb  = Wbuf + NE;                    // [M,D]   u_v -> o in place
  unsigned short* attb = uvb + NE;                     // [2048][64][64]
  unsigned short* wt   = attb + (size_t)2048 * CH * CH;// [D,D]   W^T (reused 4x)
  float* betab = (float*)(wt + (size_t)D_ * D_);       // [M,H]
  // d_out doubles as bf16 scratch: xb [0,NE), vb [NE,2NE) — exactly out bytes,
  // both dead before the final GEMM overwrites d_out with f32 output.
  unsigned short* xb = (unsigned short*)d_out;
  unsigned short* vb = xb + NE;

  dim3 gg(D_ / 128, M_ / 128);
  dim3 wg(D_ / 64, D_ / 64);

  to_bf16<<<NE / 2048, 256, 0, stream>>>(x, xb);

  wtrans<<<wg, 256, 0, stream>>>(Wq, wt);
  gemm_bf16<false><<<gg, 256, 0, stream>>>(xb, wt, gout, M_, D_, D_);
  conv_silu_bf16<<<M_, 256, 0, stream>>>(gout, cq, qb, 2);

  wtrans<<<wg, 256, 0, stream>>>(Wk, wt);
  gemm_bf16<false><<<gg, 256, 0, stream>>>(xb, wt, gout, M_, D_, D_);
  conv_silu_bf16<<<M_, 256, 0, stream>>>(gout, ck, kb2, 1);

  wtrans<<<wg, 256, 0, stream>>>(Wv, wt);
  gemm_bf16<false><<<gg, 256, 0, stream>>>(xb, wt, gout, M_, D_, D_);
  conv_silu_bf16<<<M_, 256, 0, stream>>>(gout, cv, vb, 0);

  beta_sigmoid<<<M_ / 4, 256, 0, stream>>>(x, Wb, betab);

  delta_prep<<<32 * NCH, 256, 0, stream>>>(qb, kb2, vb, betab, Wbuf, uvb, attb);
  delta_seq<<<256, 512, 0, stream>>>(qb, kb2, Wbuf, attb, uvb);

  rms_onorm_bf16<<<M_, 256, 0, stream>>>(uvb, ow);

  wtrans<<<wg, 256, 0, stream>>>(Wo, wt);
  gemm_bf16<true><<<gg, 256, 0, stream>>>(uvb, wt, out, M_, D_, D_);
}

// Round 6
// 958.614 us; speedup vs baseline: 10.9115x; 1.4452x over previous
//
#include <hip/hip_runtime.h>
#include <math.h>

#define B_ 2
#define T_ 4096
#define D_ 2048
#define H_ 16
#define DK 128
#define DV 128
#define CH 64
#define M_ (B_ * T_)  // 8192
#define NCH (T_ / CH) // 64 chunks

typedef __attribute__((ext_vector_type(8))) short bfrag;   // 8 bf16
typedef __attribute__((ext_vector_type(4))) float ffrag;   // 4 f32 acc
typedef __attribute__((ext_vector_type(8))) unsigned short u16x8;
typedef unsigned short us;

__device__ inline us f2bf(float f) {
  union { float f; unsigned u; } v; v.f = f;
  unsigned r = v.u + 0x7fffu + ((v.u >> 16) & 1u);
  return (us)(r >> 16);
}
__device__ inline float bf2f(us u) {
  union { unsigned u; float f; } v; v.u = ((unsigned)u) << 16;
  return v.f;
}

// async global->LDS, 16B per lane (dest = wave-uniform base + lane*16)
__device__ inline void gl_lds16(const us* g, us* l) {
  __builtin_amdgcn_global_load_lds(
      (const __attribute__((address_space(1))) void*)g,
      (__attribute__((address_space(3))) void*)l, 16, 0, 0);
}

// ---------------------------------------------------------------------------
// flat f32 -> bf16 (8 elems/thread)
// ---------------------------------------------------------------------------
__global__ __launch_bounds__(256) void to_bf16(const float* __restrict__ in,
                                               us* __restrict__ out) {
  const size_t i = ((size_t)blockIdx.x * 256 + threadIdx.x) * 8;
  const float4 a = *reinterpret_cast<const float4*>(in + i);
  const float4 b = *reinterpret_cast<const float4*>(in + i + 4);
  ushort4 o0, o1;
  o0.x = f2bf(a.x); o0.y = f2bf(a.y); o0.z = f2bf(a.z); o0.w = f2bf(a.w);
  o1.x = f2bf(b.x); o1.y = f2bf(b.y); o1.z = f2bf(b.z); o1.w = f2bf(b.w);
  *reinterpret_cast<ushort4*>(out + i) = o0;
  *reinterpret_cast<ushort4*>(out + i + 4) = o1;
}

// ---------------------------------------------------------------------------
// transpose + convert: Wt[n][k] = bf16(W[k][n]), 64x64 tiles
// ---------------------------------------------------------------------------
__global__ __launch_bounds__(256) void wtrans(const float* __restrict__ W,
                                              us* __restrict__ Wt) {
  __shared__ float tile[64][68];
  const int k0 = blockIdx.y * 64, n0 = blockIdx.x * 64;
  const int lr = threadIdx.x >> 4, lc = (threadIdx.x & 15) * 4;
#pragma unroll
  for (int p = 0; p < 4; ++p) {
    const int r = lr + p * 16;
    *reinterpret_cast<float4*>(&tile[r][lc]) =
        *reinterpret_cast<const float4*>(&W[(size_t)(k0 + r) * D_ + n0 + lc]);
  }
  __syncthreads();
#pragma unroll
  for (int p = 0; p < 4; ++p) {
    const int r = lr + p * 16;
    ushort4 o;
    o.x = f2bf(tile[lc + 0][r]); o.y = f2bf(tile[lc + 1][r]);
    o.z = f2bf(tile[lc + 2][r]); o.w = f2bf(tile[lc + 3][r]);
    *reinterpret_cast<ushort4*>(&Wt[(size_t)(n0 + r) * D_ + k0 + lc]) = o;
  }
}

// ---------------------------------------------------------------------------
// bf16 MFMA GEMM (m97 structure, proven R4): C = A @ Bt^T.
// ---------------------------------------------------------------------------
template <bool OUTF32>
__global__ __launch_bounds__(256) void gemm_bf16(const us* __restrict__ A,
                                                 const us* __restrict__ Bt,
                                                 void* __restrict__ Cp,
                                                 int M, int N, int K) {
  __shared__ __align__(16) us As[128 * 32];
  __shared__ __align__(16) us Bs[128 * 32];
  const int t = threadIdx.x, l = t & 63, w = t >> 6;
  const int m0 = blockIdx.y * 128, n0 = blockIdx.x * 128;
  const int wr = w >> 1, wc = w & 1;
  const int sr = t >> 2, sp = (t & 3) * 8;
  const int fr = l & 15, fs = (l >> 4) * 8;

  ffrag acc[4][4];
#pragma unroll
  for (int mi = 0; mi < 4; ++mi)
#pragma unroll
    for (int ni = 0; ni < 4; ++ni)
#pragma unroll
      for (int e = 0; e < 4; ++e) acc[mi][ni][e] = 0.f;

  const us* Ag0 = A + (size_t)(m0 + sr) * K + sp;
  const us* Ag1 = A + (size_t)(m0 + sr + 64) * K + sp;
  const us* Bg0 = Bt + (size_t)(n0 + sr) * K + sp;
  const us* Bg1 = Bt + (size_t)(n0 + sr + 64) * K + sp;
  us* Al0 = As + sr * 32 + sp;
  us* Al1 = As + (sr + 64) * 32 + sp;
  us* Bl0 = Bs + sr * 32 + sp;
  us* Bl1 = Bs + (sr + 64) * 32 + sp;

  for (int k0 = 0; k0 < K; k0 += 32) {
    __syncthreads();
    gl_lds16(Ag0 + k0, Al0);
    gl_lds16(Ag1 + k0, Al1);
    gl_lds16(Bg0 + k0, Bl0);
    gl_lds16(Bg1 + k0, Bl1);
    __syncthreads();
    bfrag af[4], bfr[4];
#pragma unroll
    for (int mi = 0; mi < 4; ++mi)
      af[mi] = *reinterpret_cast<const bfrag*>(As + (wr * 64 + mi * 16 + fr) * 32 + fs);
#pragma unroll
    for (int ni = 0; ni < 4; ++ni)
      bfr[ni] = *reinterpret_cast<const bfrag*>(Bs + (wc * 64 + ni * 16 + fr) * 32 + fs);
#pragma unroll
    for (int mi = 0; mi < 4; ++mi)
#pragma unroll
      for (int ni = 0; ni < 4; ++ni)
        acc[mi][ni] = __builtin_amdgcn_mfma_f32_16x16x32_bf16(af[mi], bfr[ni], acc[mi][ni], 0, 0, 0);
  }
  const int cr = (l >> 4) * 4, cc = l & 15;
#pragma unroll
  for (int mi = 0; mi < 4; ++mi)
#pragma unroll
    for (int ni = 0; ni < 4; ++ni)
#pragma unroll
      for (int j = 0; j < 4; ++j) {
        const size_t idx = (size_t)(m0 + wr * 64 + mi * 16 + cr + j) * N +
                           n0 + wc * 64 + ni * 16 + cc;
        if constexpr (OUTF32) ((float*)Cp)[idx] = acc[mi][ni][j];
        else ((us*)Cp)[idx] = f2bf(acc[mi][ni][j]);
      }
}

// ---------------------------------------------------------------------------
// conv+silu -> plain [M,D] bf16 (for v)
// ---------------------------------------------------------------------------
__device__ inline void conv_body(const us* __restrict__ in, const float* cw,
                                 int bt, int d0, int mode, float v[8]) {
  const int tb = bt & (T_ - 1);
  const us* row = in + (size_t)bt * D_ + d0;
#pragma unroll
  for (int j = 0; j < 8; ++j) v[j] = 0.f;
#pragma unroll
  for (int j = 0; j < 4; ++j) {
    if (tb >= j) {
      const us* rp = row - (size_t)(j * D_);
      const ushort4 a = *reinterpret_cast<const ushort4*>(rp);
      const ushort4 b = *reinterpret_cast<const ushort4*>(rp + 4);
      const float wj = cw[3 - j];
      v[0] = fmaf(wj, bf2f(a.x), v[0]); v[1] = fmaf(wj, bf2f(a.y), v[1]);
      v[2] = fmaf(wj, bf2f(a.z), v[2]); v[3] = fmaf(wj, bf2f(a.w), v[3]);
      v[4] = fmaf(wj, bf2f(b.x), v[4]); v[5] = fmaf(wj, bf2f(b.y), v[5]);
      v[6] = fmaf(wj, bf2f(b.z), v[6]); v[7] = fmaf(wj, bf2f(b.w), v[7]);
    }
  }
#pragma unroll
  for (int j = 0; j < 8; ++j) v[j] = v[j] / (1.f + expf(-v[j]));
  if (mode) {
    float ss = 0.f;
#pragma unroll
    for (int j = 0; j < 8; ++j) ss = fmaf(v[j], v[j], ss);
    ss += __shfl_xor(ss, 1);
    ss += __shfl_xor(ss, 2);
    ss += __shfl_xor(ss, 4);
    ss += __shfl_xor(ss, 8);
    float sc = rsqrtf(ss + 1e-6f);
    if (mode == 2) sc *= 0.08838834764831845f;  // 128^-0.5
#pragma unroll
    for (int j = 0; j < 8; ++j) v[j] *= sc;
  }
}

__global__ __launch_bounds__(256) void conv_silu_plain(const us* __restrict__ in,
                                                       const float* __restrict__ cw,
                                                       us* __restrict__ out) {
  const int bt = blockIdx.x, d0 = threadIdx.x * 8;
  float v[8];
  conv_body(in, cw, bt, d0, 0, v);
  ushort4 o0, o1;
  o0.x = f2bf(v[0]); o0.y = f2bf(v[1]); o0.z = f2bf(v[2]); o0.w = f2bf(v[3]);
  o1.x = f2bf(v[4]); o1.y = f2bf(v[5]); o1.z = f2bf(v[6]); o1.w = f2bf(v[7]);
  us* op = out + (size_t)bt * D_ + d0;
  *reinterpret_cast<ushort4*>(op) = o0;
  *reinterpret_cast<ushort4*>(op + 4) = o1;
}

// conv+silu+l2norm -> swizzled chunk layout [bh][cid][64][128], 16B-group XOR(r&15)
__global__ __launch_bounds__(256) void conv_silu_chunk(const us* __restrict__ in,
                                                       const float* __restrict__ cw,
                                                       us* __restrict__ out,
                                                       int mode) {
  const int bt = blockIdx.x, d0 = threadIdx.x * 8;
  float v[8];
  conv_body(in, cw, bt, d0, mode, v);
  const int b = bt >> 12, tt = bt & (T_ - 1);
  const int cid = tt >> 6, r = tt & 63;
  const int h = d0 >> 7, g = (d0 & 127) >> 3;
  us* dst = out + ((size_t)((b * H_ + h) * NCH + cid)) * (CH * DK) +
            r * 128 + ((g ^ (r & 15)) * 8);
  ushort4 o0, o1;
  o0.x = f2bf(v[0]); o0.y = f2bf(v[1]); o0.z = f2bf(v[2]); o0.w = f2bf(v[3]);
  o1.x = f2bf(v[4]); o1.y = f2bf(v[5]); o1.z = f2bf(v[6]); o1.w = f2bf(v[7]);
  *reinterpret_cast<ushort4*>(dst) = o0;
  *reinterpret_cast<ushort4*>(dst + 4) = o1;
}

// ---------------------------------------------------------------------------
// beta = sigmoid(x @ Wb)
// ---------------------------------------------------------------------------
__global__ __launch_bounds__(256) void beta_sigmoid(const float* __restrict__ x,
                                                    const float* __restrict__ Wb,
                                                    float* __restrict__ beta) {
  const int t = threadIdx.x;
  const int m = blockIdx.x * 4 + (t >> 6);
  const int l = t & 63;
  const int c = l & 15;
  const int s = l >> 4;
  const float* xr = x + (size_t)m * D_;
  const int kb = s * (D_ / 4);
  float acc = 0.f;
  for (int k = 0; k < D_ / 4; ++k)
    acc = fmaf(xr[kb + k], Wb[(size_t)(kb + k) * H_ + c], acc);
  acc += __shfl_xor(acc, 16);
  acc += __shfl_xor(acc, 32);
  if (l < 16) beta[(size_t)m * H_ + c] = 1.f / (1.f + expf(-acc));
}

// ---------------------------------------------------------------------------
// delta_prep: block per (b,h,chunk) = 2048. In: q/k swizzled chunk bf16, v [M,D].
// Out: attn (swz8 chunk), Wneg = -M^-1(beta*k) (swz16 chunk), kT (swz8 chunk),
//      u_v = M^-1(beta*v) in-place over v.
// ---------------------------------------------------------------------------
__global__ __launch_bounds__(256) void delta_prep(const us* __restrict__ qch,
                                                  const us* __restrict__ kch,
                                                  const float* __restrict__ beta,
                                                  us* __restrict__ v_uv,
                                                  us* __restrict__ Wout,
                                                  us* __restrict__ kTout,
                                                  us* __restrict__ Aout) {
  __shared__ float kc[CH][132];
  __shared__ float qc[CH][132];
  __shared__ float Am[CH][68];
  __shared__ float uvw[CH][264];  // 0..127 = W, 128..255 = u_v
  __shared__ float betac[CH];

  const int bx = blockIdx.x;
  const int bh = bx >> 6, cid = bx & 63;
  const int b = bh >> 4, h = bh & 15;
  const int t = threadIdx.x;
  const size_t rowbase = ((size_t)b * T_ + (size_t)cid * CH) * D_ + (size_t)h * DK;
  const size_t cbase = (size_t)bx * (CH * DK);

  {  // stage q,k from swizzled chunk layout -> f32 LDS (logical layout)
#pragma unroll
    for (int p = 0; p < 4; ++p) {
      const int unit = t + p * 256;       // 0..1023
      const int r = unit >> 4, g = unit & 15;
      const u16x8 kv = *reinterpret_cast<const u16x8*>(&kch[cbase + r * 128 + g * 8]);
      const u16x8 qv = *reinterpret_cast<const u16x8*>(&qch[cbase + r * 128 + g * 8]);
      const int lc = (g ^ (r & 15)) * 8;  // logical col
#pragma unroll
      for (int j = 0; j < 8; ++j) { kc[r][lc + j] = bf2f(kv[j]); qc[r][lc + j] = bf2f(qv[j]); }
    }
    if (t < CH) betac[t] = beta[((size_t)b * T_ + (size_t)cid * CH + t) * H_ + h];
  }
  __syncthreads();

  {  // A (strict tril, beta-scaled) -> Am ; attn (tril incl diag) -> global swz8
    const int ti = t >> 4, tj = t & 15;
    float accA[4][4], accQ[4][4];
#pragma unroll
    for (int a = 0; a < 4; ++a)
#pragma unroll
      for (int c = 0; c < 4; ++c) { accA[a][c] = 0.f; accQ[a][c] = 0.f; }
    for (int d = 0; d < DK; d += 4) {
      float4 kj[4], ai[4], qi[4];
#pragma unroll
      for (int c = 0; c < 4; ++c) {
        kj[c] = *reinterpret_cast<float4*>(&kc[tj + 16 * c][d]);
        ai[c] = *reinterpret_cast<float4*>(&kc[ti + 16 * c][d]);
        qi[c] = *reinterpret_cast<float4*>(&qc[ti + 16 * c][d]);
      }
#pragma unroll
      for (int a = 0; a < 4; ++a)
#pragma unroll
        for (int c = 0; c < 4; ++c) {
          accA[a][c] += ai[a].x * kj[c].x + ai[a].y * kj[c].y +
                        ai[a].z * kj[c].z + ai[a].w * kj[c].w;
          accQ[a][c] += qi[a].x * kj[c].x + qi[a].y * kj[c].y +
                        qi[a].z * kj[c].z + qi[a].w * kj[c].w;
        }
    }
    const size_t abase = (size_t)bx * (CH * CH);
#pragma unroll
    for (int a = 0; a < 4; ++a)
#pragma unroll
      for (int c = 0; c < 4; ++c) {
        const int i = ti + 16 * a, j = tj + 16 * c;
        Am[i][j] = (j < i) ? betac[i] * accA[a][c] : 0.f;
        Aout[abase + i * 64 + (((j >> 3) ^ (i & 7)) * 8) + (j & 7)] =
            f2bf((j <= i) ? accQ[a][c] : 0.f);
      }
  }

  {  // uvw init: W-half = beta*k, uv-half = beta*v
    for (int idx = t; idx < CH * 32; idx += 256) {
      const int r = idx >> 5, c4 = (idx & 31) * 4;
      const float bb = betac[r];
      const float4 kv = *reinterpret_cast<float4*>(&kc[r][c4]);
      *reinterpret_cast<float4*>(&uvw[r][c4]) =
          make_float4(bb * kv.x, bb * kv.y, bb * kv.z, bb * kv.w);
      const ushort4 vv = *reinterpret_cast<const ushort4*>(&v_uv[rowbase + (size_t)r * D_ + c4]);
      *reinterpret_cast<float4*>(&uvw[r][128 + c4]) =
          make_float4(bb * bf2f(vv.x), bb * bf2f(vv.y), bb * bf2f(vv.z), bb * bf2f(vv.w));
    }
  }
  __syncthreads();

  {  // column-private blocked forward substitution
    float ue[16];
#pragma unroll 1
    for (int blk = 0; blk < 4; ++blk) {
      const int R0 = blk << 4;
#pragma unroll
      for (int i = 0; i < 16; ++i) ue[i] = uvw[R0 + i][t];
#pragma unroll
      for (int i = 1; i < 16; ++i) {
        float s = 0.f;
#pragma unroll
        for (int j = 0; j < i; ++j) s = fmaf(Am[R0 + i][R0 + j], ue[j], s);
        ue[i] -= s;
      }
#pragma unroll
      for (int i = 1; i < 16; ++i) uvw[R0 + i][t] = ue[i];
      for (int i = R0 + 16; i < CH; ++i) {
        const float4 a0 = *reinterpret_cast<float4*>(&Am[i][R0]);
        const float4 a1 = *reinterpret_cast<float4*>(&Am[i][R0 + 4]);
        const float4 a2 = *reinterpret_cast<float4*>(&Am[i][R0 + 8]);
        const float4 a3 = *reinterpret_cast<float4*>(&Am[i][R0 + 12]);
        float s = a0.x * ue[0] + a0.y * ue[1] + a0.z * ue[2] + a0.w * ue[3];
        s += a1.x * ue[4] + a1.y * ue[5] + a1.z * ue[6] + a1.w * ue[7];
        s += a2.x * ue[8] + a2.y * ue[9] + a2.z * ue[10] + a2.w * ue[11];
        s += a3.x * ue[12] + a3.y * ue[13] + a3.z * ue[14] + a3.w * ue[15];
        uvw[i][t] -= s;
      }
    }
  }
  __syncthreads();

  {  // write -W (swz16), kT (swz8), u_v (in-place over v)
#pragma unroll
    for (int p = 0; p < 4; ++p) {
      const int unit = t + p * 256;
      const int r = unit >> 4, g = unit & 15;
      u16x8 wo;
#pragma unroll
      for (int j = 0; j < 8; ++j) wo[j] = f2bf(-uvw[r][g * 8 + j]);
      *reinterpret_cast<u16x8*>(&Wout[cbase + r * 128 + ((g ^ (r & 15)) * 8)]) = wo;
    }
#pragma unroll
    for (int p = 0; p < 4; ++p) {
      const int unit = t + p * 256;
      const int d = unit >> 3, g = unit & 7;
      u16x8 ko;
#pragma unroll
      for (int j = 0; j < 8; ++j) ko[j] = f2bf(kc[g * 8 + j][d]);
      *reinterpret_cast<u16x8*>(&kTout[cbase + d * 64 + ((g ^ (d & 7)) * 8)]) = ko;
    }
    for (int idx = t; idx < CH * 32; idx += 256) {
      const int r = idx >> 5, c4 = (idx & 31) * 4;
      const float4 uv4 = *reinterpret_cast<float4*>(&uvw[r][128 + c4]);
      ushort4 uo;
      uo.x = f2bf(uv4.x); uo.y = f2bf(uv4.y); uo.z = f2bf(uv4.z); uo.w = f2bf(uv4.w);
      *reinterpret_cast<ushort4*>(&v_uv[rowbase + (size_t)r * D_ + c4]) = uo;
    }
  }
}

// ---------------------------------------------------------------------------
// delta_seq (MFMA): 256 blocks x 256 threads (4 waves). Per chunk:
//   u = uv + (-W)·Sb ; o = q·Sb + attn·u ; Sf += kT·u   (Sb = bf16(S), per chunk)
// Staging: global_load_lds dbuf; operands pre-swizzled in global.
// ---------------------------------------------------------------------------
__global__ __launch_bounds__(256, 1) void delta_seq(const us* __restrict__ qch,
                                                    const us* __restrict__ Wch,
                                                    const us* __restrict__ kTch,
                                                    const us* __restrict__ atch,
                                                    us* __restrict__ uv_o) {
  __shared__ __align__(16) us qs[2][CH * DK];    // 16KB x2
  __shared__ __align__(16) us Ws[2][CH * DK];    // 16KB x2
  __shared__ __align__(16) us kTs[2][DK * CH];   // 16KB x2
  __shared__ __align__(16) us ats[2][CH * CH];   // 8KB  x2
  __shared__ __align__(16) us uvs[2][CH * 16];   // 2KB  x2
  __shared__ __align__(16) us Sb[16 * 136];      // 4.25KB (S^T bf16)
  __shared__ __align__(16) float Sf[DK * 20];    // 10KB  (S f32 master)
  __shared__ __align__(16) us ub[CH * 18];       // 2.25KB (u bf16)

  const int t = threadIdx.x, l = t & 63, w = t >> 6;
  const int bx = blockIdx.x;
  const int vs = bx >> 5, bh = bx & 31;
  const int b = bh >> 4, h = bh & 15;
  const int rr = l & 15, hi = l >> 4;

  for (int i = t; i < DK * 20; i += 256) Sf[i] = 0.f;
  __syncthreads();

  const size_t cbQ = (size_t)(bh * NCH) * (CH * DK);
  const size_t cbA = (size_t)(bh * NCH) * (CH * CH);
  const size_t rowbase0 = ((size_t)b * T_) * D_ + (size_t)h * DK + vs * 16;

#define STAGE(buf, cid)                                                        \
  do {                                                                         \
    const us* qg = qch + cbQ + (size_t)(cid) * (CH * DK);                      \
    const us* Wg = Wch + cbQ + (size_t)(cid) * (CH * DK);                      \
    const us* kg = kTch + cbQ + (size_t)(cid) * (CH * DK);                     \
    const us* ag = atch + cbA + (size_t)(cid) * (CH * CH);                     \
    _Pragma("unroll")                                                          \
    for (int p = 0; p < 4; ++p) {                                              \
      gl_lds16(qg + p * 2048 + t * 8, &qs[buf][p * 2048 + t * 8]);             \
      gl_lds16(Wg + p * 2048 + t * 8, &Ws[buf][p * 2048 + t * 8]);             \
      gl_lds16(kg + p * 2048 + t * 8, &kTs[buf][p * 2048 + t * 8]);            \
    }                                                                          \
    _Pragma("unroll")                                                          \
    for (int p = 0; p < 2; ++p)                                                \
      gl_lds16(ag + p * 2048 + t * 8, &ats[buf][p * 2048 + t * 8]);            \
    if (t < 128)                                                               \
      gl_lds16(uv_o + rowbase0 + (size_t)((cid) * CH + (t >> 1)) * D_ + (t & 1) * 8, \
               &uvs[buf][t * 8]);                                              \
  } while (0)

  STAGE(0, 0);

  for (int cid = 0; cid < NCH; ++cid) {
    const int cur = cid & 1;
    {  // Sb = bf16(S^T)
      const int e = t & 15, d0 = (t >> 4) * 8;
      bfrag sb;
#pragma unroll
      for (int i = 0; i < 8; ++i) sb[i] = (short)f2bf(Sf[(d0 + i) * 20 + e]);
      *reinterpret_cast<bfrag*>(&Sb[e * 136 + d0]) = sb;
    }
    __syncthreads();  // drains staged vmcnt; Sb visible

    if (cid + 1 < NCH) STAGE(cur ^ 1, cid + 1);

    // ---- u-phase: wave w owns rows 16w..16w+15
    ffrag uacc;
#pragma unroll
    for (int j = 0; j < 4; ++j)
      uacc[j] = bf2f(uvs[cur][(16 * w + 4 * hi + j) * 16 + rr]);
#pragma unroll
    for (int ks = 0; ks < 4; ++ks) {
      const bfrag af = *reinterpret_cast<const bfrag*>(
          &Ws[cur][(16 * w + rr) * 128 + (((4 * ks + hi) ^ rr) * 8)]);
      const bfrag bf_ = *reinterpret_cast<const bfrag*>(&Sb[rr * 136 + ks * 32 + hi * 8]);
      uacc = __builtin_amdgcn_mfma_f32_16x16x32_bf16(af, bf_, uacc, 0, 0, 0);
    }
#pragma unroll
    for (int j = 0; j < 4; ++j)
      ub[(16 * w + 4 * hi + j) * 18 + rr] = f2bf(uacc[j]);
    __syncthreads();  // ub ready

    // ---- o-phase
    {
      ffrag oacc;
#pragma unroll
      for (int j = 0; j < 4; ++j) oacc[j] = 0.f;
#pragma unroll
      for (int ks = 0; ks < 4; ++ks) {
        const bfrag af = *reinterpret_cast<const bfrag*>(
            &qs[cur][(16 * w + rr) * 128 + (((4 * ks + hi) ^ rr) * 8)]);
        const bfrag bf_ = *reinterpret_cast<const bfrag*>(&Sb[rr * 136 + ks * 32 + hi * 8]);
        oacc = __builtin_amdgcn_mfma_f32_16x16x32_bf16(af, bf_, oacc, 0, 0, 0);
      }
      const int nks = (w < 2) ? 1 : 2;  // causal: upper attn cols are zero
      for (int ks = 0; ks < nks; ++ks) {
        bfrag ubf;
#pragma unroll
        for (int j = 0; j < 8; ++j)
          ubf[j] = (short)ub[(32 * ks + 8 * hi + j) * 18 + rr];
        const bfrag af = *reinterpret_cast<const bfrag*>(
            &ats[cur][(16 * w + rr) * 64 + (((4 * ks + hi) ^ (rr & 7)) * 8)]);
        oacc = __builtin_amdgcn_mfma_f32_16x16x32_bf16(af, ubf, oacc, 0, 0, 0);
      }
      us* og = uv_o + rowbase0 + (size_t)(cid * CH) * D_;
#pragma unroll
      for (int j = 0; j < 4; ++j)
        og[(size_t)(16 * w + 4 * hi + j) * D_ + rr] = f2bf(oacc[j]);
    }

    // ---- S-phase: wave w owns S row-tiles 2w, 2w+1 (rows 32w..32w+31)
    {
      bfrag ubf[2];
#pragma unroll
      for (int ks = 0; ks < 2; ++ks)
#pragma unroll
        for (int j = 0; j < 8; ++j)
          ubf[ks][j] = (short)ub[(32 * ks + 8 * hi + j) * 18 + rr];
#pragma unroll
      for (int t2 = 0; t2 < 2; ++t2) {
        const int tile = 2 * w + t2;
        ffrag sacc;
#pragma unroll
        for (int j = 0; j < 4; ++j) sacc[j] = Sf[(16 * tile + 4 * hi + j) * 20 + rr];
#pragma unroll
        for (int ks = 0; ks < 2; ++ks) {
          const bfrag af = *reinterpret_cast<const bfrag*>(
              &kTs[cur][(16 * tile + rr) * 64 + (((4 * ks + hi) ^ (rr & 7)) * 8)]);
          sacc = __builtin_amdgcn_mfma_f32_16x16x32_bf16(af, ubf[ks], sacc, 0, 0, 0);
        }
#pragma unroll
        for (int j = 0; j < 4; ++j) Sf[(16 * tile + 4 * hi + j) * 20 + rr] = sacc[j];
      }
    }
    __syncthreads();  // Sf stable; cur-buffer reads done before restage
  }
#undef STAGE
}

// ---------------------------------------------------------------------------
// per-head RMSNorm (over 128) * onorm_w : bf16 in -> bf16 out (separate bufs)
// ---------------------------------------------------------------------------
__global__ __launch_bounds__(256) void rms_onorm_bf16(const us* __restrict__ in,
                                                      const float* __restrict__ w,
                                                      us* __restrict__ out) {
  const int bt = blockIdx.x;
  const int d0 = threadIdx.x * 8;
  const us* p = in + (size_t)bt * D_ + d0;
  const ushort4 a = *reinterpret_cast<const ushort4*>(p);
  const ushort4 b = *reinterpret_cast<const ushort4*>(p + 4);
  float v[8] = {bf2f(a.x), bf2f(a.y), bf2f(a.z), bf2f(a.w),
                bf2f(b.x), bf2f(b.y), bf2f(b.z), bf2f(b.w)};
  float ss = 0.f;
#pragma unroll
  for (int j = 0; j < 8; ++j) ss = fmaf(v[j], v[j], ss);
  ss += __shfl_xor(ss, 1);
  ss += __shfl_xor(ss, 2);
  ss += __shfl_xor(ss, 4);
  ss += __shfl_xor(ss, 8);
  const float sc = rsqrtf(ss * (1.0f / 128.0f) + 1e-5f);
  const int hd = d0 & 127;
  ushort4 o0, o1;
  o0.x = f2bf(v[0] * sc * w[hd + 0]); o0.y = f2bf(v[1] * sc * w[hd + 1]);
  o0.z = f2bf(v[2] * sc * w[hd + 2]); o0.w = f2bf(v[3] * sc * w[hd + 3]);
  o1.x = f2bf(v[4] * sc * w[hd + 4]); o1.y = f2bf(v[5] * sc * w[hd + 5]);
  o1.z = f2bf(v[6] * sc * w[hd + 6]); o1.w = f2bf(v[7] * sc * w[hd + 7]);
  us* op = out + (size_t)bt * D_ + d0;
  *reinterpret_cast<ushort4*>(op) = o0;
  *reinterpret_cast<ushort4*>(op + 4) = o1;
}

// ---------------------------------------------------------------------------
extern "C" void kernel_launch(void* const* d_in, const int* in_sizes, int n_in,
                              void* d_out, int out_size, void* d_ws, size_t ws_size,
                              hipStream_t stream) {
  const float* x  = (const float*)d_in[0];
  const float* Wq = (const float*)d_in[1];
  const float* Wk = (const float*)d_in[2];
  const float* Wv = (const float*)d_in[3];
  const float* Wb = (const float*)d_in[4];
  const float* Wo = (const float*)d_in[5];
  const float* cq = (const float*)d_in[6];
  const float* ck = (const float*)d_in[7];
  const float* cv = (const float*)d_in[8];
  const float* ow = (const float*)d_in[9];
  float* out = (float*)d_out;

  // workspace: 5*NE + D*D bf16 units = 176.2 MB (< 201.8 MB proven floor)
  const size_t NE = (size_t)M_ * D_;  // 16.78M elems
  us* ws   = (us*)d_ws;
  us* gout = ws;              // [M,D] gemm scratch; later: attn chunks + betab
  us* qch  = ws + NE;         // q swizzled chunk layout
  us* kch  = ws + 2 * NE;     // k swizzled chunk layout
  us* Wch  = ws + 3 * NE;     // -W swizzled chunk layout
  us* kTch = ws + 4 * NE;     // kT swizzled chunk; after seq: rms-out [M,D]
  us* wt   = ws + 5 * NE;     // [D,D] W^T (reused 4x)
  us* attb = gout;                                  // [2048][64][64] = 8.39M
  float* betab = (float*)(gout + 12 * 1024 * 1024); // [M,H] f32
  // d_out as bf16 scratch: xb [0,NE), v/uv/o [NE,2NE) — dead before final GEMM
  us* xb = (us*)d_out;
  us* vb = xb + NE;

  dim3 gg(D_ / 128, M_ / 128);
  dim3 wg(D_ / 64, D_ / 64);

  to_bf16<<<NE / 2048, 256, 0, stream>>>(x, xb);

  wtrans<<<wg, 256, 0, stream>>>(Wv, wt);
  gemm_bf16<false><<<gg, 256, 0, stream>>>(xb, wt, gout, M_, D_, D_);
  conv_silu_plain<<<M_, 256, 0, stream>>>(gout, cv, vb);

  wtrans<<<wg, 256, 0, stream>>>(Wq, wt);
  gemm_bf16<false><<<gg, 256, 0, stream>>>(xb, wt, gout, M_, D_, D_);
  conv_silu_chunk<<<M_, 256, 0, stream>>>(gout, cq, qch, 2);

  wtrans<<<wg, 256, 0, stream>>>(Wk, wt);
  gemm_bf16<false><<<gg, 256, 0, stream>>>(xb, wt, gout, M_, D_, D_);
  conv_silu_chunk<<<M_, 256, 0, stream>>>(gout, ck, kch, 1);

  beta_sigmoid<<<M_ / 4, 256, 0, stream>>>(x, Wb, betab);

  delta_prep<<<32 * NCH, 256, 0, stream>>>(qch, kch, betab, vb, Wch, kTch, attb);
  delta_seq<<<256, 256, 0, stream>>>(qch, Wch, kTch, attb, vb);

  rms_onorm_bf16<<<M_, 256, 0, stream>>>(vb, ow, kTch);

  wtrans<<<wg, 256, 0, stream>>>(Wo, wt);
  gemm_bf16<true><<<gg, 256, 0, stream>>>(kTch, wt, out, M_, D_, D_);
}

// Round 7
// 798.928 us; speedup vs baseline: 13.0925x; 1.1999x over previous
//
#include <hip/hip_runtime.h>
#include <math.h>

#define B_ 2
#define T_ 4096
#define D_ 2048
#define H_ 16
#define DK 128
#define DV 128
#define CH 64
#define M_ (B_ * T_)  // 8192
#define NCH (T_ / CH) // 64 chunks

typedef __attribute__((ext_vector_type(8))) short bfrag;   // 8 bf16
typedef __attribute__((ext_vector_type(4))) float ffrag;   // 4 f32 acc
typedef __attribute__((ext_vector_type(8))) unsigned short u16x8;
typedef unsigned short us;

#define MFMA __builtin_amdgcn_mfma_f32_16x16x32_bf16

__device__ inline us f2bf(float f) {
  union { float f; unsigned u; } v; v.f = f;
  unsigned r = v.u + 0x7fffu + ((v.u >> 16) & 1u);
  return (us)(r >> 16);
}
__device__ inline float bf2f(us u) {
  union { unsigned u; float f; } v; v.u = ((unsigned)u) << 16;
  return v.f;
}

// async global->LDS, 16B per lane (dest = wave-uniform base + lane*16)
__device__ inline void gl_lds16(const us* g, us* l) {
  __builtin_amdgcn_global_load_lds(
      (const __attribute__((address_space(1))) void*)g,
      (__attribute__((address_space(3))) void*)l, 16, 0, 0);
}

// ---------------------------------------------------------------------------
// flat f32 -> bf16 (8 elems/thread)
// ---------------------------------------------------------------------------
__global__ __launch_bounds__(256) void to_bf16(const float* __restrict__ in,
                                               us* __restrict__ out) {
  const size_t i = ((size_t)blockIdx.x * 256 + threadIdx.x) * 8;
  const float4 a = *reinterpret_cast<const float4*>(in + i);
  const float4 b = *reinterpret_cast<const float4*>(in + i + 4);
  ushort4 o0, o1;
  o0.x = f2bf(a.x); o0.y = f2bf(a.y); o0.z = f2bf(a.z); o0.w = f2bf(a.w);
  o1.x = f2bf(b.x); o1.y = f2bf(b.y); o1.z = f2bf(b.z); o1.w = f2bf(b.w);
  *reinterpret_cast<ushort4*>(out + i) = o0;
  *reinterpret_cast<ushort4*>(out + i + 4) = o1;
}

// ---------------------------------------------------------------------------
// transpose + convert: Wt[n][k] = bf16(W[k][n]), 64x64 tiles
// ---------------------------------------------------------------------------
__global__ __launch_bounds__(256) void wtrans(const float* __restrict__ W,
                                              us* __restrict__ Wt) {
  __shared__ float tile[64][68];
  const int k0 = blockIdx.y * 64, n0 = blockIdx.x * 64;
  const int lr = threadIdx.x >> 4, lc = (threadIdx.x & 15) * 4;
#pragma unroll
  for (int p = 0; p < 4; ++p) {
    const int r = lr + p * 16;
    *reinterpret_cast<float4*>(&tile[r][lc]) =
        *reinterpret_cast<const float4*>(&W[(size_t)(k0 + r) * D_ + n0 + lc]);
  }
  __syncthreads();
#pragma unroll
  for (int p = 0; p < 4; ++p) {
    const int r = lr + p * 16;
    ushort4 o;
    o.x = f2bf(tile[lc + 0][r]); o.y = f2bf(tile[lc + 1][r]);
    o.z = f2bf(tile[lc + 2][r]); o.w = f2bf(tile[lc + 3][r]);
    *reinterpret_cast<ushort4*>(&Wt[(size_t)(n0 + r) * D_ + k0 + lc]) = o;
  }
}

// ---------------------------------------------------------------------------
// bf16 MFMA GEMM (m97 structure) + T1 XCD-aware block swizzle.
// ---------------------------------------------------------------------------
template <bool OUTF32>
__global__ __launch_bounds__(256) void gemm_bf16(const us* __restrict__ A,
                                                 const us* __restrict__ Bt,
                                                 void* __restrict__ Cp,
                                                 int M, int N, int K) {
  __shared__ __align__(16) us As[128 * 32];
  __shared__ __align__(16) us Bs[128 * 32];
  const int t = threadIdx.x, l = t & 63, w = t >> 6;
  // XCD swizzle: nwg multiple of 8 by construction
  const int nwg = gridDim.x * gridDim.y;
  const int lin = blockIdx.y * gridDim.x + blockIdx.x;
  const int swz = (lin & 7) * (nwg >> 3) + (lin >> 3);
  const int m0 = (swz / gridDim.x) * 128, n0 = (swz % gridDim.x) * 128;
  const int wr = w >> 1, wc = w & 1;
  const int sr = t >> 2, sp = (t & 3) * 8;
  const int fr = l & 15, fs = (l >> 4) * 8;

  ffrag acc[4][4];
#pragma unroll
  for (int mi = 0; mi < 4; ++mi)
#pragma unroll
    for (int ni = 0; ni < 4; ++ni)
#pragma unroll
      for (int e = 0; e < 4; ++e) acc[mi][ni][e] = 0.f;

  const us* Ag0 = A + (size_t)(m0 + sr) * K + sp;
  const us* Ag1 = A + (size_t)(m0 + sr + 64) * K + sp;
  const us* Bg0 = Bt + (size_t)(n0 + sr) * K + sp;
  const us* Bg1 = Bt + (size_t)(n0 + sr + 64) * K + sp;
  us* Al0 = As + sr * 32 + sp;
  us* Al1 = As + (sr + 64) * 32 + sp;
  us* Bl0 = Bs + sr * 32 + sp;
  us* Bl1 = Bs + (sr + 64) * 32 + sp;

  for (int k0 = 0; k0 < K; k0 += 32) {
    __syncthreads();
    gl_lds16(Ag0 + k0, Al0);
    gl_lds16(Ag1 + k0, Al1);
    gl_lds16(Bg0 + k0, Bl0);
    gl_lds16(Bg1 + k0, Bl1);
    __syncthreads();
    bfrag af[4], bfr[4];
#pragma unroll
    for (int mi = 0; mi < 4; ++mi)
      af[mi] = *reinterpret_cast<const bfrag*>(As + (wr * 64 + mi * 16 + fr) * 32 + fs);
#pragma unroll
    for (int ni = 0; ni < 4; ++ni)
      bfr[ni] = *reinterpret_cast<const bfrag*>(Bs + (wc * 64 + ni * 16 + fr) * 32 + fs);
#pragma unroll
    for (int mi = 0; mi < 4; ++mi)
#pragma unroll
      for (int ni = 0; ni < 4; ++ni)
        acc[mi][ni] = MFMA(af[mi], bfr[ni], acc[mi][ni], 0, 0, 0);
  }
  const int cr = (l >> 4) * 4, cc = l & 15;
#pragma unroll
  for (int mi = 0; mi < 4; ++mi)
#pragma unroll
    for (int ni = 0; ni < 4; ++ni)
#pragma unroll
      for (int j = 0; j < 4; ++j) {
        const size_t idx = (size_t)(m0 + wr * 64 + mi * 16 + cr + j) * N +
                           n0 + wc * 64 + ni * 16 + cc;
        if constexpr (OUTF32) ((float*)Cp)[idx] = acc[mi][ni][j];
        else ((us*)Cp)[idx] = f2bf(acc[mi][ni][j]);
      }
}

// ---------------------------------------------------------------------------
// conv+silu bodies
// ---------------------------------------------------------------------------
__device__ inline void conv_body(const us* __restrict__ in, const float* cw,
                                 int bt, int d0, int mode, float v[8]) {
  const int tb = bt & (T_ - 1);
  const us* row = in + (size_t)bt * D_ + d0;
#pragma unroll
  for (int j = 0; j < 8; ++j) v[j] = 0.f;
#pragma unroll
  for (int j = 0; j < 4; ++j) {
    if (tb >= j) {
      const us* rp = row - (size_t)(j * D_);
      const ushort4 a = *reinterpret_cast<const ushort4*>(rp);
      const ushort4 b = *reinterpret_cast<const ushort4*>(rp + 4);
      const float wj = cw[3 - j];
      v[0] = fmaf(wj, bf2f(a.x), v[0]); v[1] = fmaf(wj, bf2f(a.y), v[1]);
      v[2] = fmaf(wj, bf2f(a.z), v[2]); v[3] = fmaf(wj, bf2f(a.w), v[3]);
      v[4] = fmaf(wj, bf2f(b.x), v[4]); v[5] = fmaf(wj, bf2f(b.y), v[5]);
      v[6] = fmaf(wj, bf2f(b.z), v[6]); v[7] = fmaf(wj, bf2f(b.w), v[7]);
    }
  }
#pragma unroll
  for (int j = 0; j < 8; ++j) v[j] = v[j] / (1.f + expf(-v[j]));
  if (mode) {
    float ss = 0.f;
#pragma unroll
    for (int j = 0; j < 8; ++j) ss = fmaf(v[j], v[j], ss);
    ss += __shfl_xor(ss, 1);
    ss += __shfl_xor(ss, 2);
    ss += __shfl_xor(ss, 4);
    ss += __shfl_xor(ss, 8);
    float sc = rsqrtf(ss + 1e-6f);
    if (mode == 2) sc *= 0.08838834764831845f;  // 128^-0.5
#pragma unroll
    for (int j = 0; j < 8; ++j) v[j] *= sc;
  }
}

__global__ __launch_bounds__(256) void conv_silu_plain(const us* __restrict__ in,
                                                       const float* __restrict__ cw,
                                                       us* __restrict__ out) {
  const int bt = blockIdx.x, d0 = threadIdx.x * 8;
  float v[8];
  conv_body(in, cw, bt, d0, 0, v);
  ushort4 o0, o1;
  o0.x = f2bf(v[0]); o0.y = f2bf(v[1]); o0.z = f2bf(v[2]); o0.w = f2bf(v[3]);
  o1.x = f2bf(v[4]); o1.y = f2bf(v[5]); o1.z = f2bf(v[6]); o1.w = f2bf(v[7]);
  us* op = out + (size_t)bt * D_ + d0;
  *reinterpret_cast<ushort4*>(op) = o0;
  *reinterpret_cast<ushort4*>(op + 4) = o1;
}

// conv+silu+l2norm -> swizzled chunk layout [bh][cid][64][128], 16B-group XOR(r&15)
__global__ __launch_bounds__(256) void conv_silu_chunk(const us* __restrict__ in,
                                                       const float* __restrict__ cw,
                                                       us* __restrict__ out,
                                                       int mode) {
  const int bt = blockIdx.x, d0 = threadIdx.x * 8;
  float v[8];
  conv_body(in, cw, bt, d0, mode, v);
  const int b = bt >> 12, tt = bt & (T_ - 1);
  const int cid = tt >> 6, r = tt & 63;
  const int h = d0 >> 7, g = (d0 & 127) >> 3;
  us* dst = out + ((size_t)((b * H_ + h) * NCH + cid)) * (CH * DK) +
            r * 128 + ((g ^ (r & 15)) * 8);
  ushort4 o0, o1;
  o0.x = f2bf(v[0]); o0.y = f2bf(v[1]); o0.z = f2bf(v[2]); o0.w = f2bf(v[3]);
  o1.x = f2bf(v[4]); o1.y = f2bf(v[5]); o1.z = f2bf(v[6]); o1.w = f2bf(v[7]);
  *reinterpret_cast<ushort4*>(dst) = o0;
  *reinterpret_cast<ushort4*>(dst + 4) = o1;
}

// ---------------------------------------------------------------------------
// beta = sigmoid(x @ Wb) -> [bh][T] layout (contiguous for prep)
// ---------------------------------------------------------------------------
__global__ __launch_bounds__(256) void beta_sigmoid(const float* __restrict__ x,
                                                    const float* __restrict__ Wb,
                                                    float* __restrict__ betaT) {
  const int t = threadIdx.x;
  const int m = blockIdx.x * 4 + (t >> 6);
  const int l = t & 63;
  const int c = l & 15;
  const int s = l >> 4;
  const float* xr = x + (size_t)m * D_;
  const int kb = s * (D_ / 4);
  float acc = 0.f;
  for (int k = 0; k < D_ / 4; ++k)
    acc = fmaf(xr[kb + k], Wb[(size_t)(kb + k) * H_ + c], acc);
  acc += __shfl_xor(acc, 16);
  acc += __shfl_xor(acc, 32);
  if (l < 16) {
    const int b = m >> 12, tt = m & (T_ - 1);
    betaT[((size_t)(b * H_ + c)) * T_ + tt] = 1.f / (1.f + expf(-acc));
  }
}

// ---------------------------------------------------------------------------
// f32 blocked product step for T = M^-1: T[I][J] = -T_II * (sum_K M[I][K] T[K][J])
// ---------------------------------------------------------------------------
__device__ inline void prod_step(float* Tf, const float* Am, float* xbuf,
                                 int r, int c, int I, int J,
                                 int nk, int K0, int K1, int K2) {
  float X = 0.f;
  const int Ks[3] = {K0, K1, K2};
  for (int kk = 0; kk < nk; ++kk) {
    const int K = Ks[kk];
    const float* amrow = Am + (16 * I + r) * 72 + 16 * K;
    const float* tcol = Tf + (16 * K) * 68 + 16 * J + c;
#pragma unroll
    for (int m = 0; m < 16; ++m) X = fmaf(amrow[m], tcol[m * 68], X);
  }
  __syncthreads();               // prior step's xbuf readers done
  xbuf[r * 17 + c] = X;
  __syncthreads();               // xbuf ready
  float s = 0.f;
  const float* trow = Tf + (16 * I + r) * 68 + 16 * I;
#pragma unroll
  for (int m = 0; m < 16; ++m) s = fmaf(trow[m], xbuf[m * 17 + c], s);
  Tf[(16 * I + r) * 68 + 16 * J + c] = -s;   // disjoint from reads above
  __syncthreads();               // block (I,J) visible for next step
}

// ---------------------------------------------------------------------------
// delta_prep v2: block per (b,h,chunk) = 2048, 256 thr, 2 blocks/CU.
// MFMA: A, attn, W, u_v. f32 blocked inverse for T. LDS unioned to 70.3 KB.
// ---------------------------------------------------------------------------
__global__ __launch_bounds__(256, 2) void delta_prep(const us* __restrict__ qch,
                                                     const us* __restrict__ kch,
                                                     const float* __restrict__ betaT,
                                                     us* __restrict__ v_uv,
                                                     us* __restrict__ Wout,
                                                     us* __restrict__ kTout,
                                                     us* __restrict__ Aout) {
  __shared__ __align__(16) unsigned char lds[72000];
  us*    ks    = (us*)(lds);             // [64*128] swz     (P0-P1)
  us*    Tb    = (us*)(lds);             // [64][72] bf16    (P5-)
  float* Am    = (float*)(lds + 16384);  // [64][72] f32     (P1-P4)
  us*    vTb   = (us*)(lds + 16384);     // [128][72] bf16   (P5-)
  float* Tf    = (float*)(lds + 34816);  // [64][68] f32     (P2-P5)
  us*    atst  = (us*)(lds + 34816);     // attn stage [64*64] (P0-P2)
  us*    Wst   = (us*)(lds + 34816);     // W stage [64*128] (P6-)
  us*    kTb   = (us*)(lds + 52224);     // [128][72] bf16   (P1-P6a)
  us*    UVst  = (us*)(lds + 52224);     // [64*128]         (P6b-)
  float* betac = (float*)(lds + 70656);  // [64]
  float* xbuf  = (float*)(lds + 70912);  // [16][17]

  const int t = threadIdx.x, w = t >> 6, l = t & 63;
  const int rr = l & 15, hi = l >> 4;
  const int bx = blockIdx.x;
  const int bh = bx >> 6, cid = bx & 63;
  const int b = bh >> 4, h = bh & 15;
  const size_t rowbase = ((size_t)b * T_ + (size_t)cid * CH) * D_ + (size_t)h * DK;
  const size_t cbase = (size_t)bx * (CH * DK);
  const size_t abase = (size_t)bx * (CH * CH);

  // ---- P0: stage ks, zero attn-stage, betac
  {
    const us* kg = kch + cbase;
#pragma unroll
    for (int p = 0; p < 4; ++p)
      gl_lds16(kg + p * 2048 + t * 8, ks + p * 2048 + t * 8);
    const float4 z = make_float4(0.f, 0.f, 0.f, 0.f);
    *reinterpret_cast<float4*>(atst + t * 16) = z;
    *reinterpret_cast<float4*>(atst + t * 16 + 8) = z;
    if (t < 64) betac[t] = betaT[(size_t)bh * T_ + cid * CH + t];
  }
  __syncthreads();

  // ---- P1: A MFMA (beta-scaled strict-tril -> Am f32), attn MFMA -> atst,
  //          kTb build (plain k^T bf16)
  {
    bfrag qf[4], kf[4];
#pragma unroll
    for (int k4 = 0; k4 < 4; ++k4) {
      const int go = ((4 * k4 + hi) ^ rr) * 8;
      qf[k4] = *reinterpret_cast<const bfrag*>(qch + cbase + (16 * w + rr) * 128 + go);
      kf[k4] = *reinterpret_cast<const bfrag*>(ks + (16 * w + rr) * 128 + go);
    }
    for (int jt = 0; jt <= w; ++jt) {
      ffrag accA = {0.f, 0.f, 0.f, 0.f}, accQ = {0.f, 0.f, 0.f, 0.f};
#pragma unroll
      for (int k4 = 0; k4 < 4; ++k4) {
        const bfrag bfr = *reinterpret_cast<const bfrag*>(
            ks + (16 * jt + rr) * 128 + (((4 * k4 + hi) ^ rr) * 8));
        accA = MFMA(kf[k4], bfr, accA, 0, 0, 0);
        accQ = MFMA(qf[k4], bfr, accQ, 0, 0, 0);
      }
#pragma unroll
      for (int j4 = 0; j4 < 4; ++j4) {
        const int i = 16 * w + 4 * hi + j4, j = 16 * jt + rr;
        Am[i * 72 + j] = (j < i) ? betac[i] * accA[j4] : 0.f;
        if (j <= i)
          atst[i * 64 + (((j >> 3) ^ (i & 7)) * 8) + (j & 7)] = f2bf(accQ[j4]);
      }
    }
    const int r = t & 63, part = t >> 6;
#pragma unroll
    for (int gi = 0; gi < 4; ++gi) {
      const int g = 4 * part + gi;
      const u16x8 kv = *reinterpret_cast<const u16x8*>(ks + r * 128 + ((g ^ (r & 15)) * 8));
#pragma unroll
      for (int j = 0; j < 8; ++j) kTb[(g * 8 + j) * 72 + r] = kv[j];
    }
  }
  __syncthreads();

  // ---- P2: copy attn + kT to global; then zero Tf (same region as atst!)
  {
#pragma unroll
    for (int p = 0; p < 2; ++p) {
      const int unit = t + p * 256;
      *reinterpret_cast<u16x8*>(Aout + abase + unit * 8) =
          *reinterpret_cast<const u16x8*>(atst + unit * 8);
    }
#pragma unroll
    for (int p = 0; p < 4; ++p) {
      const int unit = t + p * 256;
      const int d = unit >> 3, sg = unit & 7;
      *reinterpret_cast<u16x8*>(kTout + cbase + unit * 8) =
          *reinterpret_cast<const u16x8*>(kTb + d * 72 + ((sg ^ (d & 7)) * 8));
    }
  }
  __syncthreads();  // atst reads done before Tf overwrite
  for (int i = t; i < 64 * 68; i += 256) Tf[i] = 0.f;
  __syncthreads();

  // ---- P3: four 16x16 unit-lower diagonal inverses (64 threads)
  if (t < 64) {
    const int blk = t >> 4, j = t & 15, bd = blk * 16;
    Tf[(bd + j) * 68 + bd + j] = 1.f;
    for (int i = j + 1; i < 16; ++i) {
      float s = 0.f;
      for (int m = j; m < i; ++m)
        s = fmaf(Am[(bd + i) * 72 + bd + m], Tf[(bd + m) * 68 + bd + j], s);
      Tf[(bd + i) * 68 + bd + j] = -s;
    }
  }
  __syncthreads();

  // ---- P4: off-diagonal blocks of T (f32, all 256 threads)
  {
    const int r = t >> 4, c = t & 15;
    prod_step(Tf, Am, xbuf, r, c, 1, 0, 1, 0, 0, 0);
    prod_step(Tf, Am, xbuf, r, c, 2, 0, 2, 0, 1, 0);
    prod_step(Tf, Am, xbuf, r, c, 3, 0, 3, 0, 1, 2);
    prod_step(Tf, Am, xbuf, r, c, 2, 1, 1, 1, 0, 0);
    prod_step(Tf, Am, xbuf, r, c, 3, 1, 2, 1, 2, 0);
    prod_step(Tf, Am, xbuf, r, c, 3, 2, 1, 2, 0, 0);
  }

  // ---- P5: Tb = bf16(T * diag(beta)) into ks region; vTb = v^T into Am region
  {
    const int vr = t >> 2, vp = t & 3;
    u16x8 vv[4];
#pragma unroll
    for (int g = 0; g < 4; ++g)
      vv[g] = *reinterpret_cast<const u16x8*>(v_uv + rowbase + (size_t)vr * D_ +
                                              vp * 32 + g * 8);
    const int ti = t >> 2, tg = t & 3;
    u16x8 w0, w1;
#pragma unroll
    for (int jj = 0; jj < 8; ++jj) {
      const int j0 = tg * 16 + jj, j1 = j0 + 8;
      w0[jj] = f2bf(Tf[ti * 68 + j0] * betac[j0]);
      w1[jj] = f2bf(Tf[ti * 68 + j1] * betac[j1]);
    }
    *reinterpret_cast<u16x8*>(Tb + ti * 72 + tg * 16) = w0;
    *reinterpret_cast<u16x8*>(Tb + ti * 72 + tg * 16 + 8) = w1;
#pragma unroll
    for (int g = 0; g < 4; ++g)
#pragma unroll
      for (int j = 0; j < 8; ++j)
        vTb[(vp * 32 + g * 8 + j) * 72 + vr] = vv[g][j];
  }
  __syncthreads();

  // ---- P6a: W = -(Tb . kTb) -> Wst (swz16)
  {
    bfrag ta[2];
#pragma unroll
    for (int k2 = 0; k2 < 2; ++k2)
      ta[k2] = *reinterpret_cast<const bfrag*>(Tb + (16 * w + rr) * 72 + 32 * k2 + 8 * hi);
#pragma unroll
    for (int dt = 0; dt < 8; ++dt) {
      ffrag acc = {0.f, 0.f, 0.f, 0.f};
#pragma unroll
      for (int k2 = 0; k2 < 2; ++k2) {
        const bfrag bfr = *reinterpret_cast<const bfrag*>(
            kTb + (16 * dt + rr) * 72 + 32 * k2 + 8 * hi);
        acc = MFMA(ta[k2], bfr, acc, 0, 0, 0);
      }
#pragma unroll
      for (int j4 = 0; j4 < 4; ++j4) {
        const int i = 16 * w + 4 * hi + j4, d = 16 * dt + rr;
        Wst[i * 128 + (((d >> 3) ^ (i & 15)) * 8) + (d & 7)] = f2bf(-acc[j4]);
      }
    }
  }
  __syncthreads();  // kTb reads done (UVst may overwrite); Wst complete

  // ---- P6b: UV = Tb . vTb -> UVst; copy W out
  {
    bfrag ta[2];
#pragma unroll
    for (int k2 = 0; k2 < 2; ++k2)
      ta[k2] = *reinterpret_cast<const bfrag*>(Tb + (16 * w + rr) * 72 + 32 * k2 + 8 * hi);
#pragma unroll
    for (int et = 0; et < 8; ++et) {
      ffrag acc = {0.f, 0.f, 0.f, 0.f};
#pragma unroll
      for (int k2 = 0; k2 < 2; ++k2) {
        const bfrag bfr = *reinterpret_cast<const bfrag*>(
            vTb + (16 * et + rr) * 72 + 32 * k2 + 8 * hi);
        acc = MFMA(ta[k2], bfr, acc, 0, 0, 0);
      }
#pragma unroll
      for (int j4 = 0; j4 < 4; ++j4)
        UVst[(16 * w + 4 * hi + j4) * 128 + 16 * et + rr] = f2bf(acc[j4]);
    }
#pragma unroll
    for (int p = 0; p < 4; ++p) {
      const int unit = t + p * 256;
      *reinterpret_cast<u16x8*>(Wout + cbase + unit * 8) =
          *reinterpret_cast<const u16x8*>(Wst + unit * 8);
    }
  }
  __syncthreads();

  // ---- P7: copy u_v out (in-place over v, row-major [M,D])
#pragma unroll
  for (int p = 0; p < 4; ++p) {
    const int unit = t + p * 256;
    const int r = unit >> 4, g = unit & 15;
    *reinterpret_cast<u16x8*>(v_uv + rowbase + (size_t)r * D_ + g * 8) =
        *reinterpret_cast<const u16x8*>(UVst + r * 128 + g * 8);
  }
}

// ---------------------------------------------------------------------------
// delta_seq (MFMA): unchanged from R5 (proven).
// ---------------------------------------------------------------------------
__global__ __launch_bounds__(256, 1) void delta_seq(const us* __restrict__ qch,
                                                    const us* __restrict__ Wch,
                                                    const us* __restrict__ kTch,
                                                    const us* __restrict__ atch,
                                                    us* __restrict__ uv_o) {
  __shared__ __align__(16) us qs[2][CH * DK];
  __shared__ __align__(16) us Ws[2][CH * DK];
  __shared__ __align__(16) us kTs[2][DK * CH];
  __shared__ __align__(16) us ats[2][CH * CH];
  __shared__ __align__(16) us uvs[2][CH * 16];
  __shared__ __align__(16) us Sb[16 * 136];
  __shared__ __align__(16) float Sf[DK * 20];
  __shared__ __align__(16) us ub[CH * 18];

  const int t = threadIdx.x, l = t & 63, w = t >> 6;
  const int bx = blockIdx.x;
  const int vs = bx >> 5, bh = bx & 31;
  const int b = bh >> 4, h = bh & 15;
  const int rr = l & 15, hi = l >> 4;

  for (int i = t; i < DK * 20; i += 256) Sf[i] = 0.f;
  __syncthreads();

  const size_t cbQ = (size_t)(bh * NCH) * (CH * DK);
  const size_t cbA = (size_t)(bh * NCH) * (CH * CH);
  const size_t rowbase0 = ((size_t)b * T_) * D_ + (size_t)h * DK + vs * 16;

#define STAGE(buf, cid)                                                        \
  do {                                                                         \
    const us* qg = qch + cbQ + (size_t)(cid) * (CH * DK);                      \
    const us* Wg = Wch + cbQ + (size_t)(cid) * (CH * DK);                      \
    const us* kg = kTch + cbQ + (size_t)(cid) * (CH * DK);                     \
    const us* ag = atch + cbA + (size_t)(cid) * (CH * CH);                     \
    _Pragma("unroll")                                                          \
    for (int p = 0; p < 4; ++p) {                                              \
      gl_lds16(qg + p * 2048 + t * 8, &qs[buf][p * 2048 + t * 8]);             \
      gl_lds16(Wg + p * 2048 + t * 8, &Ws[buf][p * 2048 + t * 8]);             \
      gl_lds16(kg + p * 2048 + t * 8, &kTs[buf][p * 2048 + t * 8]);            \
    }                                                                          \
    _Pragma("unroll")                                                          \
    for (int p = 0; p < 2; ++p)                                                \
      gl_lds16(ag + p * 2048 + t * 8, &ats[buf][p * 2048 + t * 8]);            \
    if (t < 128)                                                               \
      gl_lds16(uv_o + rowbase0 + (size_t)((cid) * CH + (t >> 1)) * D_ + (t & 1) * 8, \
               &uvs[buf][t * 8]);                                              \
  } while (0)

  STAGE(0, 0);

  for (int cid = 0; cid < NCH; ++cid) {
    const int cur = cid & 1;
    {
      const int e = t & 15, d0 = (t >> 4) * 8;
      bfrag sb;
#pragma unroll
      for (int i = 0; i < 8; ++i) sb[i] = (short)f2bf(Sf[(d0 + i) * 20 + e]);
      *reinterpret_cast<bfrag*>(&Sb[e * 136 + d0]) = sb;
    }
    __syncthreads();

    if (cid + 1 < NCH) STAGE(cur ^ 1, cid + 1);

    ffrag uacc;
#pragma unroll
    for (int j = 0; j < 4; ++j)
      uacc[j] = bf2f(uvs[cur][(16 * w + 4 * hi + j) * 16 + rr]);
#pragma unroll
    for (int ks = 0; ks < 4; ++ks) {
      const bfrag af = *reinterpret_cast<const bfrag*>(
          &Ws[cur][(16 * w + rr) * 128 + (((4 * ks + hi) ^ rr) * 8)]);
      const bfrag bf_ = *reinterpret_cast<const bfrag*>(&Sb[rr * 136 + ks * 32 + hi * 8]);
      uacc = MFMA(af, bf_, uacc, 0, 0, 0);
    }
#pragma unroll
    for (int j = 0; j < 4; ++j)
      ub[(16 * w + 4 * hi + j) * 18 + rr] = f2bf(uacc[j]);
    __syncthreads();

    {
      ffrag oacc;
#pragma unroll
      for (int j = 0; j < 4; ++j) oacc[j] = 0.f;
#pragma unroll
      for (int ks = 0; ks < 4; ++ks) {
        const bfrag af = *reinterpret_cast<const bfrag*>(
            &qs[cur][(16 * w + rr) * 128 + (((4 * ks + hi) ^ rr) * 8)]);
        const bfrag bf_ = *reinterpret_cast<const bfrag*>(&Sb[rr * 136 + ks * 32 + hi * 8]);
        oacc = MFMA(af, bf_, oacc, 0, 0, 0);
      }
      const int nks = (w < 2) ? 1 : 2;
      for (int ks = 0; ks < nks; ++ks) {
        bfrag ubf;
#pragma unroll
        for (int j = 0; j < 8; ++j)
          ubf[j] = (short)ub[(32 * ks + 8 * hi + j) * 18 + rr];
        const bfrag af = *reinterpret_cast<const bfrag*>(
            &ats[cur][(16 * w + rr) * 64 + (((4 * ks + hi) ^ (rr & 7)) * 8)]);
        oacc = MFMA(af, ubf, oacc, 0, 0, 0);
      }
      us* og = uv_o + rowbase0 + (size_t)(cid * CH) * D_;
#pragma unroll
      for (int j = 0; j < 4; ++j)
        og[(size_t)(16 * w + 4 * hi + j) * D_ + rr] = f2bf(oacc[j]);
    }

    {
      bfrag ubf[2];
#pragma unroll
      for (int ks = 0; ks < 2; ++ks)
#pragma unroll
        for (int j = 0; j < 8; ++j)
          ubf[ks][j] = (short)ub[(32 * ks + 8 * hi + j) * 18 + rr];
#pragma unroll
      for (int t2 = 0; t2 < 2; ++t2) {
        const int tile = 2 * w + t2;
        ffrag sacc;
#pragma unroll
        for (int j = 0; j < 4; ++j) sacc[j] = Sf[(16 * tile + 4 * hi + j) * 20 + rr];
#pragma unroll
        for (int ks = 0; ks < 2; ++ks) {
          const bfrag af = *reinterpret_cast<const bfrag*>(
              &kTs[cur][(16 * tile + rr) * 64 + (((4 * ks + hi) ^ (rr & 7)) * 8)]);
          sacc = MFMA(af, ubf[ks], sacc, 0, 0, 0);
        }
#pragma unroll
        for (int j = 0; j < 4; ++j) Sf[(16 * tile + 4 * hi + j) * 20 + rr] = sacc[j];
      }
    }
    __syncthreads();
  }
#undef STAGE
}

// ---------------------------------------------------------------------------
// per-head RMSNorm (over 128) * onorm_w : bf16 in -> bf16 out
// ---------------------------------------------------------------------------
__global__ __launch_bounds__(256) void rms_onorm_bf16(const us* __restrict__ in,
                                                      const float* __restrict__ w,
                                                      us* __restrict__ out) {
  const int bt = blockIdx.x;
  const int d0 = threadIdx.x * 8;
  const us* p = in + (size_t)bt * D_ + d0;
  const ushort4 a = *reinterpret_cast<const ushort4*>(p);
  const ushort4 b = *reinterpret_cast<const ushort4*>(p + 4);
  float v[8] = {bf2f(a.x), bf2f(a.y), bf2f(a.z), bf2f(a.w),
                bf2f(b.x), bf2f(b.y), bf2f(b.z), bf2f(b.w)};
  float ss = 0.f;
#pragma unroll
  for (int j = 0; j < 8; ++j) ss = fmaf(v[j], v[j], ss);
  ss += __shfl_xor(ss, 1);
  ss += __shfl_xor(ss, 2);
  ss += __shfl_xor(ss, 4);
  ss += __shfl_xor(ss, 8);
  const float sc = rsqrtf(ss * (1.0f / 128.0f) + 1e-5f);
  const int hd = d0 & 127;
  ushort4 o0, o1;
  o0.x = f2bf(v[0] * sc * w[hd + 0]); o0.y = f2bf(v[1] * sc * w[hd + 1]);
  o0.z = f2bf(v[2] * sc * w[hd + 2]); o0.w = f2bf(v[3] * sc * w[hd + 3]);
  o1.x = f2bf(v[4] * sc * w[hd + 4]); o1.y = f2bf(v[5] * sc * w[hd + 5]);
  o1.z = f2bf(v[6] * sc * w[hd + 6]); o1.w = f2bf(v[7] * sc * w[hd + 7]);
  us* op = out + (size_t)bt * D_ + d0;
  *reinterpret_cast<ushort4*>(op) = o0;
  *reinterpret_cast<ushort4*>(op + 4) = o1;
}

// ---------------------------------------------------------------------------
extern "C" void kernel_launch(void* const* d_in, const int* in_sizes, int n_in,
                              void* d_out, int out_size, void* d_ws, size_t ws_size,
                              hipStream_t stream) {
  const float* x  = (const float*)d_in[0];
  const float* Wq = (const float*)d_in[1];
  const float* Wk = (const float*)d_in[2];
  const float* Wv = (const float*)d_in[3];
  const float* Wb = (const float*)d_in[4];
  const float* Wo = (const float*)d_in[5];
  const float* cq = (const float*)d_in[6];
  const float* ck = (const float*)d_in[7];
  const float* cv = (const float*)d_in[8];
  const float* ow = (const float*)d_in[9];
  float* out = (float*)d_out;

  // workspace: 5*NE + D*D bf16 units = 176.2 MB (proven-safe footprint)
  const size_t NE = (size_t)M_ * D_;
  us* ws   = (us*)d_ws;
  us* gout = ws;              // [M,D] gemm scratch; later attn chunks + betaT
  us* qch  = ws + NE;         // q swizzled chunk layout
  us* kch  = ws + 2 * NE;     // k swizzled chunk layout
  us* Wch  = ws + 3 * NE;     // -W swizzled chunk layout
  us* kTch = ws + 4 * NE;     // kT swizzled chunk; after seq: rms-out [M,D]
  us* wt   = ws + 5 * NE;     // [D,D] W^T (reused 4x)
  us* attb = gout;                                  // [2048][64][64]
  float* betaT = (float*)(gout + 12 * 1024 * 1024); // [32][4096] f32
  // d_out as bf16 scratch: xb [0,NE), v/uv/o [NE,2NE)
  us* xb = (us*)d_out;
  us* vb = xb + NE;

  dim3 gg(D_ / 128, M_ / 128);
  dim3 wg(D_ / 64, D_ / 64);

  to_bf16<<<NE / 2048, 256, 0, stream>>>(x, xb);

  wtrans<<<wg, 256, 0, stream>>>(Wv, wt);
  gemm_bf16<false><<<gg, 256, 0, stream>>>(xb, wt, gout, M_, D_, D_);
  conv_silu_plain<<<M_, 256, 0, stream>>>(gout, cv, vb);

  wtrans<<<wg, 256, 0, stream>>>(Wq, wt);
  gemm_bf16<false><<<gg, 256, 0, stream>>>(xb, wt, gout, M_, D_, D_);
  conv_silu_chunk<<<M_, 256, 0, stream>>>(gout, cq, qch, 2);

  wtrans<<<wg, 256, 0, stream>>>(Wk, wt);
  gemm_bf16<false><<<gg, 256, 0, stream>>>(xb, wt, gout, M_, D_, D_);
  conv_silu_chunk<<<M_, 256, 0, stream>>>(gout, ck, kch, 1);

  beta_sigmoid<<<M_ / 4, 256, 0, stream>>>(x, Wb, betaT);

  delta_prep<<<32 * NCH, 256, 0, stream>>>(qch, kch, betaT, vb, Wch, kTch, attb);
  delta_seq<<<256, 256, 0, stream>>>(qch, Wch, kTch, attb, vb);

  rms_onorm_bf16<<<M_, 256, 0, stream>>>(vb, ow, kTch);

  wtrans<<<wg, 256, 0, stream>>>(Wo, wt);
  gemm_bf16<true><<<gg, 256, 0, stream>>>(kTch, wt, out, M_, D_, D_);
}

// Round 8
// 786.491 us; speedup vs baseline: 13.2995x; 1.0158x over previous
//
#include <hip/hip_runtime.h>
#include <math.h>

#define B_ 2
#define T_ 4096
#define D_ 2048
#define H_ 16
#define DK 128
#define DV 128
#define CH 64
#define M_ (B_ * T_)  // 8192
#define NCH (T_ / CH) // 64 chunks

typedef __attribute__((ext_vector_type(8))) short bfrag;   // 8 bf16
typedef __attribute__((ext_vector_type(4))) float ffrag;   // 4 f32 acc
typedef __attribute__((ext_vector_type(8))) unsigned short u16x8;
typedef unsigned short us;

#define MFMA __builtin_amdgcn_mfma_f32_16x16x32_bf16

__device__ inline us f2bf(float f) {
  union { float f; unsigned u; } v; v.f = f;
  unsigned r = v.u + 0x7fffu + ((v.u >> 16) & 1u);
  return (us)(r >> 16);
}
__device__ inline float bf2f(us u) {
  union { unsigned u; float f; } v; v.u = ((unsigned)u) << 16;
  return v.f;
}

// async global->LDS, 16B per lane (dest = wave-uniform base + lane*16)
__device__ inline void gl_lds16(const us* g, us* l) {
  __builtin_amdgcn_global_load_lds(
      (const __attribute__((address_space(1))) void*)g,
      (__attribute__((address_space(3))) void*)l, 16, 0, 0);
}

// ---------------------------------------------------------------------------
// flat f32 -> bf16 (8 elems/thread)
// ---------------------------------------------------------------------------
__global__ __launch_bounds__(256) void to_bf16(const float* __restrict__ in,
                                               us* __restrict__ out) {
  const size_t i = ((size_t)blockIdx.x * 256 + threadIdx.x) * 8;
  const float4 a = *reinterpret_cast<const float4*>(in + i);
  const float4 b = *reinterpret_cast<const float4*>(in + i + 4);
  ushort4 o0, o1;
  o0.x = f2bf(a.x); o0.y = f2bf(a.y); o0.z = f2bf(a.z); o0.w = f2bf(a.w);
  o1.x = f2bf(b.x); o1.y = f2bf(b.y); o1.z = f2bf(b.z); o1.w = f2bf(b.w);
  *reinterpret_cast<ushort4*>(out + i) = o0;
  *reinterpret_cast<ushort4*>(out + i + 4) = o1;
}

// ---------------------------------------------------------------------------
// transpose + convert: Wt[n][k] = bf16(W[k][n]), 64x64 tiles
// ---------------------------------------------------------------------------
__global__ __launch_bounds__(256) void wtrans(const float* __restrict__ W,
                                              us* __restrict__ Wt) {
  __shared__ float tile[64][68];
  const int k0 = blockIdx.y * 64, n0 = blockIdx.x * 64;
  const int lr = threadIdx.x >> 4, lc = (threadIdx.x & 15) * 4;
#pragma unroll
  for (int p = 0; p < 4; ++p) {
    const int r = lr + p * 16;
    *reinterpret_cast<float4*>(&tile[r][lc]) =
        *reinterpret_cast<const float4*>(&W[(size_t)(k0 + r) * D_ + n0 + lc]);
  }
  __syncthreads();
#pragma unroll
  for (int p = 0; p < 4; ++p) {
    const int r = lr + p * 16;
    ushort4 o;
    o.x = f2bf(tile[lc + 0][r]); o.y = f2bf(tile[lc + 1][r]);
    o.z = f2bf(tile[lc + 2][r]); o.w = f2bf(tile[lc + 3][r]);
    *reinterpret_cast<ushort4*>(&Wt[(size_t)(n0 + r) * D_ + k0 + lc]) = o;
  }
}

// ---------------------------------------------------------------------------
// bf16 MFMA GEMM (m97 structure) + T1 XCD-aware block swizzle.
// ---------------------------------------------------------------------------
template <bool OUTF32>
__global__ __launch_bounds__(256) void gemm_bf16(const us* __restrict__ A,
                                                 const us* __restrict__ Bt,
                                                 void* __restrict__ Cp,
                                                 int M, int N, int K) {
  __shared__ __align__(16) us As[128 * 32];
  __shared__ __align__(16) us Bs[128 * 32];
  const int t = threadIdx.x, l = t & 63, w = t >> 6;
  // XCD swizzle: nwg multiple of 8 by construction
  const int nwg = gridDim.x * gridDim.y;
  const int lin = blockIdx.y * gridDim.x + blockIdx.x;
  const int swz = (lin & 7) * (nwg >> 3) + (lin >> 3);
  const int m0 = (swz / gridDim.x) * 128, n0 = (swz % gridDim.x) * 128;
  const int wr = w >> 1, wc = w & 1;
  const int sr = t >> 2, sp = (t & 3) * 8;
  const int fr = l & 15, fs = (l >> 4) * 8;

  ffrag acc[4][4];
#pragma unroll
  for (int mi = 0; mi < 4; ++mi)
#pragma unroll
    for (int ni = 0; ni < 4; ++ni)
#pragma unroll
      for (int e = 0; e < 4; ++e) acc[mi][ni][e] = 0.f;

  const us* Ag0 = A + (size_t)(m0 + sr) * K + sp;
  const us* Ag1 = A + (size_t)(m0 + sr + 64) * K + sp;
  const us* Bg0 = Bt + (size_t)(n0 + sr) * K + sp;
  const us* Bg1 = Bt + (size_t)(n0 + sr + 64) * K + sp;
  us* Al0 = As + sr * 32 + sp;
  us* Al1 = As + (sr + 64) * 32 + sp;
  us* Bl0 = Bs + sr * 32 + sp;
  us* Bl1 = Bs + (sr + 64) * 32 + sp;

  for (int k0 = 0; k0 < K; k0 += 32) {
    __syncthreads();
    gl_lds16(Ag0 + k0, Al0);
    gl_lds16(Ag1 + k0, Al1);
    gl_lds16(Bg0 + k0, Bl0);
    gl_lds16(Bg1 + k0, Bl1);
    __syncthreads();
    bfrag af[4], bfr[4];
#pragma unroll
    for (int mi = 0; mi < 4; ++mi)
      af[mi] = *reinterpret_cast<const bfrag*>(As + (wr * 64 + mi * 16 + fr) * 32 + fs);
#pragma unroll
    for (int ni = 0; ni < 4; ++ni)
      bfr[ni] = *reinterpret_cast<const bfrag*>(Bs + (wc * 64 + ni * 16 + fr) * 32 + fs);
#pragma unroll
    for (int mi = 0; mi < 4; ++mi)
#pragma unroll
      for (int ni = 0; ni < 4; ++ni)
        acc[mi][ni] = MFMA(af[mi], bfr[ni], acc[mi][ni], 0, 0, 0);
  }
  const int cr = (l >> 4) * 4, cc = l & 15;
#pragma unroll
  for (int mi = 0; mi < 4; ++mi)
#pragma unroll
    for (int ni = 0; ni < 4; ++ni)
#pragma unroll
      for (int j = 0; j < 4; ++j) {
        const size_t idx = (size_t)(m0 + wr * 64 + mi * 16 + cr + j) * N +
                           n0 + wc * 64 + ni * 16 + cc;
        if constexpr (OUTF32) ((float*)Cp)[idx] = acc[mi][ni][j];
        else ((us*)Cp)[idx] = f2bf(acc[mi][ni][j]);
      }
}

// ---------------------------------------------------------------------------
// conv+silu bodies
// ---------------------------------------------------------------------------
__device__ inline void conv_body(const us* __restrict__ in, const float* cw,
                                 int bt, int d0, int mode, float v[8]) {
  const int tb = bt & (T_ - 1);
  const us* row = in + (size_t)bt * D_ + d0;
#pragma unroll
  for (int j = 0; j < 8; ++j) v[j] = 0.f;
#pragma unroll
  for (int j = 0; j < 4; ++j) {
    if (tb >= j) {
      const us* rp = row - (size_t)(j * D_);
      const ushort4 a = *reinterpret_cast<const ushort4*>(rp);
      const ushort4 b = *reinterpret_cast<const ushort4*>(rp + 4);
      const float wj = cw[3 - j];
      v[0] = fmaf(wj, bf2f(a.x), v[0]); v[1] = fmaf(wj, bf2f(a.y), v[1]);
      v[2] = fmaf(wj, bf2f(a.z), v[2]); v[3] = fmaf(wj, bf2f(a.w), v[3]);
      v[4] = fmaf(wj, bf2f(b.x), v[4]); v[5] = fmaf(wj, bf2f(b.y), v[5]);
      v[6] = fmaf(wj, bf2f(b.z), v[6]); v[7] = fmaf(wj, bf2f(b.w), v[7]);
    }
  }
#pragma unroll
  for (int j = 0; j < 8; ++j) v[j] = v[j] / (1.f + expf(-v[j]));
  if (mode) {
    float ss = 0.f;
#pragma unroll
    for (int j = 0; j < 8; ++j) ss = fmaf(v[j], v[j], ss);
    ss += __shfl_xor(ss, 1);
    ss += __shfl_xor(ss, 2);
    ss += __shfl_xor(ss, 4);
    ss += __shfl_xor(ss, 8);
    float sc = rsqrtf(ss + 1e-6f);
    if (mode == 2) sc *= 0.08838834764831845f;  // 128^-0.5
#pragma unroll
    for (int j = 0; j < 8; ++j) v[j] *= sc;
  }
}

__global__ __launch_bounds__(256) void conv_silu_plain(const us* __restrict__ in,
                                                       const float* __restrict__ cw,
                                                       us* __restrict__ out) {
  const int bt = blockIdx.x, d0 = threadIdx.x * 8;
  float v[8];
  conv_body(in, cw, bt, d0, 0, v);
  ushort4 o0, o1;
  o0.x = f2bf(v[0]); o0.y = f2bf(v[1]); o0.z = f2bf(v[2]); o0.w = f2bf(v[3]);
  o1.x = f2bf(v[4]); o1.y = f2bf(v[5]); o1.z = f2bf(v[6]); o1.w = f2bf(v[7]);
  us* op = out + (size_t)bt * D_ + d0;
  *reinterpret_cast<ushort4*>(op) = o0;
  *reinterpret_cast<ushort4*>(op + 4) = o1;
}

// conv+silu+l2norm -> swizzled chunk layout [bh][cid][64][128], 16B-group XOR(r&15)
__global__ __launch_bounds__(256) void conv_silu_chunk(const us* __restrict__ in,
                                                       const float* __restrict__ cw,
                                                       us* __restrict__ out,
                                                       int mode) {
  const int bt = blockIdx.x, d0 = threadIdx.x * 8;
  float v[8];
  conv_body(in, cw, bt, d0, mode, v);
  const int b = bt >> 12, tt = bt & (T_ - 1);
  const int cid = tt >> 6, r = tt & 63;
  const int h = d0 >> 7, g = (d0 & 127) >> 3;
  us* dst = out + ((size_t)((b * H_ + h) * NCH + cid)) * (CH * DK) +
            r * 128 + ((g ^ (r & 15)) * 8);
  ushort4 o0, o1;
  o0.x = f2bf(v[0]); o0.y = f2bf(v[1]); o0.z = f2bf(v[2]); o0.w = f2bf(v[3]);
  o1.x = f2bf(v[4]); o1.y = f2bf(v[5]); o1.z = f2bf(v[6]); o1.w = f2bf(v[7]);
  *reinterpret_cast<ushort4*>(dst) = o0;
  *reinterpret_cast<ushort4*>(dst + 4) = o1;
}

// ---------------------------------------------------------------------------
// beta = sigmoid(x @ Wb) -> [bh][T] layout (contiguous for prep)
// ---------------------------------------------------------------------------
__global__ __launch_bounds__(256) void beta_sigmoid(const float* __restrict__ x,
                                                    const float* __restrict__ Wb,
                                                    float* __restrict__ betaT) {
  const int t = threadIdx.x;
  const int m = blockIdx.x * 4 + (t >> 6);
  const int l = t & 63;
  const int c = l & 15;
  const int s = l >> 4;
  const float* xr = x + (size_t)m * D_;
  const int kb = s * (D_ / 4);
  float acc = 0.f;
  for (int k = 0; k < D_ / 4; ++k)
    acc = fmaf(xr[kb + k], Wb[(size_t)(kb + k) * H_ + c], acc);
  acc += __shfl_xor(acc, 16);
  acc += __shfl_xor(acc, 32);
  if (l < 16) {
    const int b = m >> 12, tt = m & (T_ - 1);
    betaT[((size_t)(b * H_ + c)) * T_ + tt] = 1.f / (1.f + expf(-acc));
  }
}

// ---------------------------------------------------------------------------
// f32 blocked product step for T = M^-1: T[I][J] = -T_II * (sum_K M[I][K] T[K][J])
// ---------------------------------------------------------------------------
__device__ inline void prod_step(float* Tf, const float* Am, float* xbuf,
                                 int r, int c, int I, int J,
                                 int nk, int K0, int K1, int K2) {
  float X = 0.f;
  const int Ks[3] = {K0, K1, K2};
  for (int kk = 0; kk < nk; ++kk) {
    const int K = Ks[kk];
    const float* amrow = Am + (16 * I + r) * 72 + 16 * K;
    const float* tcol = Tf + (16 * K) * 68 + 16 * J + c;
#pragma unroll
    for (int m = 0; m < 16; ++m) X = fmaf(amrow[m], tcol[m * 68], X);
  }
  __syncthreads();               // prior step's xbuf readers done
  xbuf[r * 17 + c] = X;
  __syncthreads();               // xbuf ready
  float s = 0.f;
  const float* trow = Tf + (16 * I + r) * 68 + 16 * I;
#pragma unroll
  for (int m = 0; m < 16; ++m) s = fmaf(trow[m], xbuf[m * 17 + c], s);
  Tf[(16 * I + r) * 68 + 16 * J + c] = -s;   // disjoint from reads above
  __syncthreads();               // block (I,J) visible for next step
}

// ---------------------------------------------------------------------------
// delta_prep v2 (proven R6): block per (b,h,chunk) = 2048, 256 thr, 2 blocks/CU.
// ---------------------------------------------------------------------------
__global__ __launch_bounds__(256, 2) void delta_prep(const us* __restrict__ qch,
                                                     const us* __restrict__ kch,
                                                     const float* __restrict__ betaT,
                                                     us* __restrict__ v_uv,
                                                     us* __restrict__ Wout,
                                                     us* __restrict__ kTout,
                                                     us* __restrict__ Aout) {
  __shared__ __align__(16) unsigned char lds[72000];
  us*    ks    = (us*)(lds);             // [64*128] swz     (P0-P1)
  us*    Tb    = (us*)(lds);             // [64][72] bf16    (P5-)
  float* Am    = (float*)(lds + 16384);  // [64][72] f32     (P1-P4)
  us*    vTb   = (us*)(lds + 16384);     // [128][72] bf16   (P5-)
  float* Tf    = (float*)(lds + 34816);  // [64][68] f32     (P2-P5)
  us*    atst  = (us*)(lds + 34816);     // attn stage [64*64] (P0-P2)
  us*    Wst   = (us*)(lds + 34816);     // W stage [64*128] (P6-)
  us*    kTb   = (us*)(lds + 52224);     // [128][72] bf16   (P1-P6a)
  us*    UVst  = (us*)(lds + 52224);     // [64*128]         (P6b-)
  float* betac = (float*)(lds + 70656);  // [64]
  float* xbuf  = (float*)(lds + 70912);  // [16][17]

  const int t = threadIdx.x, w = t >> 6, l = t & 63;
  const int rr = l & 15, hi = l >> 4;
  const int bx = blockIdx.x;
  const int bh = bx >> 6, cid = bx & 63;
  const int b = bh >> 4, h = bh & 15;
  const size_t rowbase = ((size_t)b * T_ + (size_t)cid * CH) * D_ + (size_t)h * DK;
  const size_t cbase = (size_t)bx * (CH * DK);
  const size_t abase = (size_t)bx * (CH * CH);

  // ---- P0: stage ks, zero attn-stage, betac
  {
    const us* kg = kch + cbase;
#pragma unroll
    for (int p = 0; p < 4; ++p)
      gl_lds16(kg + p * 2048 + t * 8, ks + p * 2048 + t * 8);
    const float4 z = make_float4(0.f, 0.f, 0.f, 0.f);
    *reinterpret_cast<float4*>(atst + t * 16) = z;
    *reinterpret_cast<float4*>(atst + t * 16 + 8) = z;
    if (t < 64) betac[t] = betaT[(size_t)bh * T_ + cid * CH + t];
  }
  __syncthreads();

  // ---- P1: A MFMA (beta-scaled strict-tril -> Am f32), attn MFMA -> atst,
  //          kTb build (plain k^T bf16)
  {
    bfrag qf[4], kf[4];
#pragma unroll
    for (int k4 = 0; k4 < 4; ++k4) {
      const int go = ((4 * k4 + hi) ^ rr) * 8;
      qf[k4] = *reinterpret_cast<const bfrag*>(qch + cbase + (16 * w + rr) * 128 + go);
      kf[k4] = *reinterpret_cast<const bfrag*>(ks + (16 * w + rr) * 128 + go);
    }
    for (int jt = 0; jt <= w; ++jt) {
      ffrag accA = {0.f, 0.f, 0.f, 0.f}, accQ = {0.f, 0.f, 0.f, 0.f};
#pragma unroll
      for (int k4 = 0; k4 < 4; ++k4) {
        const bfrag bfr = *reinterpret_cast<const bfrag*>(
            ks + (16 * jt + rr) * 128 + (((4 * k4 + hi) ^ rr) * 8));
        accA = MFMA(kf[k4], bfr, accA, 0, 0, 0);
        accQ = MFMA(qf[k4], bfr, accQ, 0, 0, 0);
      }
#pragma unroll
      for (int j4 = 0; j4 < 4; ++j4) {
        const int i = 16 * w + 4 * hi + j4, j = 16 * jt + rr;
        Am[i * 72 + j] = (j < i) ? betac[i] * accA[j4] : 0.f;
        if (j <= i)
          atst[i * 64 + (((j >> 3) ^ (i & 7)) * 8) + (j & 7)] = f2bf(accQ[j4]);
      }
    }
    const int r = t & 63, part = t >> 6;
#pragma unroll
    for (int gi = 0; gi < 4; ++gi) {
      const int g = 4 * part + gi;
      const u16x8 kv = *reinterpret_cast<const u16x8*>(ks + r * 128 + ((g ^ (r & 15)) * 8));
#pragma unroll
      for (int j = 0; j < 8; ++j) kTb[(g * 8 + j) * 72 + r] = kv[j];
    }
  }
  __syncthreads();

  // ---- P2: copy attn + kT to global; then zero Tf (same region as atst!)
  {
#pragma unroll
    for (int p = 0; p < 2; ++p) {
      const int unit = t + p * 256;
      *reinterpret_cast<u16x8*>(Aout + abase + unit * 8) =
          *reinterpret_cast<const u16x8*>(atst + unit * 8);
    }
#pragma unroll
    for (int p = 0; p < 4; ++p) {
      const int unit = t + p * 256;
      const int d = unit >> 3, sg = unit & 7;
      *reinterpret_cast<u16x8*>(kTout + cbase + unit * 8) =
          *reinterpret_cast<const u16x8*>(kTb + d * 72 + ((sg ^ (d & 7)) * 8));
    }
  }
  __syncthreads();  // atst reads done before Tf overwrite
  for (int i = t; i < 64 * 68; i += 256) Tf[i] = 0.f;
  __syncthreads();

  // ---- P3: four 16x16 unit-lower diagonal inverses (64 threads)
  if (t < 64) {
    const int blk = t >> 4, j = t & 15, bd = blk * 16;
    Tf[(bd + j) * 68 + bd + j] = 1.f;
    for (int i = j + 1; i < 16; ++i) {
      float s = 0.f;
      for (int m = j; m < i; ++m)
        s = fmaf(Am[(bd + i) * 72 + bd + m], Tf[(bd + m) * 68 + bd + j], s);
      Tf[(bd + i) * 68 + bd + j] = -s;
    }
  }
  __syncthreads();

  // ---- P4: off-diagonal blocks of T (f32, all 256 threads)
  {
    const int r = t >> 4, c = t & 15;
    prod_step(Tf, Am, xbuf, r, c, 1, 0, 1, 0, 0, 0);
    prod_step(Tf, Am, xbuf, r, c, 2, 0, 2, 0, 1, 0);
    prod_step(Tf, Am, xbuf, r, c, 3, 0, 3, 0, 1, 2);
    prod_step(Tf, Am, xbuf, r, c, 2, 1, 1, 1, 0, 0);
    prod_step(Tf, Am, xbuf, r, c, 3, 1, 2, 1, 2, 0);
    prod_step(Tf, Am, xbuf, r, c, 3, 2, 1, 2, 0, 0);
  }

  // ---- P5: Tb = bf16(T * diag(beta)) into ks region; vTb = v^T into Am region
  {
    const int vr = t >> 2, vp = t & 3;
    u16x8 vv[4];
#pragma unroll
    for (int g = 0; g < 4; ++g)
      vv[g] = *reinterpret_cast<const u16x8*>(v_uv + rowbase + (size_t)vr * D_ +
                                              vp * 32 + g * 8);
    const int ti = t >> 2, tg = t & 3;
    u16x8 w0, w1;
#pragma unroll
    for (int jj = 0; jj < 8; ++jj) {
      const int j0 = tg * 16 + jj, j1 = j0 + 8;
      w0[jj] = f2bf(Tf[ti * 68 + j0] * betac[j0]);
      w1[jj] = f2bf(Tf[ti * 68 + j1] * betac[j1]);
    }
    *reinterpret_cast<u16x8*>(Tb + ti * 72 + tg * 16) = w0;
    *reinterpret_cast<u16x8*>(Tb + ti * 72 + tg * 16 + 8) = w1;
#pragma unroll
    for (int g = 0; g < 4; ++g)
#pragma unroll
      for (int j = 0; j < 8; ++j)
        vTb[(vp * 32 + g * 8 + j) * 72 + vr] = vv[g][j];
  }
  __syncthreads();

  // ---- P6a: W = -(Tb . kTb) -> Wst (swz16)
  {
    bfrag ta[2];
#pragma unroll
    for (int k2 = 0; k2 < 2; ++k2)
      ta[k2] = *reinterpret_cast<const bfrag*>(Tb + (16 * w + rr) * 72 + 32 * k2 + 8 * hi);
#pragma unroll
    for (int dt = 0; dt < 8; ++dt) {
      ffrag acc = {0.f, 0.f, 0.f, 0.f};
#pragma unroll
      for (int k2 = 0; k2 < 2; ++k2) {
        const bfrag bfr = *reinterpret_cast<const bfrag*>(
            kTb + (16 * dt + rr) * 72 + 32 * k2 + 8 * hi);
        acc = MFMA(ta[k2], bfr, acc, 0, 0, 0);
      }
#pragma unroll
      for (int j4 = 0; j4 < 4; ++j4) {
        const int i = 16 * w + 4 * hi + j4, d = 16 * dt + rr;
        Wst[i * 128 + (((d >> 3) ^ (i & 15)) * 8) + (d & 7)] = f2bf(-acc[j4]);
      }
    }
  }
  __syncthreads();  // kTb reads done (UVst may overwrite); Wst complete

  // ---- P6b: UV = Tb . vTb -> UVst; copy W out
  {
    bfrag ta[2];
#pragma unroll
    for (int k2 = 0; k2 < 2; ++k2)
      ta[k2] = *reinterpret_cast<const bfrag*>(Tb + (16 * w + rr) * 72 + 32 * k2 + 8 * hi);
#pragma unroll
    for (int et = 0; et < 8; ++et) {
      ffrag acc = {0.f, 0.f, 0.f, 0.f};
#pragma unroll
      for (int k2 = 0; k2 < 2; ++k2) {
        const bfrag bfr = *reinterpret_cast<const bfrag*>(
            vTb + (16 * et + rr) * 72 + 32 * k2 + 8 * hi);
        acc = MFMA(ta[k2], bfr, acc, 0, 0, 0);
      }
#pragma unroll
      for (int j4 = 0; j4 < 4; ++j4)
        UVst[(16 * w + 4 * hi + j4) * 128 + 16 * et + rr] = f2bf(acc[j4]);
    }
#pragma unroll
    for (int p = 0; p < 4; ++p) {
      const int unit = t + p * 256;
      *reinterpret_cast<u16x8*>(Wout + cbase + unit * 8) =
          *reinterpret_cast<const u16x8*>(Wst + unit * 8);
    }
  }
  __syncthreads();

  // ---- P7: copy u_v out (in-place over v, row-major [M,D])
#pragma unroll
  for (int p = 0; p < 4; ++p) {
    const int unit = t + p * 256;
    const int r = unit >> 4, g = unit & 15;
    *reinterpret_cast<u16x8*>(v_uv + rowbase + (size_t)r * D_ + g * 8) =
        *reinterpret_cast<const u16x8*>(UVst + r * 128 + g * 8);
  }
}

// ---------------------------------------------------------------------------
// delta_seq v3 (MFMA + T4 counted-vmcnt + register-resident S).
// 256 blocks x 256 threads (4 waves). Per chunk (2 raw barriers):
//   u = uv + (-W)·Sb[cs] ; o = q·Sb[cs] + attn·u ; Sreg += kT·u -> Sb[cs^1]
// Staged loads stay in flight across the mid barrier (lgkmcnt-only wait);
// single vmcnt(0) drain at end-of-chunk gives them the full compute phase.
// ---------------------------------------------------------------------------
__global__ __launch_bounds__(256, 1) void delta_seq(const us* __restrict__ qch,
                                                    const us* __restrict__ Wch,
                                                    const us* __restrict__ kTch,
                                                    const us* __restrict__ atch,
                                                    us* __restrict__ uv_o) {
  __shared__ __align__(16) us qs[2][CH * DK];    // 16KB x2
  __shared__ __align__(16) us Ws[2][CH * DK];    // 16KB x2
  __shared__ __align__(16) us kTs[2][DK * CH];   // 16KB x2
  __shared__ __align__(16) us ats[2][CH * CH];   // 8KB  x2
  __shared__ __align__(16) us uvs[2][CH * 16];   // 2KB  x2
  __shared__ __align__(16) us Sb[2][16 * 136];   // 4.25KB x2 (S^T bf16, dbuf)
  __shared__ __align__(16) us ub[CH * 18];       // 2.25KB (u bf16)

  const int t = threadIdx.x, l = t & 63, w = t >> 6;
  const int bx = blockIdx.x;
  const int vs = bx >> 5, bh = bx & 31;
  const int b = bh >> 4, h = bh & 15;
  const int rr = l & 15, hi = l >> 4;

  // S lives in registers: wave w owns rows 32w..32w+31 (2 tiles), col rr per lane
  ffrag sacc[2];
#pragma unroll
  for (int t2 = 0; t2 < 2; ++t2)
#pragma unroll
    for (int j = 0; j < 4; ++j) sacc[t2][j] = 0.f;

  for (int i = t; i < 16 * 136; i += 256) Sb[0][i] = 0;

  const size_t cbQ = (size_t)(bh * NCH) * (CH * DK);
  const size_t cbA = (size_t)(bh * NCH) * (CH * CH);
  const size_t rowbase0 = ((size_t)b * T_) * D_ + (size_t)h * DK + vs * 16;

#define STAGE(buf, cid)                                                        \
  do {                                                                         \
    const us* qg = qch + cbQ + (size_t)(cid) * (CH * DK);                      \
    const us* Wg = Wch + cbQ + (size_t)(cid) * (CH * DK);                      \
    const us* kg = kTch + cbQ + (size_t)(cid) * (CH * DK);                     \
    const us* ag = atch + cbA + (size_t)(cid) * (CH * CH);                     \
    _Pragma("unroll")                                                          \
    for (int p = 0; p < 4; ++p) {                                              \
      gl_lds16(qg + p * 2048 + t * 8, &qs[buf][p * 2048 + t * 8]);             \
      gl_lds16(Wg + p * 2048 + t * 8, &Ws[buf][p * 2048 + t * 8]);             \
      gl_lds16(kg + p * 2048 + t * 8, &kTs[buf][p * 2048 + t * 8]);            \
    }                                                                          \
    _Pragma("unroll")                                                          \
    for (int p = 0; p < 2; ++p)                                                \
      gl_lds16(ag + p * 2048 + t * 8, &ats[buf][p * 2048 + t * 8]);            \
    if (t < 128)                                                               \
      gl_lds16(uv_o + rowbase0 + (size_t)((cid) * CH + (t >> 1)) * D_ + (t & 1) * 8, \
               &uvs[buf][t * 8]);                                              \
  } while (0)

  STAGE(0, 0);
  asm volatile("s_waitcnt vmcnt(0) lgkmcnt(0)" ::: "memory");
  __builtin_amdgcn_s_barrier();
  __builtin_amdgcn_sched_barrier(0);

  for (int cid = 0; cid < NCH; ++cid) {
    const int cur = cid & 1;
    if (cid + 1 < NCH) STAGE(cur ^ 1, cid + 1);  // async; drained at end barrier

    // Sb fragments (shared by u- and o-phases)
    bfrag sbf[4];
#pragma unroll
    for (int ks = 0; ks < 4; ++ks)
      sbf[ks] = *reinterpret_cast<const bfrag*>(&Sb[cur][rr * 136 + ks * 32 + hi * 8]);

    // ---- u-phase: wave w owns rows 16w..16w+15
    {
      ffrag uacc;
#pragma unroll
      for (int j = 0; j < 4; ++j)
        uacc[j] = bf2f(uvs[cur][(16 * w + 4 * hi + j) * 16 + rr]);
#pragma unroll
      for (int ks = 0; ks < 4; ++ks) {
        const bfrag af = *reinterpret_cast<const bfrag*>(
            &Ws[cur][(16 * w + rr) * 128 + (((4 * ks + hi) ^ rr) * 8)]);
        uacc = MFMA(af, sbf[ks], uacc, 0, 0, 0);
      }
#pragma unroll
      for (int j = 0; j < 4; ++j)
        ub[(16 * w + 4 * hi + j) * 18 + rr] = f2bf(uacc[j]);
    }
    asm volatile("s_waitcnt lgkmcnt(0)" ::: "memory");  // ub visible; loads stay in flight
    __builtin_amdgcn_s_barrier();
    __builtin_amdgcn_sched_barrier(0);

    // ---- o-phase
    {
      ffrag oacc;
#pragma unroll
      for (int j = 0; j < 4; ++j) oacc[j] = 0.f;
#pragma unroll
      for (int ks = 0; ks < 4; ++ks) {
        const bfrag af = *reinterpret_cast<const bfrag*>(
            &qs[cur][(16 * w + rr) * 128 + (((4 * ks + hi) ^ rr) * 8)]);
        oacc = MFMA(af, sbf[ks], oacc, 0, 0, 0);
      }
      const int nks = (w < 2) ? 1 : 2;  // causal: upper attn cols are zero
      for (int ks = 0; ks < nks; ++ks) {
        bfrag ubf;
#pragma unroll
        for (int j = 0; j < 8; ++j)
          ubf[j] = (short)ub[(32 * ks + 8 * hi + j) * 18 + rr];
        const bfrag af = *reinterpret_cast<const bfrag*>(
            &ats[cur][(16 * w + rr) * 64 + (((4 * ks + hi) ^ (rr & 7)) * 8)]);
        oacc = MFMA(af, ubf, oacc, 0, 0, 0);
      }
      us* og = uv_o + rowbase0 + (size_t)(cid * CH) * D_;
#pragma unroll
      for (int j = 0; j < 4; ++j)
        og[(size_t)(16 * w + 4 * hi + j) * D_ + rr] = f2bf(oacc[j]);
    }

    // ---- S-phase: register accumulate + write bf16(S^T) to Sb[cur^1]
    {
      bfrag ubf[2];
#pragma unroll
      for (int ks = 0; ks < 2; ++ks)
#pragma unroll
        for (int j = 0; j < 8; ++j)
          ubf[ks][j] = (short)ub[(32 * ks + 8 * hi + j) * 18 + rr];
#pragma unroll
      for (int t2 = 0; t2 < 2; ++t2) {
        const int tile = 2 * w + t2;
#pragma unroll
        for (int ks = 0; ks < 2; ++ks) {
          const bfrag af = *reinterpret_cast<const bfrag*>(
              &kTs[cur][(16 * tile + rr) * 64 + (((4 * ks + hi) ^ (rr & 7)) * 8)]);
          sacc[t2] = MFMA(af, ubf[ks], sacc[t2], 0, 0, 0);
        }
        ushort4 sw;
        sw.x = f2bf(sacc[t2][0]); sw.y = f2bf(sacc[t2][1]);
        sw.z = f2bf(sacc[t2][2]); sw.w = f2bf(sacc[t2][3]);
        *reinterpret_cast<ushort4*>(&Sb[cur ^ 1][rr * 136 + 16 * tile + 4 * hi]) = sw;
      }
    }
    // drain staged loads (had full chunk compute to land) + LDS writes; barrier
    asm volatile("s_waitcnt vmcnt(0) lgkmcnt(0)" ::: "memory");
    __builtin_amdgcn_s_barrier();
    __builtin_amdgcn_sched_barrier(0);
  }
#undef STAGE
}

// ---------------------------------------------------------------------------
// per-head RMSNorm (over 128) * onorm_w : bf16 in -> bf16 out
// ---------------------------------------------------------------------------
__global__ __launch_bounds__(256) void rms_onorm_bf16(const us* __restrict__ in,
                                                      const float* __restrict__ w,
                                                      us* __restrict__ out) {
  const int bt = blockIdx.x;
  const int d0 = threadIdx.x * 8;
  const us* p = in + (size_t)bt * D_ + d0;
  const ushort4 a = *reinterpret_cast<const ushort4*>(p);
  const ushort4 b = *reinterpret_cast<const ushort4*>(p + 4);
  float v[8] = {bf2f(a.x), bf2f(a.y), bf2f(a.z), bf2f(a.w),
                bf2f(b.x), bf2f(b.y), bf2f(b.z), bf2f(b.w)};
  float ss = 0.f;
#pragma unroll
  for (int j = 0; j < 8; ++j) ss = fmaf(v[j], v[j], ss);
  ss += __shfl_xor(ss, 1);
  ss += __shfl_xor(ss, 2);
  ss += __shfl_xor(ss, 4);
  ss += __shfl_xor(ss, 8);
  const float sc = rsqrtf(ss * (1.0f / 128.0f) + 1e-5f);
  const int hd = d0 & 127;
  ushort4 o0, o1;
  o0.x = f2bf(v[0] * sc * w[hd + 0]); o0.y = f2bf(v[1] * sc * w[hd + 1]);
  o0.z = f2bf(v[2] * sc * w[hd + 2]); o0.w = f2bf(v[3] * sc * w[hd + 3]);
  o1.x = f2bf(v[4] * sc * w[hd + 4]); o1.y = f2bf(v[5] * sc * w[hd + 5]);
  o1.z = f2bf(v[6] * sc * w[hd + 6]); o1.w = f2bf(v[7] * sc * w[hd + 7]);
  us* op = out + (size_t)bt * D_ + d0;
  *reinterpret_cast<ushort4*>(op) = o0;
  *reinterpret_cast<ushort4*>(op + 4) = o1;
}

// ---------------------------------------------------------------------------
extern "C" void kernel_launch(void* const* d_in, const int* in_sizes, int n_in,
                              void* d_out, int out_size, void* d_ws, size_t ws_size,
                              hipStream_t stream) {
  const float* x  = (const float*)d_in[0];
  const float* Wq = (const float*)d_in[1];
  const float* Wk = (const float*)d_in[2];
  const float* Wv = (const float*)d_in[3];
  const float* Wb = (const float*)d_in[4];
  const float* Wo = (const float*)d_in[5];
  const float* cq = (const float*)d_in[6];
  const float* ck = (const float*)d_in[7];
  const float* cv = (const float*)d_in[8];
  const float* ow = (const float*)d_in[9];
  float* out = (float*)d_out;

  // workspace: 5*NE + D*D bf16 units = 176.2 MB (proven-safe footprint)
  const size_t NE = (size_t)M_ * D_;
  us* ws   = (us*)d_ws;
  us* gout = ws;              // [M,D] gemm scratch; later attn chunks + betaT
  us* qch  = ws + NE;         // q swizzled chunk layout
  us* kch  = ws + 2 * NE;     // k swizzled chunk layout
  us* Wch  = ws + 3 * NE;     // -W swizzled chunk layout
  us* kTch = ws + 4 * NE;     // kT swizzled chunk; after seq: rms-out [M,D]
  us* wt   = ws + 5 * NE;     // [D,D] W^T (reused 4x)
  us* attb = gout;                                  // [2048][64][64]
  float* betaT = (float*)(gout + 12 * 1024 * 1024); // [32][4096] f32
  // d_out as bf16 scratch: xb [0,NE), v/uv/o [NE,2NE)
  us* xb = (us*)d_out;
  us* vb = xb + NE;

  dim3 gg(D_ / 128, M_ / 128);
  dim3 wg(D_ / 64, D_ / 64);

  to_bf16<<<NE / 2048, 256, 0, stream>>>(x, xb);

  wtrans<<<wg, 256, 0, stream>>>(Wv, wt);
  gemm_bf16<false><<<gg, 256, 0, stream>>>(xb, wt, gout, M_, D_, D_);
  conv_silu_plain<<<M_, 256, 0, stream>>>(gout, cv, vb);

  wtrans<<<wg, 256, 0, stream>>>(Wq, wt);
  gemm_bf16<false><<<gg, 256, 0, stream>>>(xb, wt, gout, M_, D_, D_);
  conv_silu_chunk<<<M_, 256, 0, stream>>>(gout, cq, qch, 2);

  wtrans<<<wg, 256, 0, stream>>>(Wk, wt);
  gemm_bf16<false><<<gg, 256, 0, stream>>>(xb, wt, gout, M_, D_, D_);
  conv_silu_chunk<<<M_, 256, 0, stream>>>(gout, ck, kch, 1);

  beta_sigmoid<<<M_ / 4, 256, 0, stream>>>(x, Wb, betaT);

  delta_prep<<<32 * NCH, 256, 0, stream>>>(qch, kch, betaT, vb, Wch, kTch, attb);
  delta_seq<<<256, 256, 0, stream>>>(qch, Wch, kTch, attb, vb);

  rms_onorm_bf16<<<M_, 256, 0, stream>>>(vb, ow, kTch);

  wtrans<<<wg, 256, 0, stream>>>(Wo, wt);
  gemm_bf16<true><<<gg, 256, 0, stream>>>(kTch, wt, out, M_, D_, D_);
}

// Round 9
// 677.720 us; speedup vs baseline: 15.4340x; 1.1605x over previous
//
#include <hip/hip_runtime.h>
#include <math.h>

#define B_ 2
#define T_ 4096
#define D_ 2048
#define H_ 16
#define DK 128
#define DV 128
#define CH 64
#define M_ (B_ * T_)  // 8192
#define NCH (T_ / CH) // 64 chunks

typedef __attribute__((ext_vector_type(8))) short bfrag;   // 8 bf16
typedef __attribute__((ext_vector_type(4))) float ffrag;   // 4 f32 acc
typedef __attribute__((ext_vector_type(8))) unsigned short u16x8;
typedef unsigned short us;

#define MFMA __builtin_amdgcn_mfma_f32_16x16x32_bf16

__device__ inline us f2bf(float f) {
  union { float f; unsigned u; } v; v.f = f;
  unsigned r = v.u + 0x7fffu + ((v.u >> 16) & 1u);
  return (us)(r >> 16);
}
__device__ inline float bf2f(us u) {
  union { unsigned u; float f; } v; v.u = ((unsigned)u) << 16;
  return v.f;
}

// async global->LDS, 16B per lane (dest = wave-uniform base + lane*16)
__device__ inline void gl_lds16(const us* g, us* l) {
  __builtin_amdgcn_global_load_lds(
      (const __attribute__((address_space(1))) void*)g,
      (__attribute__((address_space(3))) void*)l, 16, 0, 0);
}

// ---------------------------------------------------------------------------
// flat f32 -> bf16 (8 elems/thread)
// ---------------------------------------------------------------------------
__global__ __launch_bounds__(256) void to_bf16(const float* __restrict__ in,
                                               us* __restrict__ out) {
  const size_t i = ((size_t)blockIdx.x * 256 + threadIdx.x) * 8;
  const float4 a = *reinterpret_cast<const float4*>(in + i);
  const float4 b = *reinterpret_cast<const float4*>(in + i + 4);
  ushort4 o0, o1;
  o0.x = f2bf(a.x); o0.y = f2bf(a.y); o0.z = f2bf(a.z); o0.w = f2bf(a.w);
  o1.x = f2bf(b.x); o1.y = f2bf(b.y); o1.z = f2bf(b.z); o1.w = f2bf(b.w);
  *reinterpret_cast<ushort4*>(out + i) = o0;
  *reinterpret_cast<ushort4*>(out + i + 4) = o1;
}

// ---------------------------------------------------------------------------
// transpose + convert: Wt[n][k] = bf16(W[k][n]), 64x64 tiles
// ---------------------------------------------------------------------------
__global__ __launch_bounds__(256) void wtrans(const float* __restrict__ W,
                                              us* __restrict__ Wt) {
  __shared__ float tile[64][68];
  const int k0 = blockIdx.y * 64, n0 = blockIdx.x * 64;
  const int lr = threadIdx.x >> 4, lc = (threadIdx.x & 15) * 4;
#pragma unroll
  for (int p = 0; p < 4; ++p) {
    const int r = lr + p * 16;
    *reinterpret_cast<float4*>(&tile[r][lc]) =
        *reinterpret_cast<const float4*>(&W[(size_t)(k0 + r) * D_ + n0 + lc]);
  }
  __syncthreads();
#pragma unroll
  for (int p = 0; p < 4; ++p) {
    const int r = lr + p * 16;
    ushort4 o;
    o.x = f2bf(tile[lc + 0][r]); o.y = f2bf(tile[lc + 1][r]);
    o.z = f2bf(tile[lc + 2][r]); o.w = f2bf(tile[lc + 3][r]);
    *reinterpret_cast<ushort4*>(&Wt[(size_t)(n0 + r) * D_ + k0 + lc]) = o;
  }
}

// ---------------------------------------------------------------------------
// gemm256: C[M,N] = A[M,K] @ Bt[N,K]^T (bf16). 256x256 tile, BK=32,
// 512 thr (8 waves, 2x4), wave tile 128x64 (acc 8x4 frags).
// Triple-buffered LDS (96 KB), prefetch distance 2, counted vmcnt(4),
// two 16-MFMA phases/group with raw barriers + setprio (T2/T3/T4/T5).
// LDS swizzle: col ^= ((row>>2)&3)*8, applied via pre-swizzled global src.
// Requires M%256==0, N%256==0, K%32==0.
// ---------------------------------------------------------------------------
template <bool OUTF32>
__global__ __launch_bounds__(512, 2) void gemm256(const us* __restrict__ A,
                                                  const us* __restrict__ Bt,
                                                  void* __restrict__ Cp,
                                                  int M, int N, int K) {
  __shared__ __align__(16) us lA[3][256 * 32];
  __shared__ __align__(16) us lB[3][256 * 32];
  const int t = threadIdx.x, l = t & 63, w = t >> 6;
  const int wm = w >> 2, wn = w & 3;
  const int fr = l & 15, hi = l >> 4;
  const int colx = 8 * (hi ^ ((fr >> 2) & 3));  // swizzled frag col (bf16 units)

  // XCD-aware swizzle (nwg multiple of 8 by construction)
  const int nx = gridDim.x;
  const int nwg = nx * gridDim.y;
  const int lin = blockIdx.y * nx + blockIdx.x;
  const int swz = (lin & 7) * (nwg >> 3) + (lin >> 3);
  const int m0 = (swz / nx) * 256, n0 = (swz % nx) * 256;

  // staging map: thread t, load p -> LDS us-offset (p*512+t)*8
  //   row = p*128 + (t>>2), linear col = (t&3)*8; src col pre-swizzled.
  const int srow = t >> 2;
  const int csrc = ((t & 3) * 8) ^ (((t >> 4) & 3) * 8);
  const us* Asrc0 = A + (size_t)(m0 + srow) * K + csrc;
  const us* Asrc1 = A + (size_t)(m0 + 128 + srow) * K + csrc;
  const us* Bsrc0 = Bt + (size_t)(n0 + srow) * K + csrc;
  const us* Bsrc1 = Bt + (size_t)(n0 + 128 + srow) * K + csrc;

  ffrag acc[8][4];
#pragma unroll
  for (int mi = 0; mi < 8; ++mi)
#pragma unroll
    for (int ni = 0; ni < 4; ++ni)
#pragma unroll
      for (int e = 0; e < 4; ++e) acc[mi][ni][e] = 0.f;

#define SA_(bufp, g)                                              \
  do {                                                            \
    gl_lds16(Asrc0 + (size_t)(g) * 32, (bufp) + t * 8);           \
    gl_lds16(Asrc1 + (size_t)(g) * 32, (bufp) + 4096 + t * 8);    \
  } while (0)
#define SB_(bufp, g)                                              \
  do {                                                            \
    gl_lds16(Bsrc0 + (size_t)(g) * 32, (bufp) + t * 8);           \
    gl_lds16(Bsrc1 + (size_t)(g) * 32, (bufp) + 4096 + t * 8);    \
  } while (0)

  const int NT = K >> 5;
  us* const baseA = &lA[0][0];
  us* const baseB = &lB[0][0];

  // prologue: H[0], H[1]; wait until only H[1] (4 loads) outstanding
  SA_(baseA, 0); SB_(baseB, 0);
  SA_(baseA + 8192, 1); SB_(baseB + 8192, 1);
  asm volatile("s_waitcnt vmcnt(4)" ::: "memory");
  __builtin_amdgcn_s_barrier();
  __builtin_amdgcn_sched_barrier(0);

  int cur = 0, nxt = 2;
  const int rbA = wm * 128 + fr;  // A frag base row
  const int rbB = wn * 64 + fr;   // B frag base row

#pragma unroll 1
  for (int g = 0; g < NT; ++g) {
    us* const curA = baseA + cur * 8192;
    us* const curB = baseB + cur * 8192;
    us* const nxtA = baseA + nxt * 8192;
    us* const nxtB = baseB + nxt * 8192;

    bfrag bf4[4], af4[4];
    // ---- phase 1: mi 0..3 x ni 0..3
#pragma unroll
    for (int ni = 0; ni < 4; ++ni)
      bf4[ni] = *reinterpret_cast<const bfrag*>(curB + (rbB + ni * 16) * 32 + colx);
#pragma unroll
    for (int mi = 0; mi < 4; ++mi)
      af4[mi] = *reinterpret_cast<const bfrag*>(curA + (rbA + mi * 16) * 32 + colx);
    if (g + 2 < NT) SA_(nxtA, g + 2);
    __builtin_amdgcn_s_barrier();
    asm volatile("s_waitcnt lgkmcnt(0)" ::: "memory");
    __builtin_amdgcn_sched_barrier(0);
    __builtin_amdgcn_s_setprio(1);
#pragma unroll
    for (int mi = 0; mi < 4; ++mi)
#pragma unroll
      for (int ni = 0; ni < 4; ++ni)
        acc[mi][ni] = MFMA(af4[mi], bf4[ni], acc[mi][ni], 0, 0, 0);
    __builtin_amdgcn_s_setprio(0);
    __builtin_amdgcn_s_barrier();

    // ---- phase 2: mi 4..7 x ni 0..3 (bf4 reused)
#pragma unroll
    for (int mi = 0; mi < 4; ++mi)
      af4[mi] = *reinterpret_cast<const bfrag*>(curA + (rbA + (mi + 4) * 16) * 32 + colx);
    if (g + 2 < NT) SB_(nxtB, g + 2);
    __builtin_amdgcn_s_barrier();
    asm volatile("s_waitcnt lgkmcnt(0)" ::: "memory");
    __builtin_amdgcn_sched_barrier(0);
    __builtin_amdgcn_s_setprio(1);
#pragma unroll
    for (int mi = 0; mi < 4; ++mi)
#pragma unroll
      for (int ni = 0; ni < 4; ++ni)
        acc[mi + 4][ni] = MFMA(af4[mi], bf4[ni], acc[mi + 4][ni], 0, 0, 0);
    __builtin_amdgcn_s_setprio(0);
    // counted drain: allow this group's 4 prefetch loads to stay in flight
    if (g + 2 < NT)
      asm volatile("s_waitcnt vmcnt(4)" ::: "memory");
    else
      asm volatile("s_waitcnt vmcnt(0)" ::: "memory");
    __builtin_amdgcn_s_barrier();
    __builtin_amdgcn_sched_barrier(0);

    cur = (cur == 2) ? 0 : cur + 1;
    nxt = (nxt == 2) ? 0 : nxt + 1;
  }
#undef SA_
#undef SB_

  // epilogue: C write
  const int crow = m0 + wm * 128 + 4 * hi;
  const int ccol = n0 + wn * 64 + fr;
#pragma unroll
  for (int mi = 0; mi < 8; ++mi)
#pragma unroll
    for (int ni = 0; ni < 4; ++ni)
#pragma unroll
      for (int j = 0; j < 4; ++j) {
        const size_t idx = (size_t)(crow + mi * 16 + j) * N + ccol + ni * 16;
        if constexpr (OUTF32) ((float*)Cp)[idx] = acc[mi][ni][j];
        else ((us*)Cp)[idx] = f2bf(acc[mi][ni][j]);
      }
}

// ---------------------------------------------------------------------------
// conv+silu bodies
// ---------------------------------------------------------------------------
__device__ inline void conv_body(const us* __restrict__ in, const float* cw,
                                 int bt, int d0, int mode, float v[8]) {
  const int tb = bt & (T_ - 1);
  const us* row = in + (size_t)bt * D_ + d0;
#pragma unroll
  for (int j = 0; j < 8; ++j) v[j] = 0.f;
#pragma unroll
  for (int j = 0; j < 4; ++j) {
    if (tb >= j) {
      const us* rp = row - (size_t)(j * D_);
      const ushort4 a = *reinterpret_cast<const ushort4*>(rp);
      const ushort4 b = *reinterpret_cast<const ushort4*>(rp + 4);
      const float wj = cw[3 - j];
      v[0] = fmaf(wj, bf2f(a.x), v[0]); v[1] = fmaf(wj, bf2f(a.y), v[1]);
      v[2] = fmaf(wj, bf2f(a.z), v[2]); v[3] = fmaf(wj, bf2f(a.w), v[3]);
      v[4] = fmaf(wj, bf2f(b.x), v[4]); v[5] = fmaf(wj, bf2f(b.y), v[5]);
      v[6] = fmaf(wj, bf2f(b.z), v[6]); v[7] = fmaf(wj, bf2f(b.w), v[7]);
    }
  }
#pragma unroll
  for (int j = 0; j < 8; ++j) v[j] = v[j] / (1.f + expf(-v[j]));
  if (mode) {
    float ss = 0.f;
#pragma unroll
    for (int j = 0; j < 8; ++j) ss = fmaf(v[j], v[j], ss);
    ss += __shfl_xor(ss, 1);
    ss += __shfl_xor(ss, 2);
    ss += __shfl_xor(ss, 4);
    ss += __shfl_xor(ss, 8);
    float sc = rsqrtf(ss + 1e-6f);
    if (mode == 2) sc *= 0.08838834764831845f;  // 128^-0.5
#pragma unroll
    for (int j = 0; j < 8; ++j) v[j] *= sc;
  }
}

__global__ __launch_bounds__(256) void conv_silu_plain(const us* __restrict__ in,
                                                       const float* __restrict__ cw,
                                                       us* __restrict__ out) {
  const int bt = blockIdx.x, d0 = threadIdx.x * 8;
  float v[8];
  conv_body(in, cw, bt, d0, 0, v);
  ushort4 o0, o1;
  o0.x = f2bf(v[0]); o0.y = f2bf(v[1]); o0.z = f2bf(v[2]); o0.w = f2bf(v[3]);
  o1.x = f2bf(v[4]); o1.y = f2bf(v[5]); o1.z = f2bf(v[6]); o1.w = f2bf(v[7]);
  us* op = out + (size_t)bt * D_ + d0;
  *reinterpret_cast<ushort4*>(op) = o0;
  *reinterpret_cast<ushort4*>(op + 4) = o1;
}

// conv+silu+l2norm -> swizzled chunk layout [bh][cid][64][128], 16B-group XOR(r&15)
__global__ __launch_bounds__(256) void conv_silu_chunk(const us* __restrict__ in,
                                                       const float* __restrict__ cw,
                                                       us* __restrict__ out,
                                                       int mode) {
  const int bt = blockIdx.x, d0 = threadIdx.x * 8;
  float v[8];
  conv_body(in, cw, bt, d0, mode, v);
  const int b = bt >> 12, tt = bt & (T_ - 1);
  const int cid = tt >> 6, r = tt & 63;
  const int h = d0 >> 7, g = (d0 & 127) >> 3;
  us* dst = out + ((size_t)((b * H_ + h) * NCH + cid)) * (CH * DK) +
            r * 128 + ((g ^ (r & 15)) * 8);
  ushort4 o0, o1;
  o0.x = f2bf(v[0]); o0.y = f2bf(v[1]); o0.z = f2bf(v[2]); o0.w = f2bf(v[3]);
  o1.x = f2bf(v[4]); o1.y = f2bf(v[5]); o1.z = f2bf(v[6]); o1.w = f2bf(v[7]);
  *reinterpret_cast<ushort4*>(dst) = o0;
  *reinterpret_cast<ushort4*>(dst + 4) = o1;
}

// ---------------------------------------------------------------------------
// beta = sigmoid(x @ Wb) -> [bh][T] layout (contiguous for prep)
// ---------------------------------------------------------------------------
__global__ __launch_bounds__(256) void beta_sigmoid(const float* __restrict__ x,
                                                    const float* __restrict__ Wb,
                                                    float* __restrict__ betaT) {
  const int t = threadIdx.x;
  const int m = blockIdx.x * 4 + (t >> 6);
  const int l = t & 63;
  const int c = l & 15;
  const int s = l >> 4;
  const float* xr = x + (size_t)m * D_;
  const int kb = s * (D_ / 4);
  float acc = 0.f;
  for (int k = 0; k < D_ / 4; ++k)
    acc = fmaf(xr[kb + k], Wb[(size_t)(kb + k) * H_ + c], acc);
  acc += __shfl_xor(acc, 16);
  acc += __shfl_xor(acc, 32);
  if (l < 16) {
    const int b = m >> 12, tt = m & (T_ - 1);
    betaT[((size_t)(b * H_ + c)) * T_ + tt] = 1.f / (1.f + expf(-acc));
  }
}

// ---------------------------------------------------------------------------
// f32 blocked product step for T = M^-1: T[I][J] = -T_II * (sum_K M[I][K] T[K][J])
// ---------------------------------------------------------------------------
__device__ inline void prod_step(float* Tf, const float* Am, float* xbuf,
                                 int r, int c, int I, int J,
                                 int nk, int K0, int K1, int K2) {
  float X = 0.f;
  const int Ks[3] = {K0, K1, K2};
  for (int kk = 0; kk < nk; ++kk) {
    const int K = Ks[kk];
    const float* amrow = Am + (16 * I + r) * 72 + 16 * K;
    const float* tcol = Tf + (16 * K) * 68 + 16 * J + c;
#pragma unroll
    for (int m = 0; m < 16; ++m) X = fmaf(amrow[m], tcol[m * 68], X);
  }
  __syncthreads();               // prior step's xbuf readers done
  xbuf[r * 17 + c] = X;
  __syncthreads();               // xbuf ready
  float s = 0.f;
  const float* trow = Tf + (16 * I + r) * 68 + 16 * I;
#pragma unroll
  for (int m = 0; m < 16; ++m) s = fmaf(trow[m], xbuf[m * 17 + c], s);
  Tf[(16 * I + r) * 68 + 16 * J + c] = -s;   // disjoint from reads above
  __syncthreads();               // block (I,J) visible for next step
}

// ---------------------------------------------------------------------------
// delta_prep v2 (proven R6): block per (b,h,chunk) = 2048, 256 thr, 2 blocks/CU.
// ---------------------------------------------------------------------------
__global__ __launch_bounds__(256, 2) void delta_prep(const us* __restrict__ qch,
                                                     const us* __restrict__ kch,
                                                     const float* __restrict__ betaT,
                                                     us* __restrict__ v_uv,
                                                     us* __restrict__ Wout,
                                                     us* __restrict__ kTout,
                                                     us* __restrict__ Aout) {
  __shared__ __align__(16) unsigned char lds[72000];
  us*    ks    = (us*)(lds);             // [64*128] swz     (P0-P1)
  us*    Tb    = (us*)(lds);             // [64][72] bf16    (P5-)
  float* Am    = (float*)(lds + 16384);  // [64][72] f32     (P1-P4)
  us*    vTb   = (us*)(lds + 16384);     // [128][72] bf16   (P5-)
  float* Tf    = (float*)(lds + 34816);  // [64][68] f32     (P2-P5)
  us*    atst  = (us*)(lds + 34816);     // attn stage [64*64] (P0-P2)
  us*    Wst   = (us*)(lds + 34816);     // W stage [64*128] (P6-)
  us*    kTb   = (us*)(lds + 52224);     // [128][72] bf16   (P1-P6a)
  us*    UVst  = (us*)(lds + 52224);     // [64*128]         (P6b-)
  float* betac = (float*)(lds + 70656);  // [64]
  float* xbuf  = (float*)(lds + 70912);  // [16][17]

  const int t = threadIdx.x, w = t >> 6, l = t & 63;
  const int rr = l & 15, hi = l >> 4;
  const int bx = blockIdx.x;
  const int bh = bx >> 6, cid = bx & 63;
  const int b = bh >> 4, h = bh & 15;
  const size_t rowbase = ((size_t)b * T_ + (size_t)cid * CH) * D_ + (size_t)h * DK;
  const size_t cbase = (size_t)bx * (CH * DK);
  const size_t abase = (size_t)bx * (CH * CH);

  // ---- P0: stage ks, zero attn-stage, betac
  {
    const us* kg = kch + cbase;
#pragma unroll
    for (int p = 0; p < 4; ++p)
      gl_lds16(kg + p * 2048 + t * 8, ks + p * 2048 + t * 8);
    const float4 z = make_float4(0.f, 0.f, 0.f, 0.f);
    *reinterpret_cast<float4*>(atst + t * 16) = z;
    *reinterpret_cast<float4*>(atst + t * 16 + 8) = z;
    if (t < 64) betac[t] = betaT[(size_t)bh * T_ + cid * CH + t];
  }
  __syncthreads();

  // ---- P1: A MFMA (beta-scaled strict-tril -> Am f32), attn MFMA -> atst,
  //          kTb build (plain k^T bf16)
  {
    bfrag qf[4], kf[4];
#pragma unroll
    for (int k4 = 0; k4 < 4; ++k4) {
      const int go = ((4 * k4 + hi) ^ rr) * 8;
      qf[k4] = *reinterpret_cast<const bfrag*>(qch + cbase + (16 * w + rr) * 128 + go);
      kf[k4] = *reinterpret_cast<const bfrag*>(ks + (16 * w + rr) * 128 + go);
    }
    for (int jt = 0; jt <= w; ++jt) {
      ffrag accA = {0.f, 0.f, 0.f, 0.f}, accQ = {0.f, 0.f, 0.f, 0.f};
#pragma unroll
      for (int k4 = 0; k4 < 4; ++k4) {
        const bfrag bfr = *reinterpret_cast<const bfrag*>(
            ks + (16 * jt + rr) * 128 + (((4 * k4 + hi) ^ rr) * 8));
        accA = MFMA(kf[k4], bfr, accA, 0, 0, 0);
        accQ = MFMA(qf[k4], bfr, accQ, 0, 0, 0);
      }
#pragma unroll
      for (int j4 = 0; j4 < 4; ++j4) {
        const int i = 16 * w + 4 * hi + j4, j = 16 * jt + rr;
        Am[i * 72 + j] = (j < i) ? betac[i] * accA[j4] : 0.f;
        if (j <= i)
          atst[i * 64 + (((j >> 3) ^ (i & 7)) * 8) + (j & 7)] = f2bf(accQ[j4]);
      }
    }
    const int r = t & 63, part = t >> 6;
#pragma unroll
    for (int gi = 0; gi < 4; ++gi) {
      const int g = 4 * part + gi;
      const u16x8 kv = *reinterpret_cast<const u16x8*>(ks + r * 128 + ((g ^ (r & 15)) * 8));
#pragma unroll
      for (int j = 0; j < 8; ++j) kTb[(g * 8 + j) * 72 + r] = kv[j];
    }
  }
  __syncthreads();

  // ---- P2: copy attn + kT to global; then zero Tf (same region as atst!)
  {
#pragma unroll
    for (int p = 0; p < 2; ++p) {
      const int unit = t + p * 256;
      *reinterpret_cast<u16x8*>(Aout + abase + unit * 8) =
          *reinterpret_cast<const u16x8*>(atst + unit * 8);
    }
#pragma unroll
    for (int p = 0; p < 4; ++p) {
      const int unit = t + p * 256;
      const int d = unit >> 3, sg = unit & 7;
      *reinterpret_cast<u16x8*>(kTout + cbase + unit * 8) =
          *reinterpret_cast<const u16x8*>(kTb + d * 72 + ((sg ^ (d & 7)) * 8));
    }
  }
  __syncthreads();  // atst reads done before Tf overwrite
  for (int i = t; i < 64 * 68; i += 256) Tf[i] = 0.f;
  __syncthreads();

  // ---- P3: four 16x16 unit-lower diagonal inverses (64 threads)
  if (t < 64) {
    const int blk = t >> 4, j = t & 15, bd = blk * 16;
    Tf[(bd + j) * 68 + bd + j] = 1.f;
    for (int i = j + 1; i < 16; ++i) {
      float s = 0.f;
      for (int m = j; m < i; ++m)
        s = fmaf(Am[(bd + i) * 72 + bd + m], Tf[(bd + m) * 68 + bd + j], s);
      Tf[(bd + i) * 68 + bd + j] = -s;
    }
  }
  __syncthreads();

  // ---- P4: off-diagonal blocks of T (f32, all 256 threads)
  {
    const int r = t >> 4, c = t & 15;
    prod_step(Tf, Am, xbuf, r, c, 1, 0, 1, 0, 0, 0);
    prod_step(Tf, Am, xbuf, r, c, 2, 0, 2, 0, 1, 0);
    prod_step(Tf, Am, xbuf, r, c, 3, 0, 3, 0, 1, 2);
    prod_step(Tf, Am, xbuf, r, c, 2, 1, 1, 1, 0, 0);
    prod_step(Tf, Am, xbuf, r, c, 3, 1, 2, 1, 2, 0);
    prod_step(Tf, Am, xbuf, r, c, 3, 2, 1, 2, 0, 0);
  }

  // ---- P5: Tb = bf16(T * diag(beta)) into ks region; vTb = v^T into Am region
  {
    const int vr = t >> 2, vp = t & 3;
    u16x8 vv[4];
#pragma unroll
    for (int g = 0; g < 4; ++g)
      vv[g] = *reinterpret_cast<const u16x8*>(v_uv + rowbase + (size_t)vr * D_ +
                                              vp * 32 + g * 8);
    const int ti = t >> 2, tg = t & 3;
    u16x8 w0, w1;
#pragma unroll
    for (int jj = 0; jj < 8; ++jj) {
      const int j0 = tg * 16 + jj, j1 = j0 + 8;
      w0[jj] = f2bf(Tf[ti * 68 + j0] * betac[j0]);
      w1[jj] = f2bf(Tf[ti * 68 + j1] * betac[j1]);
    }
    *reinterpret_cast<u16x8*>(Tb + ti * 72 + tg * 16) = w0;
    *reinterpret_cast<u16x8*>(Tb + ti * 72 + tg * 16 + 8) = w1;
#pragma unroll
    for (int g = 0; g < 4; ++g)
#pragma unroll
      for (int j = 0; j < 8; ++j)
        vTb[(vp * 32 + g * 8 + j) * 72 + vr] = vv[g][j];
  }
  __syncthreads();

  // ---- P6a: W = -(Tb . kTb) -> Wst (swz16)
  {
    bfrag ta[2];
#pragma unroll
    for (int k2 = 0; k2 < 2; ++k2)
      ta[k2] = *reinterpret_cast<const bfrag*>(Tb + (16 * w + rr) * 72 + 32 * k2 + 8 * hi);
#pragma unroll
    for (int dt = 0; dt < 8; ++dt) {
      ffrag acc = {0.f, 0.f, 0.f, 0.f};
#pragma unroll
      for (int k2 = 0; k2 < 2; ++k2) {
        const bfrag bfr = *reinterpret_cast<const bfrag*>(
            kTb + (16 * dt + rr) * 72 + 32 * k2 + 8 * hi);
        acc = MFMA(ta[k2], bfr, acc, 0, 0, 0);
      }
#pragma unroll
      for (int j4 = 0; j4 < 4; ++j4) {
        const int i = 16 * w + 4 * hi + j4, d = 16 * dt + rr;
        Wst[i * 128 + (((d >> 3) ^ (i & 15)) * 8) + (d & 7)] = f2bf(-acc[j4]);
      }
    }
  }
  __syncthreads();  // kTb reads done (UVst may overwrite); Wst complete

  // ---- P6b: UV = Tb . vTb -> UVst; copy W out
  {
    bfrag ta[2];
#pragma unroll
    for (int k2 = 0; k2 < 2; ++k2)
      ta[k2] = *reinterpret_cast<const bfrag*>(Tb + (16 * w + rr) * 72 + 32 * k2 + 8 * hi);
#pragma unroll
    for (int et = 0; et < 8; ++et) {
      ffrag acc = {0.f, 0.f, 0.f, 0.f};
#pragma unroll
      for (int k2 = 0; k2 < 2; ++k2) {
        const bfrag bfr = *reinterpret_cast<const bfrag*>(
            vTb + (16 * et + rr) * 72 + 32 * k2 + 8 * hi);
        acc = MFMA(ta[k2], bfr, acc, 0, 0, 0);
      }
#pragma unroll
      for (int j4 = 0; j4 < 4; ++j4)
        UVst[(16 * w + 4 * hi + j4) * 128 + 16 * et + rr] = f2bf(acc[j4]);
    }
#pragma unroll
    for (int p = 0; p < 4; ++p) {
      const int unit = t + p * 256;
      *reinterpret_cast<u16x8*>(Wout + cbase + unit * 8) =
          *reinterpret_cast<const u16x8*>(Wst + unit * 8);
    }
  }
  __syncthreads();

  // ---- P7: copy u_v out (in-place over v, row-major [M,D])
#pragma unroll
  for (int p = 0; p < 4; ++p) {
    const int unit = t + p * 256;
    const int r = unit >> 4, g = unit & 15;
    *reinterpret_cast<u16x8*>(v_uv + rowbase + (size_t)r * D_ + g * 8) =
        *reinterpret_cast<const u16x8*>(UVst + r * 128 + g * 8);
  }
}

// ---------------------------------------------------------------------------
// delta_seq v3 (proven R7): MFMA + counted-vmcnt + register-resident S.
// ---------------------------------------------------------------------------
__global__ __launch_bounds__(256, 1) void delta_seq(const us* __restrict__ qch,
                                                    const us* __restrict__ Wch,
                                                    const us* __restrict__ kTch,
                                                    const us* __restrict__ atch,
                                                    us* __restrict__ uv_o) {
  __shared__ __align__(16) us qs[2][CH * DK];    // 16KB x2
  __shared__ __align__(16) us Ws[2][CH * DK];    // 16KB x2
  __shared__ __align__(16) us kTs[2][DK * CH];   // 16KB x2
  __shared__ __align__(16) us ats[2][CH * CH];   // 8KB  x2
  __shared__ __align__(16) us uvs[2][CH * 16];   // 2KB  x2
  __shared__ __align__(16) us Sb[2][16 * 136];   // 4.25KB x2 (S^T bf16, dbuf)
  __shared__ __align__(16) us ub[CH * 18];       // 2.25KB (u bf16)

  const int t = threadIdx.x, l = t & 63, w = t >> 6;
  const int bx = blockIdx.x;
  const int vs = bx >> 5, bh = bx & 31;
  const int b = bh >> 4, h = bh & 15;
  const int rr = l & 15, hi = l >> 4;

  // S lives in registers: wave w owns rows 32w..32w+31 (2 tiles), col rr per lane
  ffrag sacc[2];
#pragma unroll
  for (int t2 = 0; t2 < 2; ++t2)
#pragma unroll
    for (int j = 0; j < 4; ++j) sacc[t2][j] = 0.f;

  for (int i = t; i < 16 * 136; i += 256) Sb[0][i] = 0;

  const size_t cbQ = (size_t)(bh * NCH) * (CH * DK);
  const size_t cbA = (size_t)(bh * NCH) * (CH * CH);
  const size_t rowbase0 = ((size_t)b * T_) * D_ + (size_t)h * DK + vs * 16;

#define STAGE(buf, cid)                                                        \
  do {                                                                         \
    const us* qg = qch + cbQ + (size_t)(cid) * (CH * DK);                      \
    const us* Wg = Wch + cbQ + (size_t)(cid) * (CH * DK);                      \
    const us* kg = kTch + cbQ + (size_t)(cid) * (CH * DK);                     \
    const us* ag = atch + cbA + (size_t)(cid) * (CH * CH);                     \
    _Pragma("unroll")                                                          \
    for (int p = 0; p < 4; ++p) {                                              \
      gl_lds16(qg + p * 2048 + t * 8, &qs[buf][p * 2048 + t * 8]);             \
      gl_lds16(Wg + p * 2048 + t * 8, &Ws[buf][p * 2048 + t * 8]);             \
      gl_lds16(kg + p * 2048 + t * 8, &kTs[buf][p * 2048 + t * 8]);            \
    }                                                                          \
    _Pragma("unroll")                                                          \
    for (int p = 0; p < 2; ++p)                                                \
      gl_lds16(ag + p * 2048 + t * 8, &ats[buf][p * 2048 + t * 8]);            \
    if (t < 128)                                                               \
      gl_lds16(uv_o + rowbase0 + (size_t)((cid) * CH + (t >> 1)) * D_ + (t & 1) * 8, \
               &uvs[buf][t * 8]);                                              \
  } while (0)

  STAGE(0, 0);
  asm volatile("s_waitcnt vmcnt(0) lgkmcnt(0)" ::: "memory");
  __builtin_amdgcn_s_barrier();
  __builtin_amdgcn_sched_barrier(0);

  for (int cid = 0; cid < NCH; ++cid) {
    const int cur = cid & 1;
    if (cid + 1 < NCH) STAGE(cur ^ 1, cid + 1);  // async; drained at end barrier

    // Sb fragments (shared by u- and o-phases)
    bfrag sbf[4];
#pragma unroll
    for (int ks = 0; ks < 4; ++ks)
      sbf[ks] = *reinterpret_cast<const bfrag*>(&Sb[cur][rr * 136 + ks * 32 + hi * 8]);

    // ---- u-phase: wave w owns rows 16w..16w+15
    {
      ffrag uacc;
#pragma unroll
      for (int j = 0; j < 4; ++j)
        uacc[j] = bf2f(uvs[cur][(16 * w + 4 * hi + j) * 16 + rr]);
#pragma unroll
      for (int ks = 0; ks < 4; ++ks) {
        const bfrag af = *reinterpret_cast<const bfrag*>(
            &Ws[cur][(16 * w + rr) * 128 + (((4 * ks + hi) ^ rr) * 8)]);
        uacc = MFMA(af, sbf[ks], uacc, 0, 0, 0);
      }
#pragma unroll
      for (int j = 0; j < 4; ++j)
        ub[(16 * w + 4 * hi + j) * 18 + rr] = f2bf(uacc[j]);
    }
    asm volatile("s_waitcnt lgkmcnt(0)" ::: "memory");  // ub visible; loads stay in flight
    __builtin_amdgcn_s_barrier();
    __builtin_amdgcn_sched_barrier(0);

    // ---- o-phase
    {
      ffrag oacc;
#pragma unroll
      for (int j = 0; j < 4; ++j) oacc[j] = 0.f;
#pragma unroll
      for (int ks = 0; ks < 4; ++ks) {
        const bfrag af = *reinterpret_cast<const bfrag*>(
            &qs[cur][(16 * w + rr) * 128 + (((4 * ks + hi) ^ rr) * 8)]);
        oacc = MFMA(af, sbf[ks], oacc, 0, 0, 0);
      }
      const int nks = (w < 2) ? 1 : 2;  // causal: upper attn cols are zero
      for (int ks = 0; ks < nks; ++ks) {
        bfrag ubf;
#pragma unroll
        for (int j = 0; j < 8; ++j)
          ubf[j] = (short)ub[(32 * ks + 8 * hi + j) * 18 + rr];
        const bfrag af = *reinterpret_cast<const bfrag*>(
            &ats[cur][(16 * w + rr) * 64 + (((4 * ks + hi) ^ (rr & 7)) * 8)]);
        oacc = MFMA(af, ubf, oacc, 0, 0, 0);
      }
      us* og = uv_o + rowbase0 + (size_t)(cid * CH) * D_;
#pragma unroll
      for (int j = 0; j < 4; ++j)
        og[(size_t)(16 * w + 4 * hi + j) * D_ + rr] = f2bf(oacc[j]);
    }

    // ---- S-phase: register accumulate + write bf16(S^T) to Sb[cur^1]
    {
      bfrag ubf[2];
#pragma unroll
      for (int ks = 0; ks < 2; ++ks)
#pragma unroll
        for (int j = 0; j < 8; ++j)
          ubf[ks][j] = (short)ub[(32 * ks + 8 * hi + j) * 18 + rr];
#pragma unroll
      for (int t2 = 0; t2 < 2; ++t2) {
        const int tile = 2 * w + t2;
#pragma unroll
        for (int ks = 0; ks < 2; ++ks) {
          const bfrag af = *reinterpret_cast<const bfrag*>(
              &kTs[cur][(16 * tile + rr) * 64 + (((4 * ks + hi) ^ (rr & 7)) * 8)]);
          sacc[t2] = MFMA(af, ubf[ks], sacc[t2], 0, 0, 0);
        }
        ushort4 sw;
        sw.x = f2bf(sacc[t2][0]); sw.y = f2bf(sacc[t2][1]);
        sw.z = f2bf(sacc[t2][2]); sw.w = f2bf(sacc[t2][3]);
        *reinterpret_cast<ushort4*>(&Sb[cur ^ 1][rr * 136 + 16 * tile + 4 * hi]) = sw;
      }
    }
    // drain staged loads (had full chunk compute to land) + LDS writes; barrier
    asm volatile("s_waitcnt vmcnt(0) lgkmcnt(0)" ::: "memory");
    __builtin_amdgcn_s_barrier();
    __builtin_amdgcn_sched_barrier(0);
  }
#undef STAGE
}

// ---------------------------------------------------------------------------
// per-head RMSNorm (over 128) * onorm_w : bf16 in -> bf16 out
// ---------------------------------------------------------------------------
__global__ __launch_bounds__(256) void rms_onorm_bf16(const us* __restrict__ in,
                                                      const float* __restrict__ w,
                                                      us* __restrict__ out) {
  const int bt = blockIdx.x;
  const int d0 = threadIdx.x * 8;
  const us* p = in + (size_t)bt * D_ + d0;
  const ushort4 a = *reinterpret_cast<const ushort4*>(p);
  const ushort4 b = *reinterpret_cast<const ushort4*>(p + 4);
  float v[8] = {bf2f(a.x), bf2f(a.y), bf2f(a.z), bf2f(a.w),
                bf2f(b.x), bf2f(b.y), bf2f(b.z), bf2f(b.w)};
  float ss = 0.f;
#pragma unroll
  for (int j = 0; j < 8; ++j) ss = fmaf(v[j], v[j], ss);
  ss += __shfl_xor(ss, 1);
  ss += __shfl_xor(ss, 2);
  ss += __shfl_xor(ss, 4);
  ss += __shfl_xor(ss, 8);
  const float sc = rsqrtf(ss * (1.0f / 128.0f) + 1e-5f);
  const int hd = d0 & 127;
  ushort4 o0, o1;
  o0.x = f2bf(v[0] * sc * w[hd + 0]); o0.y = f2bf(v[1] * sc * w[hd + 1]);
  o0.z = f2bf(v[2] * sc * w[hd + 2]); o0.w = f2bf(v[3] * sc * w[hd + 3]);
  o1.x = f2bf(v[4] * sc * w[hd + 4]); o1.y = f2bf(v[5] * sc * w[hd + 5]);
  o1.z = f2bf(v[6] * sc * w[hd + 6]); o1.w = f2bf(v[7] * sc * w[hd + 7]);
  us* op = out + (size_t)bt * D_ + d0;
  *reinterpret_cast<ushort4*>(op) = o0;
  *reinterpret_cast<ushort4*>(op + 4) = o1;
}

// ---------------------------------------------------------------------------
extern "C" void kernel_launch(void* const* d_in, const int* in_sizes, int n_in,
                              void* d_out, int out_size, void* d_ws, size_t ws_size,
                              hipStream_t stream) {
  const float* x  = (const float*)d_in[0];
  const float* Wq = (const float*)d_in[1];
  const float* Wk = (const float*)d_in[2];
  const float* Wv = (const float*)d_in[3];
  const float* Wb = (const float*)d_in[4];
  const float* Wo = (const float*)d_in[5];
  const float* cq = (const float*)d_in[6];
  const float* ck = (const float*)d_in[7];
  const float* cv = (const float*)d_in[8];
  const float* ow = (const float*)d_in[9];
  float* out = (float*)d_out;

  // workspace: 5*NE + D*D bf16 units = 176.2 MB (proven-safe footprint)
  const size_t NE = (size_t)M_ * D_;
  us* ws   = (us*)d_ws;
  us* gout = ws;              // [M,D] gemm scratch; later attn chunks + betaT
  us* qch  = ws + NE;         // q swizzled chunk layout
  us* kch  = ws + 2 * NE;     // k swizzled chunk layout
  us* Wch  = ws + 3 * NE;     // -W swizzled chunk layout
  us* kTch = ws + 4 * NE;     // kT swizzled chunk; after seq: rms-out [M,D]
  us* wt   = ws + 5 * NE;     // [D,D] W^T (reused 4x)
  us* attb = gout;                                  // [2048][64][64]
  float* betaT = (float*)(gout + 12 * 1024 * 1024); // [32][4096] f32
  // d_out as bf16 scratch: xb [0,NE), v/uv/o [NE,2NE)
  us* xb = (us*)d_out;
  us* vb = xb + NE;

  dim3 gg(D_ / 256, M_ / 256);  // 8 x 32 = 256 workgroups
  dim3 wg(D_ / 64, D_ / 64);

  to_bf16<<<NE / 2048, 256, 0, stream>>>(x, xb);

  wtrans<<<wg, 256, 0, stream>>>(Wv, wt);
  gemm256<false><<<gg, 512, 0, stream>>>(xb, wt, gout, M_, D_, D_);
  conv_silu_plain<<<M_, 256, 0, stream>>>(gout, cv, vb);

  wtrans<<<wg, 256, 0, stream>>>(Wq, wt);
  gemm256<false><<<gg, 512, 0, stream>>>(xb, wt, gout, M_, D_, D_);
  conv_silu_chunk<<<M_, 256, 0, stream>>>(gout, cq, qch, 2);

  wtrans<<<wg, 256, 0, stream>>>(Wk, wt);
  gemm256<false><<<gg, 512, 0, stream>>>(xb, wt, gout, M_, D_, D_);
  conv_silu_chunk<<<M_, 256, 0, stream>>>(gout, ck, kch, 1);

  beta_sigmoid<<<M_ / 4, 256, 0, stream>>>(x, Wb, betaT);

  delta_prep<<<32 * NCH, 256, 0, stream>>>(qch, kch, betaT, vb, Wch, kTch, attb);
  delta_seq<<<256, 256, 0, stream>>>(qch, Wch, kTch, attb, vb);

  rms_onorm_bf16<<<M_, 256, 0, stream>>>(vb, ow, kTch);

  wtrans<<<wg, 256, 0, stream>>>(Wo, wt);
  gemm256<true><<<gg, 512, 0, stream>>>(kTch, wt, out, M_, D_, D_);
}

// Round 10
// 650.931 us; speedup vs baseline: 16.0692x; 1.0412x over previous
//
#include <hip/hip_runtime.h>
#include <math.h>

#define B_ 2
#define T_ 4096
#define D_ 2048
#define H_ 16
#define DK 128
#define DV 128
#define CH 64
#define M_ (B_ * T_)  // 8192
#define NCH (T_ / CH) // 64 chunks

typedef __attribute__((ext_vector_type(8))) short bfrag;   // 8 bf16
typedef __attribute__((ext_vector_type(4))) float ffrag;   // 4 f32 acc
typedef __attribute__((ext_vector_type(8))) unsigned short u16x8;
typedef unsigned short us;

#define MFMA __builtin_amdgcn_mfma_f32_16x16x32_bf16

__device__ inline us f2bf(float f) {
  union { float f; unsigned u; } v; v.f = f;
  unsigned r = v.u + 0x7fffu + ((v.u >> 16) & 1u);
  return (us)(r >> 16);
}
__device__ inline float bf2f(us u) {
  union { unsigned u; float f; } v; v.u = ((unsigned)u) << 16;
  return v.f;
}

// async global->LDS, 16B per lane (dest = wave-uniform base + lane*16)
__device__ inline void gl_lds16(const us* g, us* l) {
  __builtin_amdgcn_global_load_lds(
      (const __attribute__((address_space(1))) void*)g,
      (__attribute__((address_space(3))) void*)l, 16, 0, 0);
}

// ---------------------------------------------------------------------------
// flat f32 -> bf16 (8 elems/thread)
// ---------------------------------------------------------------------------
__global__ __launch_bounds__(256) void to_bf16(const float* __restrict__ in,
                                               us* __restrict__ out) {
  const size_t i = ((size_t)blockIdx.x * 256 + threadIdx.x) * 8;
  const float4 a = *reinterpret_cast<const float4*>(in + i);
  const float4 b = *reinterpret_cast<const float4*>(in + i + 4);
  ushort4 o0, o1;
  o0.x = f2bf(a.x); o0.y = f2bf(a.y); o0.z = f2bf(a.z); o0.w = f2bf(a.w);
  o1.x = f2bf(b.x); o1.y = f2bf(b.y); o1.z = f2bf(b.z); o1.w = f2bf(b.w);
  *reinterpret_cast<ushort4*>(out + i) = o0;
  *reinterpret_cast<ushort4*>(out + i + 4) = o1;
}

// ---------------------------------------------------------------------------
// transpose + convert: Wt[n][k] = bf16(W[k][n]), 64x64 tiles
// ---------------------------------------------------------------------------
__global__ __launch_bounds__(256) void wtrans(const float* __restrict__ W,
                                              us* __restrict__ Wt) {
  __shared__ float tile[64][68];
  const int k0 = blockIdx.y * 64, n0 = blockIdx.x * 64;
  const int lr = threadIdx.x >> 4, lc = (threadIdx.x & 15) * 4;
#pragma unroll
  for (int p = 0; p < 4; ++p) {
    const int r = lr + p * 16;
    *reinterpret_cast<float4*>(&tile[r][lc]) =
        *reinterpret_cast<const float4*>(&W[(size_t)(k0 + r) * D_ + n0 + lc]);
  }
  __syncthreads();
#pragma unroll
  for (int p = 0; p < 4; ++p) {
    const int r = lr + p * 16;
    ushort4 o;
    o.x = f2bf(tile[lc + 0][r]); o.y = f2bf(tile[lc + 1][r]);
    o.z = f2bf(tile[lc + 2][r]); o.w = f2bf(tile[lc + 3][r]);
    *reinterpret_cast<ushort4*>(&Wt[(size_t)(n0 + r) * D_ + k0 + lc]) = o;
  }
}

// ---------------------------------------------------------------------------
// gemm256 v2 (m201-economics): C[M,N] = A[M,K] @ Bt[N,K]^T (bf16).
// BM=BN=256, BK=64, 512 thr (8 waves, 2M x 4N), wave tile 128x64 (acc 8x4).
// LDS 128KB: [dbuf 2][mat 2][kk-half 2][256 rows x 32 bf16].
// Swizzle: 16B slot ^= (row>>1)&3 (bank-balanced, 2 lanes/bank on b128 reads);
// applied on GLOBAL source, gl_lds dest linear. Stage order Akk0,Bkk0,Akk1,
// Bkk1 at 2 instrs/phase -> counted vmcnt(4) twice per tile, never 0 mid-loop.
// Natural blockIdx.x = N-stripe -> per-XCD 1MB B panel L2-resident.
// Requires M%256==0, N%256==0, K%64==0, gridDim.x == N/256 == 8.
// ---------------------------------------------------------------------------
template <bool OUTF32>
__global__ __launch_bounds__(512, 2) void gemm256(const us* __restrict__ A,
                                                  const us* __restrict__ Bt,
                                                  void* __restrict__ Cp,
                                                  int M, int N, int K) {
  __shared__ __align__(16) us lds[2][2][2][256 * 32];  // 128 KiB
  const int t = threadIdx.x, l = t & 63, w = t >> 6;
  const int wm = w >> 2, wn = w & 3;           // 2 x 4 waves
  const int fr = l & 15, hi = l >> 4;
  const int sx = 8 * (hi ^ ((fr >> 1) & 3));   // swizzled frag slot (bf16 units)

  const int m0 = blockIdx.y * 256;
  const int n0 = blockIdx.x * 256;             // XCD stripe (x dim == 8)

  // staging: instr (mat,kk,p): dest lds[..][kk][p*4096 + t*8] (linear);
  // src row = p*128 + (t>>2), src 16B-slot = (t&3) ^ ((t>>3)&3)
  const int srow = t >> 2;
  const int scol = 8 * ((t & 3) ^ ((t >> 3) & 3));
  const us* Ab = A + (size_t)(m0 + srow) * K + scol;
  const us* Bb = Bt + (size_t)(n0 + srow) * K + scol;

  ffrag acc[8][4];
#pragma unroll
  for (int mi = 0; mi < 8; ++mi)
#pragma unroll
    for (int ni = 0; ni < 4; ++ni)
#pragma unroll
      for (int e = 0; e < 4; ++e) acc[mi][ni][e] = 0.f;

#define STG_A(bf, kk, kt)                                                      \
  do {                                                                         \
    gl_lds16(Ab + (size_t)(kt) * 64 + (kk) * 32, &lds[bf][0][kk][t * 8]);      \
    gl_lds16(Ab + (size_t)128 * K + (size_t)(kt) * 64 + (kk) * 32,             \
             &lds[bf][0][kk][4096 + t * 8]);                                   \
  } while (0)
#define STG_B(bf, kk, kt)                                                      \
  do {                                                                         \
    gl_lds16(Bb + (size_t)(kt) * 64 + (kk) * 32, &lds[bf][1][kk][t * 8]);      \
    gl_lds16(Bb + (size_t)128 * K + (size_t)(kt) * 64 + (kk) * 32,             \
             &lds[bf][1][kk][4096 + t * 8]);                                   \
  } while (0)

  const int NT = K >> 6;
  // prologue: tile 0, order Akk0 Bkk0 Akk1 Bkk1 -> oldest 4 = kk0 halves
  STG_A(0, 0, 0); STG_B(0, 0, 0); STG_A(0, 1, 0); STG_B(0, 1, 0);
  asm volatile("s_waitcnt vmcnt(4)" ::: "memory");
  __builtin_amdgcn_s_barrier();
  __builtin_amdgcn_sched_barrier(0);

  const int arow = wm * 128 + fr;  // A frag base row (within 256)
  const int brow = wn * 64 + fr;   // B frag base row

#pragma unroll 1
  for (int kt = 0; kt < NT; ++kt) {
    const int cur = kt & 1, oth = cur ^ 1;
    const bool pf = (kt + 1 < NT);
    bfrag af4[4], bf4[4];

    // ======== kk = 0 ========
    {
      const us* pa = &lds[cur][0][0][0];
      const us* pb = &lds[cur][1][0][0];
#pragma unroll
      for (int ni = 0; ni < 4; ++ni)
        bf4[ni] = *reinterpret_cast<const bfrag*>(pb + (brow + ni * 16) * 32 + sx);
#pragma unroll
      for (int mi = 0; mi < 4; ++mi)
        af4[mi] = *reinterpret_cast<const bfrag*>(pa + (arow + mi * 16) * 32 + sx);
      if (pf) STG_A(oth, 0, kt + 1);
      __builtin_amdgcn_s_setprio(1);
#pragma unroll
      for (int mi = 0; mi < 4; ++mi)
#pragma unroll
        for (int ni = 0; ni < 4; ++ni)
          acc[mi][ni] = MFMA(af4[mi], bf4[ni], acc[mi][ni], 0, 0, 0);
      __builtin_amdgcn_s_setprio(0);
#pragma unroll
      for (int mi = 0; mi < 4; ++mi)
        af4[mi] = *reinterpret_cast<const bfrag*>(pa + (arow + 64 + mi * 16) * 32 + sx);
      if (pf) STG_B(oth, 0, kt + 1);
      __builtin_amdgcn_s_setprio(1);
#pragma unroll
      for (int mi = 0; mi < 4; ++mi)
#pragma unroll
        for (int ni = 0; ni < 4; ++ni)
          acc[mi + 4][ni] = MFMA(af4[mi], bf4[ni], acc[mi + 4][ni], 0, 0, 0);
      __builtin_amdgcn_s_setprio(0);
    }
    // W2: current tile's kk1 halves complete; next tile's kk0 stay in flight
    if (pf) asm volatile("s_waitcnt vmcnt(4)" ::: "memory");
    else    asm volatile("s_waitcnt vmcnt(0)" ::: "memory");
    __builtin_amdgcn_s_barrier();
    __builtin_amdgcn_sched_barrier(0);

    // ======== kk = 1 ========
    {
      const us* pa = &lds[cur][0][1][0];
      const us* pb = &lds[cur][1][1][0];
#pragma unroll
      for (int ni = 0; ni < 4; ++ni)
        bf4[ni] = *reinterpret_cast<const bfrag*>(pb + (brow + ni * 16) * 32 + sx);
#pragma unroll
      for (int mi = 0; mi < 4; ++mi)
        af4[mi] = *reinterpret_cast<const bfrag*>(pa + (arow + mi * 16) * 32 + sx);
      if (pf) STG_A(oth, 1, kt + 1);
      __builtin_amdgcn_s_setprio(1);
#pragma unroll
      for (int mi = 0; mi < 4; ++mi)
#pragma unroll
        for (int ni = 0; ni < 4; ++ni)
          acc[mi][ni] = MFMA(af4[mi], bf4[ni], acc[mi][ni], 0, 0, 0);
      __builtin_amdgcn_s_setprio(0);
#pragma unroll
      for (int mi = 0; mi < 4; ++mi)
        af4[mi] = *reinterpret_cast<const bfrag*>(pa + (arow + 64 + mi * 16) * 32 + sx);
      if (pf) STG_B(oth, 1, kt + 1);
      __builtin_amdgcn_s_setprio(1);
#pragma unroll
      for (int mi = 0; mi < 4; ++mi)
#pragma unroll
        for (int ni = 0; ni < 4; ++ni)
          acc[mi + 4][ni] = MFMA(af4[mi], bf4[ni], acc[mi + 4][ni], 0, 0, 0);
      __builtin_amdgcn_s_setprio(0);
    }
    // W1: next tile's kk0 halves complete; its kk1 stay in flight
    if (pf) asm volatile("s_waitcnt vmcnt(4)" ::: "memory");
    else    asm volatile("s_waitcnt vmcnt(0)" ::: "memory");
    __builtin_amdgcn_s_barrier();
    __builtin_amdgcn_sched_barrier(0);
  }
#undef STG_A
#undef STG_B

  // epilogue: C write (C/D map: col = lane&15, row = hi*4 + reg)
  const int crow = m0 + wm * 128 + hi * 4;
  const int ccol = n0 + wn * 64 + fr;
#pragma unroll
  for (int mi = 0; mi < 8; ++mi)
#pragma unroll
    for (int ni = 0; ni < 4; ++ni)
#pragma unroll
      for (int j = 0; j < 4; ++j) {
        const size_t idx = (size_t)(crow + mi * 16 + j) * N + ccol + ni * 16;
        if constexpr (OUTF32) ((float*)Cp)[idx] = acc[mi][ni][j];
        else ((us*)Cp)[idx] = f2bf(acc[mi][ni][j]);
      }
}

// ---------------------------------------------------------------------------
// conv+silu bodies
// ---------------------------------------------------------------------------
__device__ inline void conv_body(const us* __restrict__ in, const float* cw,
                                 int bt, int d0, int mode, float v[8]) {
  const int tb = bt & (T_ - 1);
  const us* row = in + (size_t)bt * D_ + d0;
#pragma unroll
  for (int j = 0; j < 8; ++j) v[j] = 0.f;
#pragma unroll
  for (int j = 0; j < 4; ++j) {
    if (tb >= j) {
      const us* rp = row - (size_t)(j * D_);
      const ushort4 a = *reinterpret_cast<const ushort4*>(rp);
      const ushort4 b = *reinterpret_cast<const ushort4*>(rp + 4);
      const float wj = cw[3 - j];
      v[0] = fmaf(wj, bf2f(a.x), v[0]); v[1] = fmaf(wj, bf2f(a.y), v[1]);
      v[2] = fmaf(wj, bf2f(a.z), v[2]); v[3] = fmaf(wj, bf2f(a.w), v[3]);
      v[4] = fmaf(wj, bf2f(b.x), v[4]); v[5] = fmaf(wj, bf2f(b.y), v[5]);
      v[6] = fmaf(wj, bf2f(b.z), v[6]); v[7] = fmaf(wj, bf2f(b.w), v[7]);
    }
  }
#pragma unroll
  for (int j = 0; j < 8; ++j) v[j] = v[j] / (1.f + expf(-v[j]));
  if (mode) {
    float ss = 0.f;
#pragma unroll
    for (int j = 0; j < 8; ++j) ss = fmaf(v[j], v[j], ss);
    ss += __shfl_xor(ss, 1);
    ss += __shfl_xor(ss, 2);
    ss += __shfl_xor(ss, 4);
    ss += __shfl_xor(ss, 8);
    float sc = rsqrtf(ss + 1e-6f);
    if (mode == 2) sc *= 0.08838834764831845f;  // 128^-0.5
#pragma unroll
    for (int j = 0; j < 8; ++j) v[j] *= sc;
  }
}

__global__ __launch_bounds__(256) void conv_silu_plain(const us* __restrict__ in,
                                                       const float* __restrict__ cw,
                                                       us* __restrict__ out) {
  const int bt = blockIdx.x, d0 = threadIdx.x * 8;
  float v[8];
  conv_body(in, cw, bt, d0, 0, v);
  ushort4 o0, o1;
  o0.x = f2bf(v[0]); o0.y = f2bf(v[1]); o0.z = f2bf(v[2]); o0.w = f2bf(v[3]);
  o1.x = f2bf(v[4]); o1.y = f2bf(v[5]); o1.z = f2bf(v[6]); o1.w = f2bf(v[7]);
  us* op = out + (size_t)bt * D_ + d0;
  *reinterpret_cast<ushort4*>(op) = o0;
  *reinterpret_cast<ushort4*>(op + 4) = o1;
}

// conv+silu+l2norm -> swizzled chunk layout [bh][cid][64][128], 16B-group XOR(r&15)
__global__ __launch_bounds__(256) void conv_silu_chunk(const us* __restrict__ in,
                                                       const float* __restrict__ cw,
                                                       us* __restrict__ out,
                                                       int mode) {
  const int bt = blockIdx.x, d0 = threadIdx.x * 8;
  float v[8];
  conv_body(in, cw, bt, d0, mode, v);
  const int b = bt >> 12, tt = bt & (T_ - 1);
  const int cid = tt >> 6, r = tt & 63;
  const int h = d0 >> 7, g = (d0 & 127) >> 3;
  us* dst = out + ((size_t)((b * H_ + h) * NCH + cid)) * (CH * DK) +
            r * 128 + ((g ^ (r & 15)) * 8);
  ushort4 o0, o1;
  o0.x = f2bf(v[0]); o0.y = f2bf(v[1]); o0.z = f2bf(v[2]); o0.w = f2bf(v[3]);
  o1.x = f2bf(v[4]); o1.y = f2bf(v[5]); o1.z = f2bf(v[6]); o1.w = f2bf(v[7]);
  *reinterpret_cast<ushort4*>(dst) = o0;
  *reinterpret_cast<ushort4*>(dst + 4) = o1;
}

// ---------------------------------------------------------------------------
// beta = sigmoid(x @ Wb) -> [bh][T] layout (contiguous for prep)
// ---------------------------------------------------------------------------
__global__ __launch_bounds__(256) void beta_sigmoid(const float* __restrict__ x,
                                                    const float* __restrict__ Wb,
                                                    float* __restrict__ betaT) {
  const int t = threadIdx.x;
  const int m = blockIdx.x * 4 + (t >> 6);
  const int l = t & 63;
  const int c = l & 15;
  const int s = l >> 4;
  const float* xr = x + (size_t)m * D_;
  const int kb = s * (D_ / 4);
  float acc = 0.f;
  for (int k = 0; k < D_ / 4; ++k)
    acc = fmaf(xr[kb + k], Wb[(size_t)(kb + k) * H_ + c], acc);
  acc += __shfl_xor(acc, 16);
  acc += __shfl_xor(acc, 32);
  if (l < 16) {
    const int b = m >> 12, tt = m & (T_ - 1);
    betaT[((size_t)(b * H_ + c)) * T_ + tt] = 1.f / (1.f + expf(-acc));
  }
}

// ---------------------------------------------------------------------------
// f32 blocked product step for T = M^-1: T[I][J] = -T_II * (sum_K M[I][K] T[K][J])
// ---------------------------------------------------------------------------
__device__ inline void prod_step(float* Tf, const float* Am, float* xbuf,
                                 int r, int c, int I, int J,
                                 int nk, int K0, int K1, int K2) {
  float X = 0.f;
  const int Ks[3] = {K0, K1, K2};
  for (int kk = 0; kk < nk; ++kk) {
    const int K = Ks[kk];
    const float* amrow = Am + (16 * I + r) * 72 + 16 * K;
    const float* tcol = Tf + (16 * K) * 68 + 16 * J + c;
#pragma unroll
    for (int m = 0; m < 16; ++m) X = fmaf(amrow[m], tcol[m * 68], X);
  }
  __syncthreads();               // prior step's xbuf readers done
  xbuf[r * 17 + c] = X;
  __syncthreads();               // xbuf ready
  float s = 0.f;
  const float* trow = Tf + (16 * I + r) * 68 + 16 * I;
#pragma unroll
  for (int m = 0; m < 16; ++m) s = fmaf(trow[m], xbuf[m * 17 + c], s);
  Tf[(16 * I + r) * 68 + 16 * J + c] = -s;   // disjoint from reads above
  __syncthreads();               // block (I,J) visible for next step
}

// ---------------------------------------------------------------------------
// delta_prep v2 (proven R6): block per (b,h,chunk) = 2048, 256 thr, 2 blocks/CU.
// ---------------------------------------------------------------------------
__global__ __launch_bounds__(256, 2) void delta_prep(const us* __restrict__ qch,
                                                     const us* __restrict__ kch,
                                                     const float* __restrict__ betaT,
                                                     us* __restrict__ v_uv,
                                                     us* __restrict__ Wout,
                                                     us* __restrict__ kTout,
                                                     us* __restrict__ Aout) {
  __shared__ __align__(16) unsigned char lds[72000];
  us*    ks    = (us*)(lds);             // [64*128] swz     (P0-P1)
  us*    Tb    = (us*)(lds);             // [64][72] bf16    (P5-)
  float* Am    = (float*)(lds + 16384);  // [64][72] f32     (P1-P4)
  us*    vTb   = (us*)(lds + 16384);     // [128][72] bf16   (P5-)
  float* Tf    = (float*)(lds + 34816);  // [64][68] f32     (P2-P5)
  us*    atst  = (us*)(lds + 34816);     // attn stage [64*64] (P0-P2)
  us*    Wst   = (us*)(lds + 34816);     // W stage [64*128] (P6-)
  us*    kTb   = (us*)(lds + 52224);     // [128][72] bf16   (P1-P6a)
  us*    UVst  = (us*)(lds + 52224);     // [64*128]         (P6b-)
  float* betac = (float*)(lds + 70656);  // [64]
  float* xbuf  = (float*)(lds + 70912);  // [16][17]

  const int t = threadIdx.x, w = t >> 6, l = t & 63;
  const int rr = l & 15, hi = l >> 4;
  const int bx = blockIdx.x;
  const int bh = bx >> 6, cid = bx & 63;
  const int b = bh >> 4, h = bh & 15;
  const size_t rowbase = ((size_t)b * T_ + (size_t)cid * CH) * D_ + (size_t)h * DK;
  const size_t cbase = (size_t)bx * (CH * DK);
  const size_t abase = (size_t)bx * (CH * CH);

  // ---- P0: stage ks, zero attn-stage, betac
  {
    const us* kg = kch + cbase;
#pragma unroll
    for (int p = 0; p < 4; ++p)
      gl_lds16(kg + p * 2048 + t * 8, ks + p * 2048 + t * 8);
    const float4 z = make_float4(0.f, 0.f, 0.f, 0.f);
    *reinterpret_cast<float4*>(atst + t * 16) = z;
    *reinterpret_cast<float4*>(atst + t * 16 + 8) = z;
    if (t < 64) betac[t] = betaT[(size_t)bh * T_ + cid * CH + t];
  }
  __syncthreads();

  // ---- P1: A MFMA (beta-scaled strict-tril -> Am f32), attn MFMA -> atst,
  //          kTb build (plain k^T bf16)
  {
    bfrag qf[4], kf[4];
#pragma unroll
    for (int k4 = 0; k4 < 4; ++k4) {
      const int go = ((4 * k4 + hi) ^ rr) * 8;
      qf[k4] = *reinterpret_cast<const bfrag*>(qch + cbase + (16 * w + rr) * 128 + go);
      kf[k4] = *reinterpret_cast<const bfrag*>(ks + (16 * w + rr) * 128 + go);
    }
    for (int jt = 0; jt <= w; ++jt) {
      ffrag accA = {0.f, 0.f, 0.f, 0.f}, accQ = {0.f, 0.f, 0.f, 0.f};
#pragma unroll
      for (int k4 = 0; k4 < 4; ++k4) {
        const bfrag bfr = *reinterpret_cast<const bfrag*>(
            ks + (16 * jt + rr) * 128 + (((4 * k4 + hi) ^ rr) * 8));
        accA = MFMA(kf[k4], bfr, accA, 0, 0, 0);
        accQ = MFMA(qf[k4], bfr, accQ, 0, 0, 0);
      }
#pragma unroll
      for (int j4 = 0; j4 < 4; ++j4) {
        const int i = 16 * w + 4 * hi + j4, j = 16 * jt + rr;
        Am[i * 72 + j] = (j < i) ? betac[i] * accA[j4] : 0.f;
        if (j <= i)
          atst[i * 64 + (((j >> 3) ^ (i & 7)) * 8) + (j & 7)] = f2bf(accQ[j4]);
      }
    }
    const int r = t & 63, part = t >> 6;
#pragma unroll
    for (int gi = 0; gi < 4; ++gi) {
      const int g = 4 * part + gi;
      const u16x8 kv = *reinterpret_cast<const u16x8*>(ks + r * 128 + ((g ^ (r & 15)) * 8));
#pragma unroll
      for (int j = 0; j < 8; ++j) kTb[(g * 8 + j) * 72 + r] = kv[j];
    }
  }
  __syncthreads();

  // ---- P2: copy attn + kT to global; then zero Tf (same region as atst!)
  {
#pragma unroll
    for (int p = 0; p < 2; ++p) {
      const int unit = t + p * 256;
      *reinterpret_cast<u16x8*>(Aout + abase + unit * 8) =
          *reinterpret_cast<const u16x8*>(atst + unit * 8);
    }
#pragma unroll
    for (int p = 0; p < 4; ++p) {
      const int unit = t + p * 256;
      const int d = unit >> 3, sg = unit & 7;
      *reinterpret_cast<u16x8*>(kTout + cbase + unit * 8) =
          *reinterpret_cast<const u16x8*>(kTb + d * 72 + ((sg ^ (d & 7)) * 8));
    }
  }
  __syncthreads();  // atst reads done before Tf overwrite
  for (int i = t; i < 64 * 68; i += 256) Tf[i] = 0.f;
  __syncthreads();

  // ---- P3: four 16x16 unit-lower diagonal inverses (64 threads)
  if (t < 64) {
    const int blk = t >> 4, j = t & 15, bd = blk * 16;
    Tf[(bd + j) * 68 + bd + j] = 1.f;
    for (int i = j + 1; i < 16; ++i) {
      float s = 0.f;
      for (int m = j; m < i; ++m)
        s = fmaf(Am[(bd + i) * 72 + bd + m], Tf[(bd + m) * 68 + bd + j], s);
      Tf[(bd + i) * 68 + bd + j] = -s;
    }
  }
  __syncthreads();

  // ---- P4: off-diagonal blocks of T (f32, all 256 threads)
  {
    const int r = t >> 4, c = t & 15;
    prod_step(Tf, Am, xbuf, r, c, 1, 0, 1, 0, 0, 0);
    prod_step(Tf, Am, xbuf, r, c, 2, 0, 2, 0, 1, 0);
    prod_step(Tf, Am, xbuf, r, c, 3, 0, 3, 0, 1, 2);
    prod_step(Tf, Am, xbuf, r, c, 2, 1, 1, 1, 0, 0);
    prod_step(Tf, Am, xbuf, r, c, 3, 1, 2, 1, 2, 0);
    prod_step(Tf, Am, xbuf, r, c, 3, 2, 1, 2, 0, 0);
  }

  // ---- P5: Tb = bf16(T * diag(beta)) into ks region; vTb = v^T into Am region
  {
    const int vr = t >> 2, vp = t & 3;
    u16x8 vv[4];
#pragma unroll
    for (int g = 0; g < 4; ++g)
      vv[g] = *reinterpret_cast<const u16x8*>(v_uv + rowbase + (size_t)vr * D_ +
                                              vp * 32 + g * 8);
    const int ti = t >> 2, tg = t & 3;
    u16x8 w0, w1;
#pragma unroll
    for (int jj = 0; jj < 8; ++jj) {
      const int j0 = tg * 16 + jj, j1 = j0 + 8;
      w0[jj] = f2bf(Tf[ti * 68 + j0] * betac[j0]);
      w1[jj] = f2bf(Tf[ti * 68 + j1] * betac[j1]);
    }
    *reinterpret_cast<u16x8*>(Tb + ti * 72 + tg * 16) = w0;
    *reinterpret_cast<u16x8*>(Tb + ti * 72 + tg * 16 + 8) = w1;
#pragma unroll
    for (int g = 0; g < 4; ++g)
#pragma unroll
      for (int j = 0; j < 8; ++j)
        vTb[(vp * 32 + g * 8 + j) * 72 + vr] = vv[g][j];
  }
  __syncthreads();

  // ---- P6a: W = -(Tb . kTb) -> Wst (swz16)
  {
    bfrag ta[2];
#pragma unroll
    for (int k2 = 0; k2 < 2; ++k2)
      ta[k2] = *reinterpret_cast<const bfrag*>(Tb + (16 * w + rr) * 72 + 32 * k2 + 8 * hi);
#pragma unroll
    for (int dt = 0; dt < 8; ++dt) {
      ffrag acc = {0.f, 0.f, 0.f, 0.f};
#pragma unroll
      for (int k2 = 0; k2 < 2; ++k2) {
        const bfrag bfr = *reinterpret_cast<const bfrag*>(
            kTb + (16 * dt + rr) * 72 + 32 * k2 + 8 * hi);
        acc = MFMA(ta[k2], bfr, acc, 0, 0, 0);
      }
#pragma unroll
      for (int j4 = 0; j4 < 4; ++j4) {
        const int i = 16 * w + 4 * hi + j4, d = 16 * dt + rr;
        Wst[i * 128 + (((d >> 3) ^ (i & 15)) * 8) + (d & 7)] = f2bf(-acc[j4]);
      }
    }
  }
  __syncthreads();  // kTb reads done (UVst may overwrite); Wst complete

  // ---- P6b: UV = Tb . vTb -> UVst; copy W out
  {
    bfrag ta[2];
#pragma unroll
    for (int k2 = 0; k2 < 2; ++k2)
      ta[k2] = *reinterpret_cast<const bfrag*>(Tb + (16 * w + rr) * 72 + 32 * k2 + 8 * hi);
#pragma unroll
    for (int et = 0; et < 8; ++et) {
      ffrag acc = {0.f, 0.f, 0.f, 0.f};
#pragma unroll
      for (int k2 = 0; k2 < 2; ++k2) {
        const bfrag bfr = *reinterpret_cast<const bfrag*>(
            vTb + (16 * et + rr) * 72 + 32 * k2 + 8 * hi);
        acc = MFMA(ta[k2], bfr, acc, 0, 0, 0);
      }
#pragma unroll
      for (int j4 = 0; j4 < 4; ++j4)
        UVst[(16 * w + 4 * hi + j4) * 128 + 16 * et + rr] = f2bf(acc[j4]);
    }
#pragma unroll
    for (int p = 0; p < 4; ++p) {
      const int unit = t + p * 256;
      *reinterpret_cast<u16x8*>(Wout + cbase + unit * 8) =
          *reinterpret_cast<const u16x8*>(Wst + unit * 8);
    }
  }
  __syncthreads();

  // ---- P7: copy u_v out (in-place over v, row-major [M,D])
#pragma unroll
  for (int p = 0; p < 4; ++p) {
    const int unit = t + p * 256;
    const int r = unit >> 4, g = unit & 15;
    *reinterpret_cast<u16x8*>(v_uv + rowbase + (size_t)r * D_ + g * 8) =
        *reinterpret_cast<const u16x8*>(UVst + r * 128 + g * 8);
  }
}

// ---------------------------------------------------------------------------
// delta_seq v3 (proven R7): MFMA + counted-vmcnt + register-resident S.
// ---------------------------------------------------------------------------
__global__ __launch_bounds__(256, 1) void delta_seq(const us* __restrict__ qch,
                                                    const us* __restrict__ Wch,
                                                    const us* __restrict__ kTch,
                                                    const us* __restrict__ atch,
                                                    us* __restrict__ uv_o) {
  __shared__ __align__(16) us qs[2][CH * DK];    // 16KB x2
  __shared__ __align__(16) us Ws[2][CH * DK];    // 16KB x2
  __shared__ __align__(16) us kTs[2][DK * CH];   // 16KB x2
  __shared__ __align__(16) us ats[2][CH * CH];   // 8KB  x2
  __shared__ __align__(16) us uvs[2][CH * 16];   // 2KB  x2
  __shared__ __align__(16) us Sb[2][16 * 136];   // 4.25KB x2 (S^T bf16, dbuf)
  __shared__ __align__(16) us ub[CH * 18];       // 2.25KB (u bf16)

  const int t = threadIdx.x, l = t & 63, w = t >> 6;
  const int bx = blockIdx.x;
  const int vs = bx >> 5, bh = bx & 31;
  const int b = bh >> 4, h = bh & 15;
  const int rr = l & 15, hi = l >> 4;

  // S lives in registers: wave w owns rows 32w..32w+31 (2 tiles), col rr per lane
  ffrag sacc[2];
#pragma unroll
  for (int t2 = 0; t2 < 2; ++t2)
#pragma unroll
    for (int j = 0; j < 4; ++j) sacc[t2][j] = 0.f;

  for (int i = t; i < 16 * 136; i += 256) Sb[0][i] = 0;

  const size_t cbQ = (size_t)(bh * NCH) * (CH * DK);
  const size_t cbA = (size_t)(bh * NCH) * (CH * CH);
  const size_t rowbase0 = ((size_t)b * T_) * D_ + (size_t)h * DK + vs * 16;

#define STAGE(buf, cid)                                                        \
  do {                                                                         \
    const us* qg = qch + cbQ + (size_t)(cid) * (CH * DK);                      \
    const us* Wg = Wch + cbQ + (size_t)(cid) * (CH * DK);                      \
    const us* kg = kTch + cbQ + (size_t)(cid) * (CH * DK);                     \
    const us* ag = atch + cbA + (size_t)(cid) * (CH * CH);                     \
    _Pragma("unroll")                                                          \
    for (int p = 0; p < 4; ++p) {                                              \
      gl_lds16(qg + p * 2048 + t * 8, &qs[buf][p * 2048 + t * 8]);             \
      gl_lds16(Wg + p * 2048 + t * 8, &Ws[buf][p * 2048 + t * 8]);             \
      gl_lds16(kg + p * 2048 + t * 8, &kTs[buf][p * 2048 + t * 8]);            \
    }                                                                          \
    _Pragma("unroll")                                                          \
    for (int p = 0; p < 2; ++p)                                                \
      gl_lds16(ag + p * 2048 + t * 8, &ats[buf][p * 2048 + t * 8]);            \
    if (t < 128)                                                               \
      gl_lds16(uv_o + rowbase0 + (size_t)((cid) * CH + (t >> 1)) * D_ + (t & 1) * 8, \
               &uvs[buf][t * 8]);                                              \
  } while (0)

  STAGE(0, 0);
  asm volatile("s_waitcnt vmcnt(0) lgkmcnt(0)" ::: "memory");
  __builtin_amdgcn_s_barrier();
  __builtin_amdgcn_sched_barrier(0);

  for (int cid = 0; cid < NCH; ++cid) {
    const int cur = cid & 1;
    if (cid + 1 < NCH) STAGE(cur ^ 1, cid + 1);  // async; drained at end barrier

    // Sb fragments (shared by u- and o-phases)
    bfrag sbf[4];
#pragma unroll
    for (int ks = 0; ks < 4; ++ks)
      sbf[ks] = *reinterpret_cast<const bfrag*>(&Sb[cur][rr * 136 + ks * 32 + hi * 8]);

    // ---- u-phase: wave w owns rows 16w..16w+15
    {
      ffrag uacc;
#pragma unroll
      for (int j = 0; j < 4; ++j)
        uacc[j] = bf2f(uvs[cur][(16 * w + 4 * hi + j) * 16 + rr]);
#pragma unroll
      for (int ks = 0; ks < 4; ++ks) {
        const bfrag af = *reinterpret_cast<const bfrag*>(
            &Ws[cur][(16 * w + rr) * 128 + (((4 * ks + hi) ^ rr) * 8)]);
        uacc = MFMA(af, sbf[ks], uacc, 0, 0, 0);
      }
#pragma unroll
      for (int j = 0; j < 4; ++j)
        ub[(16 * w + 4 * hi + j) * 18 + rr] = f2bf(uacc[j]);
    }
    asm volatile("s_waitcnt lgkmcnt(0)" ::: "memory");  // ub visible; loads stay in flight
    __builtin_amdgcn_s_barrier();
    __builtin_amdgcn_sched_barrier(0);

    // ---- o-phase
    {
      ffrag oacc;
#pragma unroll
      for (int j = 0; j < 4; ++j) oacc[j] = 0.f;
#pragma unroll
      for (int ks = 0; ks < 4; ++ks) {
        const bfrag af = *reinterpret_cast<const bfrag*>(
            &qs[cur][(16 * w + rr) * 128 + (((4 * ks + hi) ^ rr) * 8)]);
        oacc = MFMA(af, sbf[ks], oacc, 0, 0, 0);
      }
      const int nks = (w < 2) ? 1 : 2;  // causal: upper attn cols are zero
      for (int ks = 0; ks < nks; ++ks) {
        bfrag ubf;
#pragma unroll
        for (int j = 0; j < 8; ++j)
          ubf[j] = (short)ub[(32 * ks + 8 * hi + j) * 18 + rr];
        const bfrag af = *reinterpret_cast<const bfrag*>(
            &ats[cur][(16 * w + rr) * 64 + (((4 * ks + hi) ^ (rr & 7)) * 8)]);
        oacc = MFMA(af, ubf, oacc, 0, 0, 0);
      }
      us* og = uv_o + rowbase0 + (size_t)(cid * CH) * D_;
#pragma unroll
      for (int j = 0; j < 4; ++j)
        og[(size_t)(16 * w + 4 * hi + j) * D_ + rr] = f2bf(oacc[j]);
    }

    // ---- S-phase: register accumulate + write bf16(S^T) to Sb[cur^1]
    {
      bfrag ubf[2];
#pragma unroll
      for (int ks = 0; ks < 2; ++ks)
#pragma unroll
        for (int j = 0; j < 8; ++j)
          ubf[ks][j] = (short)ub[(32 * ks + 8 * hi + j) * 18 + rr];
#pragma unroll
      for (int t2 = 0; t2 < 2; ++t2) {
        const int tile = 2 * w + t2;
#pragma unroll
        for (int ks = 0; ks < 2; ++ks) {
          const bfrag af = *reinterpret_cast<const bfrag*>(
              &kTs[cur][(16 * tile + rr) * 64 + (((4 * ks + hi) ^ (rr & 7)) * 8)]);
          sacc[t2] = MFMA(af, ubf[ks], sacc[t2], 0, 0, 0);
        }
        ushort4 sw;
        sw.x = f2bf(sacc[t2][0]); sw.y = f2bf(sacc[t2][1]);
        sw.z = f2bf(sacc[t2][2]); sw.w = f2bf(sacc[t2][3]);
        *reinterpret_cast<ushort4*>(&Sb[cur ^ 1][rr * 136 + 16 * tile + 4 * hi]) = sw;
      }
    }
    // drain staged loads (had full chunk compute to land) + LDS writes; barrier
    asm volatile("s_waitcnt vmcnt(0) lgkmcnt(0)" ::: "memory");
    __builtin_amdgcn_s_barrier();
    __builtin_amdgcn_sched_barrier(0);
  }
#undef STAGE
}

// ---------------------------------------------------------------------------
// per-head RMSNorm (over 128) * onorm_w : bf16 in -> bf16 out
// ---------------------------------------------------------------------------
__global__ __launch_bounds__(256) void rms_onorm_bf16(const us* __restrict__ in,
                                                      const float* __restrict__ w,
                                                      us* __restrict__ out) {
  const int bt = blockIdx.x;
  const int d0 = threadIdx.x * 8;
  const us* p = in + (size_t)bt * D_ + d0;
  const ushort4 a = *reinterpret_cast<const ushort4*>(p);
  const ushort4 b = *reinterpret_cast<const ushort4*>(p + 4);
  float v[8] = {bf2f(a.x), bf2f(a.y), bf2f(a.z), bf2f(a.w),
                bf2f(b.x), bf2f(b.y), bf2f(b.z), bf2f(b.w)};
  float ss = 0.f;
#pragma unroll
  for (int j = 0; j < 8; ++j) ss = fmaf(v[j], v[j], ss);
  ss += __shfl_xor(ss, 1);
  ss += __shfl_xor(ss, 2);
  ss += __shfl_xor(ss, 4);
  ss += __shfl_xor(ss, 8);
  const float sc = rsqrtf(ss * (1.0f / 128.0f) + 1e-5f);
  const int hd = d0 & 127;
  ushort4 o0, o1;
  o0.x = f2bf(v[0] * sc * w[hd + 0]); o0.y = f2bf(v[1] * sc * w[hd + 1]);
  o0.z = f2bf(v[2] * sc * w[hd + 2]); o0.w = f2bf(v[3] * sc * w[hd + 3]);
  o1.x = f2bf(v[4] * sc * w[hd + 4]); o1.y = f2bf(v[5] * sc * w[hd + 5]);
  o1.z = f2bf(v[6] * sc * w[hd + 6]); o1.w = f2bf(v[7] * sc * w[hd + 7]);
  us* op = out + (size_t)bt * D_ + d0;
  *reinterpret_cast<ushort4*>(op) = o0;
  *reinterpret_cast<ushort4*>(op + 4) = o1;
}

// ---------------------------------------------------------------------------
extern "C" void kernel_launch(void* const* d_in, const int* in_sizes, int n_in,
                              void* d_out, int out_size, void* d_ws, size_t ws_size,
                              hipStream_t stream) {
  const float* x  = (const float*)d_in[0];
  const float* Wq = (const float*)d_in[1];
  const float* Wk = (const float*)d_in[2];
  const float* Wv = (const float*)d_in[3];
  const float* Wb = (const float*)d_in[4];
  const float* Wo = (const float*)d_in[5];
  const float* cq = (const float*)d_in[6];
  const float* ck = (const float*)d_in[7];
  const float* cv = (const float*)d_in[8];
  const float* ow = (const float*)d_in[9];
  float* out = (float*)d_out;

  // workspace: 5*NE + D*D bf16 units = 176.2 MB (proven-safe footprint)
  const size_t NE = (size_t)M_ * D_;
  us* ws   = (us*)d_ws;
  us* gout = ws;              // [M,D] gemm scratch; later attn chunks + betaT
  us* qch  = ws + NE;         // q swizzled chunk layout
  us* kch  = ws + 2 * NE;     // k swizzled chunk layout
  us* Wch  = ws + 3 * NE;     // -W swizzled chunk layout
  us* kTch = ws + 4 * NE;     // kT swizzled chunk; after seq: rms-out [M,D]
  us* wt   = ws + 5 * NE;     // [D,D] W^T (reused 4x)
  us* attb = gout;                                  // [2048][64][64]
  float* betaT = (float*)(gout + 12 * 1024 * 1024); // [32][4096] f32
  // d_out as bf16 scratch: xb [0,NE), v/uv/o [NE,2NE)
  us* xb = (us*)d_out;
  us* vb = xb + NE;

  dim3 gg(D_ / 256, M_ / 256);  // 8 x 32 = 256 workgroups; x == N-stripe
  dim3 wg(D_ / 64, D_ / 64);

  to_bf16<<<NE / 2048, 256, 0, stream>>>(x, xb);

  wtrans<<<wg, 256, 0, stream>>>(Wv, wt);
  gemm256<false><<<gg, 512, 0, stream>>>(xb, wt, gout, M_, D_, D_);
  conv_silu_plain<<<M_, 256, 0, stream>>>(gout, cv, vb);

  wtrans<<<wg, 256, 0, stream>>>(Wq, wt);
  gemm256<false><<<gg, 512, 0, stream>>>(xb, wt, gout, M_, D_, D_);
  conv_silu_chunk<<<M_, 256, 0, stream>>>(gout, cq, qch, 2);

  wtrans<<<wg, 256, 0, stream>>>(Wk, wt);
  gemm256<false><<<gg, 512, 0, stream>>>(xb, wt, gout, M_, D_, D_);
  conv_silu_chunk<<<M_, 256, 0, stream>>>(gout, ck, kch, 1);

  beta_sigmoid<<<M_ / 4, 256, 0, stream>>>(x, Wb, betaT);

  delta_prep<<<32 * NCH, 256, 0, stream>>>(qch, kch, betaT, vb, Wch, kTch, attb);
  delta_seq<<<256, 256, 0, stream>>>(qch, Wch, kTch, attb, vb);

  rms_onorm_bf16<<<M_, 256, 0, stream>>>(vb, ow, kTch);

  wtrans<<<wg, 256, 0, stream>>>(Wo, wt);
  gemm256<true><<<gg, 512, 0, stream>>>(kTch, wt, out, M_, D_, D_);
}